// Round 10
// baseline (1438.149 us; speedup 1.0000x reference)
//
#include <hip/hip_runtime.h>
#include <math.h>

#define NN 100000
#define MPAD 100096
#define DD 128
#define EE 1600000
#define ET (EE + NN)
#define ND (NN * DD)

#define NBKT 782
#define IPB 16384
#define GSC 104
#define BCAP 6144

typedef short bf16x8 __attribute__((ext_vector_type(8)));
typedef float f32x4 __attribute__((ext_vector_type(4)));

static __device__ __forceinline__ unsigned short f2bf(float f) {
  unsigned int u = __float_as_uint(f);
  u += 0x7FFFu + ((u >> 16) & 1u);
  return (unsigned short)(u >> 16);
}
static __device__ __forceinline__ float bf2f(unsigned short h) {
  return __uint_as_float(((unsigned int)h) << 16);
}
static __device__ __forceinline__ float gelu_exact(float v) {
  return 0.5f * v * (1.f + erff(v * 0.7071067811865476f));
}

// ---------------- CSR build: bucketed counting sort ----------------

__global__ void k_zero_int(int* __restrict__ p, int n) {
  int i = blockIdx.x * blockDim.x + threadIdx.x;
  if (i < n) p[i] = 0;
}

__global__ __launch_bounds__(256) void kb_hist(const int* __restrict__ ei,
                                               int* __restrict__ cnt) {
  __shared__ int lc[NBKT];
  int t = threadIdx.x;
  for (int b = t; b < NBKT; b += 256) lc[b] = 0;
  __syncthreads();
  int i0 = blockIdx.x * IPB;
  int i1 = min(i0 + IPB, ET);
  for (int i = i0 + t; i < i1; i += 256) {
    int dst = (i < EE) ? ei[EE + i] : (i - EE);
    atomicAdd(&lc[dst >> 7], 1);
  }
  __syncthreads();
  for (int b = t; b < NBKT; b += 256) {
    int c = lc[b];
    if (c) atomicAdd(&cnt[b], c);
  }
}

__global__ __launch_bounds__(256) void kb_scan(const int* __restrict__ cnt,
                                               int* __restrict__ off,
                                               int* __restrict__ cur) {
  __shared__ int sh[256];
  int t = threadIdx.x;
  int c[4]; int s = 0;
#pragma unroll
  for (int j = 0; j < 4; ++j) {
    int b = t * 4 + j;
    c[j] = s;
    int v = (b < NBKT) ? cnt[b] : 0;
    s += v;
  }
  sh[t] = s; __syncthreads();
  for (int o = 1; o < 256; o <<= 1) {
    int v = (t >= o) ? sh[t - o] : 0;
    __syncthreads();
    sh[t] += v;
    __syncthreads();
  }
  int excl = sh[t] - s;
#pragma unroll
  for (int j = 0; j < 4; ++j) {
    int b = t * 4 + j;
    if (b < NBKT) { off[b] = excl + c[j]; cur[b] = excl + c[j]; }
  }
  if (t == 255) off[NBKT] = excl + s;
}

__global__ __launch_bounds__(256) void kb_scatter(const int* __restrict__ ei,
                                                  int* __restrict__ cur,
                                                  int* __restrict__ buf) {
  __shared__ int lc[NBKT];
  __shared__ int lb[NBKT];
  int t = threadIdx.x;
  for (int b = t; b < NBKT; b += 256) lc[b] = 0;
  __syncthreads();
  int i0 = blockIdx.x * IPB;
  int i1 = min(i0 + IPB, ET);
  for (int i = i0 + t; i < i1; i += 256) {
    int dst = (i < EE) ? ei[EE + i] : (i - EE);
    atomicAdd(&lc[dst >> 7], 1);
  }
  __syncthreads();
  for (int b = t; b < NBKT; b += 256) {
    int c = lc[b];
    lb[b] = c ? atomicAdd(&cur[b], c) : 0;
    lc[b] = 0;
  }
  __syncthreads();
  for (int i = i0 + t; i < i1; i += 256) {
    int src, dst;
    if (i < EE) { src = ei[i]; dst = ei[EE + i]; } else { src = i - EE; dst = src; }
    int b = dst >> 7;
    int l = atomicAdd(&lc[b], 1);
    buf[lb[b] + l] = src | ((dst & 127) << 17);
  }
}

__global__ __launch_bounds__(256) void kb_fin(const int* __restrict__ buf,
                                              const int* __restrict__ off,
                                              int* __restrict__ csr_src,
                                              int* __restrict__ row_ptr) {
  __shared__ int ebuf[BCAP];
  __shared__ int osrc[BCAP];
  __shared__ int cnt[128], scn[128], lcur[128];
  int b = blockIdx.x;
  int base = off[b];
  int count = min(off[b + 1] - base, BCAP);
  int t = threadIdx.x;
  if (t < 128) { cnt[t] = 0; lcur[t] = 0; }
  __syncthreads();
  for (int i = t; i < count; i += 256) {
    int w = buf[base + i];
    ebuf[i] = w;
    atomicAdd(&cnt[(w >> 17) & 127], 1);
  }
  __syncthreads();
  if (t < 128) scn[t] = cnt[t];
  __syncthreads();
  for (int o = 1; o < 128; o <<= 1) {
    int v = 0;
    if (t < 128 && t >= o) v = scn[t - o];
    __syncthreads();
    if (t < 128) scn[t] += v;
    __syncthreads();
  }
  for (int i = t; i < count; i += 256) {
    int w = ebuf[i];
    int d = (w >> 17) & 127;
    int l = atomicAdd(&lcur[d], 1);
    osrc[(scn[d] - cnt[d]) + l] = w & 0x1FFFF;
  }
  __syncthreads();
  for (int i = t; i < count; i += 256) csr_src[base + i] = osrc[i];
  if (t < 128) {
    int gd = b * 128 + t;
    if (gd <= NN) row_ptr[gd] = base + scn[t] - cnt[t];
  }
}

// ---------------- weight fragment precompute ----------------

__global__ __launch_bounds__(256) void k_wconv(const float* __restrict__ encWl,
                                               const float* __restrict__ encWr,
                                               const float* __restrict__ decWl,
                                               const float* __restrict__ decWr,
                                               const float* __restrict__ Wmu,
                                               const float* __restrict__ Wls,
                                               const float* __restrict__ Wout,
                                               unsigned short* __restrict__ wfh,
                                               unsigned short* __restrict__ wfl) {
  int wid = (blockIdx.x * 256 + threadIdx.x) >> 6;
  int lane = threadIdx.x & 63;
  if (wid >= 19 * 32) return;
  int mat = wid >> 5;
  int sub = wid & 31;
  const float* W;
  if (mat < 4) W = encWl + (size_t)mat * 16384;
  else if (mat < 8) W = encWr + (size_t)(mat - 4) * 16384;
  else if (mat < 12) W = decWl + (size_t)(mat - 8) * 16384;
  else if (mat < 16) W = decWr + (size_t)(mat - 12) * 16384;
  else if (mat == 16) W = Wmu;
  else if (mat == 17) W = Wls;
  else W = Wout;
  int t = sub >> 3, c = sub & 7;
  int col = c * 16 + (lane & 15);
  int k0 = t * 32 + (lane >> 4) * 8;
  bf16x8 vh, vl;
#pragma unroll
  for (int j = 0; j < 8; ++j) {
    float w = W[(size_t)(k0 + j) * 128 + col];
    unsigned short h = f2bf(w);
    vh[j] = (short)h;
    vl[j] = (short)f2bf(w - bf2f(h));
  }
  size_t base = ((size_t)wid * 64 + lane) * 8;
  *(bf16x8*)(wfh + base) = vh;
  *(bf16x8*)(wfl + base) = vl;
}

// ---------------- layer dual GEMM: 1-term bf16, 256 rows/block ----------------
// RF32=1: read A from fp32 x (enc layer 0), else bf16 Ah.

template <int RF32>
__global__ __launch_bounds__(512, 2) void k_mmL(const unsigned short* __restrict__ Ah,
                                                const float* __restrict__ Xf,
                                                const unsigned short* __restrict__ w1,
                                                const unsigned short* __restrict__ w2,
                                                unsigned short* __restrict__ o1,
                                                unsigned short* __restrict__ o2) {
  __shared__ float lds[128 * 132];  // 67.6 KB
  unsigned short* lw = (unsigned short*)lds;
  int tid = threadIdx.x;
  {
    int4* d = (int4*)lw;
    const int4* s1 = (const int4*)w1;
    const int4* s2 = (const int4*)w2;
#pragma unroll
    for (int i = 0; i < 4; ++i) {
      d[tid + i * 512] = s1[tid + i * 512];
      d[2048 + tid + i * 512] = s2[tid + i * 512];
    }
  }
  int wv = tid >> 6, lane = tid & 63;
  int lrow = lane & 15, lk = lane >> 4;
  int rbase = blockIdx.x * 256 + wv * 32;

  bf16x8 a_h[2][4];
#pragma unroll
  for (int n = 0; n < 2; ++n) {
    int row = rbase + n * 16 + lrow;
    if (RF32) {
#pragma unroll
      for (int t = 0; t < 4; ++t) {
        float4 f0 = {0.f, 0.f, 0.f, 0.f}, f1 = {0.f, 0.f, 0.f, 0.f};
        if (row < NN) {
          const float* xp = Xf + (size_t)row * 128 + t * 32 + lk * 8;
          f0 = *(const float4*)xp;
          f1 = *(const float4*)(xp + 4);
        }
        bf16x8 v;
        v[0] = (short)f2bf(f0.x); v[1] = (short)f2bf(f0.y);
        v[2] = (short)f2bf(f0.z); v[3] = (short)f2bf(f0.w);
        v[4] = (short)f2bf(f1.x); v[5] = (short)f2bf(f1.y);
        v[6] = (short)f2bf(f1.z); v[7] = (short)f2bf(f1.w);
        a_h[n][t] = v;
      }
    } else {
      const unsigned short* ap = Ah + (size_t)row * 128 + lk * 8;
#pragma unroll
      for (int t = 0; t < 4; ++t) a_h[n][t] = *(const bf16x8*)(ap + t * 32);
    }
  }
  __syncthreads();

  f32x4 acc1[2][8], acc2[2][8];
#pragma unroll
  for (int n = 0; n < 2; ++n)
#pragma unroll
    for (int c = 0; c < 8; ++c) {
      acc1[n][c] = (f32x4){0.f, 0.f, 0.f, 0.f};
      acc2[n][c] = (f32x4){0.f, 0.f, 0.f, 0.f};
    }
#pragma unroll
  for (int t = 0; t < 4; ++t) {
#pragma unroll
    for (int c = 0; c < 8; ++c) {
      int fo = ((t * 8 + c) * 64 + lane) * 8;
      bf16x8 wf1 = *(const bf16x8*)(lw + fo);
      bf16x8 wf2 = *(const bf16x8*)(lw + 16384 + fo);
#pragma unroll
      for (int n = 0; n < 2; ++n) {
        acc1[n][c] = __builtin_amdgcn_mfma_f32_16x16x32_bf16(a_h[n][t], wf1, acc1[n][c], 0, 0, 0);
        acc2[n][c] = __builtin_amdgcn_mfma_f32_16x16x32_bf16(a_h[n][t], wf2, acc2[n][c], 0, 0, 0);
      }
    }
  }
  __syncthreads();  // weights dead; LDS = 128x132 transpose buffer

  int lr = tid >> 2, cb = (tid & 3) << 5;
#pragma unroll
  for (int h = 0; h < 2; ++h) {
#pragma unroll
    for (int out = 0; out < 2; ++out) {
      if ((wv >> 2) == h) {
        int lrb = (wv & 3) * 32;
#pragma unroll
        for (int n = 0; n < 2; ++n)
#pragma unroll
          for (int c = 0; c < 8; ++c)
#pragma unroll
            for (int r = 0; r < 4; ++r)
              lds[(lrb + n * 16 + lk * 4 + r) * 132 + c * 16 + lrow] =
                  out ? acc2[n][c][r] : acc1[n][c][r];
      }
      __syncthreads();
      {
        unsigned short* dst = out ? o2 : o1;
        size_t o = ((size_t)blockIdx.x * 256 + h * 128 + lr) * 128 + cb;
        const float* sp = &lds[lr * 132 + cb];
#pragma unroll
        for (int i = 0; i < 4; ++i) {
          union { unsigned short u[8]; int4 v; } pk;
#pragma unroll
          for (int j = 0; j < 8; ++j) pk.u[j] = f2bf(sp[i * 8 + j]);
          *(int4*)&dst[o + i * 8] = pk.v;
        }
      }
      __syncthreads();
    }
  }
}

// ---------------- head kernel: mu, logstd, z, z-stage(hi), degree pred ----------------

__global__ __launch_bounds__(512, 3) void k_mmH(const unsigned short* Ah,
                                                const unsigned short* Al,
                                                const unsigned short* __restrict__ w1h,
                                                const unsigned short* __restrict__ w1l,
                                                const unsigned short* __restrict__ w2h,
                                                const unsigned short* __restrict__ w2l,
                                                const float* __restrict__ b1,
                                                const float* __restrict__ b2,
                                                const float* __restrict__ eps,
                                                const float* __restrict__ Wd,
                                                const float* __restrict__ bd,
                                                float* __restrict__ mu,
                                                float* __restrict__ logstd,
                                                float* __restrict__ Z,
                                                unsigned short* Zh,
                                                float* __restrict__ degp) {
  __shared__ float lds[128 * 132];
  unsigned short* lw = (unsigned short*)lds;
  int tid = threadIdx.x;
  int wv = tid >> 6, lane = tid & 63;
  int lrow = lane & 15, lk = lane >> 4;
  int rbase = blockIdx.x * 128 + wv * 16;

  {
    int4* d = (int4*)lw;
#pragma unroll
    for (int i = 0; i < 4; ++i) {
      d[tid + i * 512] = ((const int4*)w1h)[tid + i * 512];
      d[2048 + tid + i * 512] = ((const int4*)w1l)[tid + i * 512];
    }
  }
  bf16x8 a_h[4], a_l[4];
  const unsigned short* ap = Ah + (size_t)(rbase + lrow) * 128 + lk * 8;
  const unsigned short* alp = Al + (size_t)(rbase + lrow) * 128 + lk * 8;
#pragma unroll
  for (int t = 0; t < 4; ++t) {
    a_h[t] = *(const bf16x8*)(ap + t * 32);
    a_l[t] = *(const bf16x8*)(alp + t * 32);
  }
  __syncthreads();

  f32x4 acc1[8];
#pragma unroll
  for (int c = 0; c < 8; ++c) acc1[c] = (f32x4){0.f, 0.f, 0.f, 0.f};
#pragma unroll
  for (int t = 0; t < 4; ++t) {
#pragma unroll
    for (int c = 0; c < 8; ++c) {
      int fo = ((t * 8 + c) * 64 + lane) * 8;
      bf16x8 wh = *(const bf16x8*)(lw + fo);
      bf16x8 wl = *(const bf16x8*)(lw + 16384 + fo);
      acc1[c] = __builtin_amdgcn_mfma_f32_16x16x32_bf16(a_h[t], wh, acc1[c], 0, 0, 0);
      acc1[c] = __builtin_amdgcn_mfma_f32_16x16x32_bf16(a_l[t], wh, acc1[c], 0, 0, 0);
      acc1[c] = __builtin_amdgcn_mfma_f32_16x16x32_bf16(a_h[t], wl, acc1[c], 0, 0, 0);
    }
  }
  __syncthreads();

  {
    int4* d = (int4*)lw;
#pragma unroll
    for (int i = 0; i < 4; ++i) {
      d[tid + i * 512] = ((const int4*)w2h)[tid + i * 512];
      d[2048 + tid + i * 512] = ((const int4*)w2l)[tid + i * 512];
    }
  }
  __syncthreads();

  f32x4 acc2[8];
#pragma unroll
  for (int c = 0; c < 8; ++c) acc2[c] = (f32x4){0.f, 0.f, 0.f, 0.f};
#pragma unroll
  for (int t = 0; t < 4; ++t) {
#pragma unroll
    for (int c = 0; c < 8; ++c) {
      int fo = ((t * 8 + c) * 64 + lane) * 8;
      bf16x8 wh = *(const bf16x8*)(lw + fo);
      bf16x8 wl = *(const bf16x8*)(lw + 16384 + fo);
      acc2[c] = __builtin_amdgcn_mfma_f32_16x16x32_bf16(a_h[t], wh, acc2[c], 0, 0, 0);
      acc2[c] = __builtin_amdgcn_mfma_f32_16x16x32_bf16(a_l[t], wh, acc2[c], 0, 0, 0);
      acc2[c] = __builtin_amdgcn_mfma_f32_16x16x32_bf16(a_h[t], wl, acc2[c], 0, 0, 0);
    }
  }
  __syncthreads();

  int lr = tid >> 2, cb = (tid & 3) << 5;
  int grow = blockIdx.x * 128 + lr;
  size_t o = (size_t)grow * 128 + cb;

#pragma unroll
  for (int c = 0; c < 8; ++c)
#pragma unroll
    for (int r = 0; r < 4; ++r)
      lds[(wv * 16 + lk * 4 + r) * 132 + c * 16 + lrow] = acc1[c][r];
  __syncthreads();
  float4 mureg[8];
  if (grow < NN) {
    const float* sp = &lds[lr * 132 + cb];
#pragma unroll
    for (int i = 0; i < 8; ++i) {
      float4 v = *(const float4*)(sp + i * 4);
      float4 b4 = *(const float4*)&b1[cb + i * 4];
      v.x += b4.x; v.y += b4.y; v.z += b4.z; v.w += b4.w;
      mureg[i] = v;
      *(float4*)&mu[o + i * 4] = v;
    }
  }
  __syncthreads();
#pragma unroll
  for (int c = 0; c < 8; ++c)
#pragma unroll
    for (int r = 0; r < 4; ++r)
      lds[(wv * 16 + lk * 4 + r) * 132 + c * 16 + lrow] = acc2[c][r];
  __syncthreads();
  float s_deg = 0.f;
  if (grow < NN) {
    const float* sp = &lds[lr * 132 + cb];
#pragma unroll
    for (int i = 0; i < 8; ++i) {
      float4 v = *(const float4*)(sp + i * 4);
      float4 b4 = *(const float4*)&b2[cb + i * 4];
      float4 ls;
      ls.x = fminf(v.x + b4.x, 10.f);
      ls.y = fminf(v.y + b4.y, 10.f);
      ls.z = fminf(v.z + b4.z, 10.f);
      ls.w = fminf(v.w + b4.w, 10.f);
      *(float4*)&logstd[o + i * 4] = ls;
      float4 e4 = *(const float4*)&eps[o + i * 4];
      float4 z4;
      z4.x = fmaf(e4.x, expf(ls.x), mureg[i].x);
      z4.y = fmaf(e4.y, expf(ls.y), mureg[i].y);
      z4.z = fmaf(e4.z, expf(ls.z), mureg[i].z);
      z4.w = fmaf(e4.w, expf(ls.w), mureg[i].w);
      *(float4*)&Z[o + i * 4] = z4;
      ushort4 hh;
      hh.x = f2bf(z4.x); hh.y = f2bf(z4.y); hh.z = f2bf(z4.z); hh.w = f2bf(z4.w);
      *(ushort4*)&Zh[o + i * 4] = hh;
      float4 wd = *(const float4*)&Wd[cb + i * 4];
      s_deg += z4.x * wd.x + z4.y * wd.y + z4.z * wd.z + z4.w * wd.w;
    }
  }
  s_deg += __shfl_xor(s_deg, 1);
  s_deg += __shfl_xor(s_deg, 2);
  if (grow < NN && (tid & 3) == 0) degp[grow] = s_deg + bd[0];
}

// ---------------- output GEMM: x_rec = A_h@(Wh+Wl) + b, fp32 out ----------------

__global__ __launch_bounds__(512, 4) void k_mmO(const unsigned short* __restrict__ Ah,
                                                const unsigned short* __restrict__ wh,
                                                const unsigned short* __restrict__ wl,
                                                const float* __restrict__ bias,
                                                float* __restrict__ C) {
  __shared__ float lds[128 * 132];
  unsigned short* lw = (unsigned short*)lds;
  int tid = threadIdx.x;
  {
    int4* d = (int4*)lw;
#pragma unroll
    for (int i = 0; i < 4; ++i) {
      d[tid + i * 512] = ((const int4*)wh)[tid + i * 512];
      d[2048 + tid + i * 512] = ((const int4*)wl)[tid + i * 512];
    }
  }
  int wv = tid >> 6, lane = tid & 63;
  int lrow = lane & 15, lk = lane >> 4;
  int rbase = blockIdx.x * 128 + wv * 16;

  bf16x8 a_h[4];
  const unsigned short* ap = Ah + (size_t)(rbase + lrow) * 128 + lk * 8;
#pragma unroll
  for (int t = 0; t < 4; ++t) a_h[t] = *(const bf16x8*)(ap + t * 32);
  __syncthreads();

  f32x4 acc[8];
#pragma unroll
  for (int c = 0; c < 8; ++c) acc[c] = (f32x4){0.f, 0.f, 0.f, 0.f};
#pragma unroll
  for (int t = 0; t < 4; ++t) {
#pragma unroll
    for (int c = 0; c < 8; ++c) {
      int fo = ((t * 8 + c) * 64 + lane) * 8;
      bf16x8 whf = *(const bf16x8*)(lw + fo);
      bf16x8 wlf = *(const bf16x8*)(lw + 16384 + fo);
      acc[c] = __builtin_amdgcn_mfma_f32_16x16x32_bf16(a_h[t], whf, acc[c], 0, 0, 0);
      acc[c] = __builtin_amdgcn_mfma_f32_16x16x32_bf16(a_h[t], wlf, acc[c], 0, 0, 0);
    }
  }
  __syncthreads();

#pragma unroll
  for (int c = 0; c < 8; ++c)
#pragma unroll
    for (int r = 0; r < 4; ++r)
      lds[(wv * 16 + lk * 4 + r) * 132 + c * 16 + lrow] = acc[c][r];
  __syncthreads();
  int lr = tid >> 2, cb = (tid & 3) << 5;
  int grow = blockIdx.x * 128 + lr;
  if (grow < NN) {
    size_t o = (size_t)grow * 128 + cb;
    const float* sp = &lds[lr * 132 + cb];
#pragma unroll
    for (int i = 0; i < 8; ++i) {
      float4 v = *(const float4*)(sp + i * 4);
      float4 b4 = *(const float4*)&bias[cb + i * 4];
      v.x += b4.x; v.y += b4.y; v.z += b4.z; v.w += b4.w;
      *(float4*)&C[o + i * 4] = v;
    }
  }
}

// ---------------- GATv2 aggregation: wave/row, 4x16 lanes, 2-edge batches ----------------

template <int WLO>
__global__ __launch_bounds__(256) void k_gat_agg(const unsigned short* __restrict__ gxl,
                                                 const unsigned short* __restrict__ gxr,
                                                 const float* __restrict__ att,
                                                 const float* __restrict__ bias,
                                                 const int* __restrict__ row_ptr,
                                                 const int* __restrict__ csr_src,
                                                 unsigned short* __restrict__ sh,
                                                 unsigned short* __restrict__ sl) {
  int gid = blockIdx.x * blockDim.x + threadIdx.x;
  int row = gid >> 6;
  int lane = gid & 63;
  if (row >= NN) return;
  int g = lane >> 4, j = lane & 15;
  int dbase = j * 8;

  float a[8], r[8];
  {
    float4 a0 = *(const float4*)&att[dbase];
    float4 a1 = *(const float4*)&att[dbase + 4];
    a[0] = a0.x; a[1] = a0.y; a[2] = a0.z; a[3] = a0.w;
    a[4] = a1.x; a[5] = a1.y; a[6] = a1.z; a[7] = a1.w;
    bf16x8 rv = *(const bf16x8*)&gxr[(size_t)row * 128 + dbase];
#pragma unroll
    for (int k = 0; k < 8; ++k) r[k] = bf2f((unsigned short)rv[k]);
  }

  float m = -INFINITY, d = 0.f;
  float acc[8] = {0.f, 0.f, 0.f, 0.f, 0.f, 0.f, 0.f, 0.f};
  int p0 = row_ptr[row], p1 = row_ptr[row + 1];

  for (int p = p0 + g; p < p1; p += 8) {
    int pb = p + 4;
    bool hb = pb < p1;
    int sa = csr_src[p];
    int sb = csr_src[hb ? pb : p];
    bf16x8 xa = *(const bf16x8*)&gxl[(size_t)sa * 128 + dbase];
    bf16x8 xb = *(const bf16x8*)&gxl[(size_t)sb * 128 + dbase];
    float va[8], vb[8];
#pragma unroll
    for (int k = 0; k < 8; ++k) {
      va[k] = bf2f((unsigned short)xa[k]);
      vb[k] = bf2f((unsigned short)xb[k]);
    }
    float ea = 0.f, eb = 0.f;
#pragma unroll
    for (int k = 0; k < 8; ++k) {
      float ta = va[k] + r[k];
      ta = fmaxf(ta, 0.2f * ta);
      ea = fmaf(ta, a[k], ea);
      float tb = vb[k] + r[k];
      tb = fmaxf(tb, 0.2f * tb);
      eb = fmaf(tb, a[k], eb);
    }
    ea += __shfl_xor(ea, 1);
    eb += __shfl_xor(eb, 1);
    ea += __shfl_xor(ea, 2);
    eb += __shfl_xor(eb, 2);
    ea += __shfl_xor(ea, 4);
    eb += __shfl_xor(eb, 4);
    ea += __shfl_xor(ea, 8);
    eb += __shfl_xor(eb, 8);
    if (!hb) eb = -INFINITY;

    float mn = fmaxf(m, fmaxf(ea, eb));
    float scl = __expf(m - mn);
    float wa = __expf(ea - mn);
    float wb = __expf(eb - mn);
    d = d * scl + wa + wb;
#pragma unroll
    for (int k = 0; k < 8; ++k)
      acc[k] = fmaf(acc[k], scl, fmaf(wa, va[k], wb * vb[k]));
    m = mn;
  }

  float mo = fmaxf(m, __shfl_xor(m, 16));
  mo = fmaxf(mo, __shfl_xor(mo, 32));
  float scl = __expf(m - mo);
  d *= scl;
  d += __shfl_xor(d, 16);
  d += __shfl_xor(d, 32);
#pragma unroll
  for (int k = 0; k < 8; ++k) {
    acc[k] *= scl;
    acc[k] += __shfl_xor(acc[k], 16);
    acc[k] += __shfl_xor(acc[k], 32);
  }

  if (g == 0) {
    float inv = 1.f / d;
    float4 b0 = *(const float4*)&bias[dbase];
    float4 b1v = *(const float4*)&bias[dbase + 4];
    float bb[8] = {b0.x, b0.y, b0.z, b0.w, b1v.x, b1v.y, b1v.z, b1v.w};
    bf16x8 vh, vl;
#pragma unroll
    for (int k = 0; k < 8; ++k) {
      float h = gelu_exact(acc[k] * inv + bb[k]);
      unsigned short hi = f2bf(h);
      vh[k] = (short)hi;
      if (WLO) vl[k] = (short)f2bf(h - bf2f(hi));
    }
    *(bf16x8*)(sh + (size_t)row * 128 + dbase) = vh;
    if (WLO) *(bf16x8*)(sl + (size_t)row * 128 + dbase) = vl;
  }
}

// ---------------- host ----------------

static inline char* take(char*& p, size_t bytes) {
  char* r = p;
  p += (bytes + 255) & ~(size_t)255;
  return r;
}

extern "C" void kernel_launch(void* const* d_in, const int* in_sizes, int n_in,
                              void* d_out, int out_size, void* d_ws, size_t ws_size,
                              hipStream_t stream) {
  const float* x      = (const float*)d_in[0];
  const int*   ei     = (const int*)d_in[1];
  const float* eps    = (const float*)d_in[2];
  const float* encWl  = (const float*)d_in[3];
  const float* encWr  = (const float*)d_in[4];
  const float* encAtt = (const float*)d_in[5];
  const float* encB   = (const float*)d_in[6];
  const float* decWl  = (const float*)d_in[7];
  const float* decWr  = (const float*)d_in[8];
  const float* decAtt = (const float*)d_in[9];
  const float* decB   = (const float*)d_in[10];
  const float* W_mu   = (const float*)d_in[11];
  const float* b_mu   = (const float*)d_in[12];
  const float* W_ls   = (const float*)d_in[13];
  const float* b_ls   = (const float*)d_in[14];
  const float* W_out  = (const float*)d_in[15];
  const float* b_out  = (const float*)d_in[16];
  const float* W_deg  = (const float*)d_in[17];
  const float* b_deg  = (const float*)d_in[18];

  float* out    = (float*)d_out;
  float* x_rec  = out;
  float* z      = out + (size_t)ND;
  float* mu     = out + (size_t)2 * ND;
  float* logstd = out + (size_t)3 * ND;
  float* degp   = out + (size_t)4 * ND;

  char* p = (char*)d_ws;
  int* bktcnt  = (int*)take(p, 1024 * 4);
  int* bktoff  = (int*)take(p, 1024 * 4);
  int* bktcur  = (int*)take(p, 1024 * 4);
  int* ebuf_g  = (int*)take(p, (size_t)ET * 4);
  int* row_ptr = (int*)take(p, (size_t)(NN + 1) * 4);
  int* csr_src = (int*)take(p, (size_t)ET * 4);
  unsigned short* gxl  = (unsigned short*)take(p, (size_t)MPAD * 128 * 2);
  unsigned short* gxr  = (unsigned short*)take(p, (size_t)MPAD * 128 * 2);
  unsigned short* stgh = (unsigned short*)take(p, (size_t)MPAD * 128 * 2);
  unsigned short* stgl = (unsigned short*)take(p, (size_t)MPAD * 128 * 2);
  unsigned short* wfh  = (unsigned short*)take(p, (size_t)19 * 16384 * 2);
  unsigned short* wfl  = (unsigned short*)take(p, (size_t)19 * 16384 * 2);

  const int gMML  = MPAD / 256;                   // 391
  const int gMM   = MPAD / 128;                   // 782
  const int gWave = (NN * 64 + 255) / 256;        // 25000

  // CSR build
  k_zero_int<<<4, 256, 0, stream>>>(bktcnt, 1024);
  kb_hist<<<GSC, 256, 0, stream>>>(ei, bktcnt);
  kb_scan<<<1, 256, 0, stream>>>(bktcnt, bktoff, bktcur);
  kb_scatter<<<GSC, 256, 0, stream>>>(ei, bktcur, ebuf_g);
  kb_fin<<<NBKT, 256, 0, stream>>>(ebuf_g, bktoff, csr_src, row_ptr);

  // weight frags
  k_wconv<<<152, 256, 0, stream>>>(encWl, encWr, decWl, decWr, W_mu, W_ls, W_out, wfh, wfl);

  const size_t WM = 16384;
  // encoder (layer 0 reads x fp32 directly)
  for (int l = 0; l < 4; ++l) {
    if (l == 0)
      k_mmL<1><<<gMML, 512, 0, stream>>>(nullptr, x,
                                         wfh + (size_t)l * WM, wfh + (size_t)(4 + l) * WM,
                                         gxl, gxr);
    else
      k_mmL<0><<<gMML, 512, 0, stream>>>(stgh, nullptr,
                                         wfh + (size_t)l * WM, wfh + (size_t)(4 + l) * WM,
                                         gxl, gxr);
    if (l < 3)
      k_gat_agg<0><<<gWave, 256, 0, stream>>>(gxl, gxr, encAtt + (size_t)l * DD,
                                              encB + (size_t)l * DD, row_ptr, csr_src,
                                              stgh, stgl);
    else
      k_gat_agg<1><<<gWave, 256, 0, stream>>>(gxl, gxr, encAtt + (size_t)l * DD,
                                              encB + (size_t)l * DD, row_ptr, csr_src,
                                              stgh, stgl);
  }

  // heads
  k_mmH<<<gMM, 512, 0, stream>>>(stgh, stgl,
                                 wfh + (size_t)16 * WM, wfl + (size_t)16 * WM,
                                 wfh + (size_t)17 * WM, wfl + (size_t)17 * WM,
                                 b_mu, b_ls, eps, W_deg, b_deg,
                                 mu, logstd, z, stgh, degp);

  // decoder
  for (int l = 0; l < 4; ++l) {
    k_mmL<0><<<gMML, 512, 0, stream>>>(stgh, nullptr,
                                       wfh + (size_t)(8 + l) * WM, wfh + (size_t)(12 + l) * WM,
                                       gxl, gxr);
    k_gat_agg<0><<<gWave, 256, 0, stream>>>(gxl, gxr, decAtt + (size_t)l * DD,
                                            decB + (size_t)l * DD, row_ptr, csr_src,
                                            stgh, stgl);
  }

  // x_rec (A-hi only, 2-term W)
  k_mmO<<<gMM, 512, 0, stream>>>(stgh,
                                 wfh + (size_t)18 * WM, wfl + (size_t)18 * WM,
                                 b_out, x_rec);
}

// Round 11
// 1375.350 us; speedup vs baseline: 1.0457x; 1.0457x over previous
//
#include <hip/hip_runtime.h>
#include <math.h>

#define NN 100000
#define MPAD 100096
#define DD 128
#define EE 1600000
#define ET (EE + NN)
#define ND (NN * DD)

#define NBKT 782
#define IPB 16384
#define GSC 104
#define BCAP 6144

typedef short bf16x8 __attribute__((ext_vector_type(8)));
typedef float f32x4 __attribute__((ext_vector_type(4)));

static __device__ __forceinline__ unsigned short f2bf(float f) {
  unsigned int u = __float_as_uint(f);
  u += 0x7FFFu + ((u >> 16) & 1u);
  return (unsigned short)(u >> 16);
}
static __device__ __forceinline__ float bf2f(unsigned short h) {
  return __uint_as_float(((unsigned int)h) << 16);
}
static __device__ __forceinline__ float gelu_exact(float v) {
  return 0.5f * v * (1.f + erff(v * 0.7071067811865476f));
}

// ---------------- CSR build: bucketed counting sort ----------------

__global__ void k_zero_int(int* __restrict__ p, int n) {
  int i = blockIdx.x * blockDim.x + threadIdx.x;
  if (i < n) p[i] = 0;
}

__global__ __launch_bounds__(256) void kb_hist(const int* __restrict__ ei,
                                               int* __restrict__ cnt) {
  __shared__ int lc[NBKT];
  int t = threadIdx.x;
  for (int b = t; b < NBKT; b += 256) lc[b] = 0;
  __syncthreads();
  int i0 = blockIdx.x * IPB;
  int i1 = min(i0 + IPB, ET);
  for (int i = i0 + t; i < i1; i += 256) {
    int dst = (i < EE) ? ei[EE + i] : (i - EE);
    atomicAdd(&lc[dst >> 7], 1);
  }
  __syncthreads();
  for (int b = t; b < NBKT; b += 256) {
    int c = lc[b];
    if (c) atomicAdd(&cnt[b], c);
  }
}

__global__ __launch_bounds__(256) void kb_scan(const int* __restrict__ cnt,
                                               int* __restrict__ off,
                                               int* __restrict__ cur) {
  __shared__ int sh[256];
  int t = threadIdx.x;
  int c[4]; int s = 0;
#pragma unroll
  for (int j = 0; j < 4; ++j) {
    int b = t * 4 + j;
    c[j] = s;
    int v = (b < NBKT) ? cnt[b] : 0;
    s += v;
  }
  sh[t] = s; __syncthreads();
  for (int o = 1; o < 256; o <<= 1) {
    int v = (t >= o) ? sh[t - o] : 0;
    __syncthreads();
    sh[t] += v;
    __syncthreads();
  }
  int excl = sh[t] - s;
#pragma unroll
  for (int j = 0; j < 4; ++j) {
    int b = t * 4 + j;
    if (b < NBKT) { off[b] = excl + c[j]; cur[b] = excl + c[j]; }
  }
  if (t == 255) off[NBKT] = excl + s;
}

__global__ __launch_bounds__(256) void kb_scatter(const int* __restrict__ ei,
                                                  int* __restrict__ cur,
                                                  int* __restrict__ buf) {
  __shared__ int lc[NBKT];
  __shared__ int lb[NBKT];
  int t = threadIdx.x;
  for (int b = t; b < NBKT; b += 256) lc[b] = 0;
  __syncthreads();
  int i0 = blockIdx.x * IPB;
  int i1 = min(i0 + IPB, ET);
  for (int i = i0 + t; i < i1; i += 256) {
    int dst = (i < EE) ? ei[EE + i] : (i - EE);
    atomicAdd(&lc[dst >> 7], 1);
  }
  __syncthreads();
  for (int b = t; b < NBKT; b += 256) {
    int c = lc[b];
    lb[b] = c ? atomicAdd(&cur[b], c) : 0;
    lc[b] = 0;
  }
  __syncthreads();
  for (int i = i0 + t; i < i1; i += 256) {
    int src, dst;
    if (i < EE) { src = ei[i]; dst = ei[EE + i]; } else { src = i - EE; dst = src; }
    int b = dst >> 7;
    int l = atomicAdd(&lc[b], 1);
    buf[lb[b] + l] = src | ((dst & 127) << 17);
  }
}

__global__ __launch_bounds__(256) void kb_fin(const int* __restrict__ buf,
                                              const int* __restrict__ off,
                                              int* __restrict__ csr_src,
                                              int* __restrict__ row_ptr) {
  __shared__ int ebuf[BCAP];
  __shared__ int osrc[BCAP];
  __shared__ int cnt[128], scn[128], lcur[128];
  int b = blockIdx.x;
  int base = off[b];
  int count = min(off[b + 1] - base, BCAP);
  int t = threadIdx.x;
  if (t < 128) { cnt[t] = 0; lcur[t] = 0; }
  __syncthreads();
  for (int i = t; i < count; i += 256) {
    int w = buf[base + i];
    ebuf[i] = w;
    atomicAdd(&cnt[(w >> 17) & 127], 1);
  }
  __syncthreads();
  if (t < 128) scn[t] = cnt[t];
  __syncthreads();
  for (int o = 1; o < 128; o <<= 1) {
    int v = 0;
    if (t < 128 && t >= o) v = scn[t - o];
    __syncthreads();
    if (t < 128) scn[t] += v;
    __syncthreads();
  }
  for (int i = t; i < count; i += 256) {
    int w = ebuf[i];
    int d = (w >> 17) & 127;
    int l = atomicAdd(&lcur[d], 1);
    osrc[(scn[d] - cnt[d]) + l] = w & 0x1FFFF;
  }
  __syncthreads();
  for (int i = t; i < count; i += 256) csr_src[base + i] = osrc[i];
  if (t < 128) {
    int gd = b * 128 + t;
    if (gd <= NN) row_ptr[gd] = base + scn[t] - cnt[t];
  }
}

// ---------------- weight fragment precompute ----------------

__global__ __launch_bounds__(256) void k_wconv(const float* __restrict__ encWl,
                                               const float* __restrict__ encWr,
                                               const float* __restrict__ decWl,
                                               const float* __restrict__ decWr,
                                               const float* __restrict__ Wmu,
                                               const float* __restrict__ Wls,
                                               const float* __restrict__ Wout,
                                               unsigned short* __restrict__ wfh,
                                               unsigned short* __restrict__ wfl) {
  int wid = (blockIdx.x * 256 + threadIdx.x) >> 6;
  int lane = threadIdx.x & 63;
  if (wid >= 19 * 32) return;
  int mat = wid >> 5;
  int sub = wid & 31;
  const float* W;
  if (mat < 4) W = encWl + (size_t)mat * 16384;
  else if (mat < 8) W = encWr + (size_t)(mat - 4) * 16384;
  else if (mat < 12) W = decWl + (size_t)(mat - 8) * 16384;
  else if (mat < 16) W = decWr + (size_t)(mat - 12) * 16384;
  else if (mat == 16) W = Wmu;
  else if (mat == 17) W = Wls;
  else W = Wout;
  int t = sub >> 3, c = sub & 7;
  int col = c * 16 + (lane & 15);
  int k0 = t * 32 + (lane >> 4) * 8;
  bf16x8 vh, vl;
#pragma unroll
  for (int j = 0; j < 8; ++j) {
    float w = W[(size_t)(k0 + j) * 128 + col];
    unsigned short h = f2bf(w);
    vh[j] = (short)h;
    vl[j] = (short)f2bf(w - bf2f(h));
  }
  size_t base = ((size_t)wid * 64 + lane) * 8;
  *(bf16x8*)(wfh + base) = vh;
  *(bf16x8*)(wfl + base) = vl;
}

// ---------------- x -> bf16 stage (hi only) ----------------

__global__ void k_xconv(const float* __restrict__ x, unsigned short* __restrict__ sh) {
  int i = blockIdx.x * blockDim.x + threadIdx.x;
  if (i >= MPAD * 128 / 8) return;
  size_t base = (size_t)i * 8;
  float v[8];
  if (base < (size_t)ND) {
    float4 f0 = *(const float4*)(x + base);
    float4 f1 = *(const float4*)(x + base + 4);
    v[0] = f0.x; v[1] = f0.y; v[2] = f0.z; v[3] = f0.w;
    v[4] = f1.x; v[5] = f1.y; v[6] = f1.z; v[7] = f1.w;
  } else {
#pragma unroll
    for (int j = 0; j < 8; ++j) v[j] = 0.f;
  }
  bf16x8 vh;
#pragma unroll
  for (int j = 0; j < 8; ++j) vh[j] = (short)f2bf(v[j]);
  *(bf16x8*)(sh + base) = vh;
}

// ---------------- layer dual GEMM: 1-term bf16, bf16 out (r9 structure) ----------------

__global__ __launch_bounds__(512, 4) void k_mmL(const unsigned short* __restrict__ Ah,
                                                const unsigned short* __restrict__ w1,
                                                const unsigned short* __restrict__ w2,
                                                unsigned short* __restrict__ o1,
                                                unsigned short* __restrict__ o2) {
  __shared__ float lds[128 * 132];  // 67.6 KB
  unsigned short* lw = (unsigned short*)lds;
  int tid = threadIdx.x;
  {
    int4* d = (int4*)lw;
    const int4* s1 = (const int4*)w1;
    const int4* s2 = (const int4*)w2;
#pragma unroll
    for (int i = 0; i < 4; ++i) {
      d[tid + i * 512] = s1[tid + i * 512];
      d[2048 + tid + i * 512] = s2[tid + i * 512];
    }
  }
  int wv = tid >> 6, lane = tid & 63;
  int lrow = lane & 15, lk = lane >> 4;
  int rbase = blockIdx.x * 128 + wv * 16;

  bf16x8 a_h[4];
  const unsigned short* ap = Ah + (size_t)(rbase + lrow) * 128 + lk * 8;
#pragma unroll
  for (int t = 0; t < 4; ++t) a_h[t] = *(const bf16x8*)(ap + t * 32);
  __syncthreads();

  f32x4 acc1[8], acc2[8];
#pragma unroll
  for (int c = 0; c < 8; ++c) {
    acc1[c] = (f32x4){0.f, 0.f, 0.f, 0.f};
    acc2[c] = (f32x4){0.f, 0.f, 0.f, 0.f};
  }
#pragma unroll
  for (int t = 0; t < 4; ++t) {
#pragma unroll
    for (int c = 0; c < 8; ++c) {
      int fo = ((t * 8 + c) * 64 + lane) * 8;
      bf16x8 wf1 = *(const bf16x8*)(lw + fo);
      bf16x8 wf2 = *(const bf16x8*)(lw + 16384 + fo);
      acc1[c] = __builtin_amdgcn_mfma_f32_16x16x32_bf16(a_h[t], wf1, acc1[c], 0, 0, 0);
      acc2[c] = __builtin_amdgcn_mfma_f32_16x16x32_bf16(a_h[t], wf2, acc2[c], 0, 0, 0);
    }
  }
  __syncthreads();  // weights dead; LDS becomes transpose buffer

  int lr = tid >> 2, cb = (tid & 3) << 5;
  size_t o = ((size_t)blockIdx.x * 128 + lr) * 128 + cb;

#pragma unroll
  for (int out = 0; out < 2; ++out) {
#pragma unroll
    for (int c = 0; c < 8; ++c)
#pragma unroll
      for (int r = 0; r < 4; ++r)
        lds[(wv * 16 + lk * 4 + r) * 132 + c * 16 + lrow] = out ? acc2[c][r] : acc1[c][r];
    __syncthreads();
    {
      unsigned short* dst = out ? o2 : o1;
      const float* sp = &lds[lr * 132 + cb];
#pragma unroll
      for (int i = 0; i < 4; ++i) {
        union { unsigned short u[8]; int4 v; } pk;
#pragma unroll
        for (int j = 0; j < 8; ++j) pk.u[j] = f2bf(sp[i * 8 + j]);
        *(int4*)&dst[o + i * 8] = pk.v;
      }
    }
    __syncthreads();
  }
}

// ---------------- head kernel: 384 thr / 96-row blocks (tail-balanced) ----------------
// 3-term split both GEMMs; sequential weight staging (64 KB); mu via LDS.

__global__ __launch_bounds__(384, 3) void k_mmH(const unsigned short* Ah,
                                                const unsigned short* Al,
                                                const unsigned short* __restrict__ w1h,
                                                const unsigned short* __restrict__ w1l,
                                                const unsigned short* __restrict__ w2h,
                                                const unsigned short* __restrict__ w2l,
                                                const float* __restrict__ b1,
                                                const float* __restrict__ b2,
                                                const float* __restrict__ eps,
                                                const float* __restrict__ Wd,
                                                const float* __restrict__ bd,
                                                float* __restrict__ mu,
                                                float* __restrict__ logstd,
                                                float* __restrict__ Z,
                                                unsigned short* Zh,
                                                float* __restrict__ degp) {
  __shared__ float lds[128 * 132];  // weights 64 KB; transpose uses 96x132 f32
  unsigned short* lw = (unsigned short*)lds;
  int tid = threadIdx.x;
  int wv = tid >> 6, lane = tid & 63;
  int lrow = lane & 15, lk = lane >> 4;
  int rbase = blockIdx.x * 96 + wv * 16;

  {
    int4* d = (int4*)lw;
    const int4* s1 = (const int4*)w1h;
    const int4* s2 = (const int4*)w1l;
    for (int i = tid; i < 2048; i += 384) {
      d[i] = s1[i];
      d[2048 + i] = s2[i];
    }
  }
  bf16x8 a_h[4], a_l[4];
  const unsigned short* ap = Ah + (size_t)(rbase + lrow) * 128 + lk * 8;
  const unsigned short* alp = Al + (size_t)(rbase + lrow) * 128 + lk * 8;
#pragma unroll
  for (int t = 0; t < 4; ++t) {
    a_h[t] = *(const bf16x8*)(ap + t * 32);
    a_l[t] = *(const bf16x8*)(alp + t * 32);
  }
  __syncthreads();

  f32x4 acc1[8];
#pragma unroll
  for (int c = 0; c < 8; ++c) acc1[c] = (f32x4){0.f, 0.f, 0.f, 0.f};
#pragma unroll
  for (int t = 0; t < 4; ++t) {
#pragma unroll
    for (int c = 0; c < 8; ++c) {
      int fo = ((t * 8 + c) * 64 + lane) * 8;
      bf16x8 wh = *(const bf16x8*)(lw + fo);
      bf16x8 wl = *(const bf16x8*)(lw + 16384 + fo);
      acc1[c] = __builtin_amdgcn_mfma_f32_16x16x32_bf16(a_h[t], wh, acc1[c], 0, 0, 0);
      acc1[c] = __builtin_amdgcn_mfma_f32_16x16x32_bf16(a_l[t], wh, acc1[c], 0, 0, 0);
      acc1[c] = __builtin_amdgcn_mfma_f32_16x16x32_bf16(a_h[t], wl, acc1[c], 0, 0, 0);
    }
  }
  __syncthreads();

  {
    int4* d = (int4*)lw;
    const int4* s1 = (const int4*)w2h;
    const int4* s2 = (const int4*)w2l;
    for (int i = tid; i < 2048; i += 384) {
      d[i] = s1[i];
      d[2048 + i] = s2[i];
    }
  }
  __syncthreads();

  f32x4 acc2[8];
#pragma unroll
  for (int c = 0; c < 8; ++c) acc2[c] = (f32x4){0.f, 0.f, 0.f, 0.f};
#pragma unroll
  for (int t = 0; t < 4; ++t) {
#pragma unroll
    for (int c = 0; c < 8; ++c) {
      int fo = ((t * 8 + c) * 64 + lane) * 8;
      bf16x8 wh = *(const bf16x8*)(lw + fo);
      bf16x8 wl = *(const bf16x8*)(lw + 16384 + fo);
      acc2[c] = __builtin_amdgcn_mfma_f32_16x16x32_bf16(a_h[t], wh, acc2[c], 0, 0, 0);
      acc2[c] = __builtin_amdgcn_mfma_f32_16x16x32_bf16(a_l[t], wh, acc2[c], 0, 0, 0);
      acc2[c] = __builtin_amdgcn_mfma_f32_16x16x32_bf16(a_h[t], wl, acc2[c], 0, 0, 0);
    }
  }
  __syncthreads();

  int lr = tid >> 2, cb = (tid & 3) << 5;   // lr 0..95
  int grow = blockIdx.x * 96 + lr;
  size_t o = (size_t)grow * 128 + cb;

#pragma unroll
  for (int c = 0; c < 8; ++c)
#pragma unroll
    for (int r = 0; r < 4; ++r)
      lds[(wv * 16 + lk * 4 + r) * 132 + c * 16 + lrow] = acc1[c][r];
  __syncthreads();
  float4 mureg[8];
  if (grow < NN) {
    const float* sp = &lds[lr * 132 + cb];
#pragma unroll
    for (int i = 0; i < 8; ++i) {
      float4 v = *(const float4*)(sp + i * 4);
      float4 b4 = *(const float4*)&b1[cb + i * 4];
      v.x += b4.x; v.y += b4.y; v.z += b4.z; v.w += b4.w;
      mureg[i] = v;
      *(float4*)&mu[o + i * 4] = v;
    }
  }
  __syncthreads();
#pragma unroll
  for (int c = 0; c < 8; ++c)
#pragma unroll
    for (int r = 0; r < 4; ++r)
      lds[(wv * 16 + lk * 4 + r) * 132 + c * 16 + lrow] = acc2[c][r];
  __syncthreads();
  float s_deg = 0.f;
  if (grow < NN) {
    const float* sp = &lds[lr * 132 + cb];
#pragma unroll
    for (int i = 0; i < 8; ++i) {
      float4 v = *(const float4*)(sp + i * 4);
      float4 b4 = *(const float4*)&b2[cb + i * 4];
      float4 ls;
      ls.x = fminf(v.x + b4.x, 10.f);
      ls.y = fminf(v.y + b4.y, 10.f);
      ls.z = fminf(v.z + b4.z, 10.f);
      ls.w = fminf(v.w + b4.w, 10.f);
      *(float4*)&logstd[o + i * 4] = ls;
      float4 e4 = *(const float4*)&eps[o + i * 4];
      float4 z4;
      z4.x = fmaf(e4.x, expf(ls.x), mureg[i].x);
      z4.y = fmaf(e4.y, expf(ls.y), mureg[i].y);
      z4.z = fmaf(e4.z, expf(ls.z), mureg[i].z);
      z4.w = fmaf(e4.w, expf(ls.w), mureg[i].w);
      *(float4*)&Z[o + i * 4] = z4;
      ushort4 hh;
      hh.x = f2bf(z4.x); hh.y = f2bf(z4.y); hh.z = f2bf(z4.z); hh.w = f2bf(z4.w);
      *(ushort4*)&Zh[o + i * 4] = hh;
      float4 wd = *(const float4*)&Wd[cb + i * 4];
      s_deg += z4.x * wd.x + z4.y * wd.y + z4.z * wd.z + z4.w * wd.w;
    }
  }
  s_deg += __shfl_xor(s_deg, 1);
  s_deg += __shfl_xor(s_deg, 2);
  if (grow < NN && (tid & 3) == 0) degp[grow] = s_deg + bd[0];
}

// ---------------- output GEMM: x_rec = A_h@(Wh+Wl) + b, fp32 out ----------------

__global__ __launch_bounds__(512, 4) void k_mmO(const unsigned short* __restrict__ Ah,
                                                const unsigned short* __restrict__ wh,
                                                const unsigned short* __restrict__ wl,
                                                const float* __restrict__ bias,
                                                float* __restrict__ C) {
  __shared__ float lds[128 * 132];
  unsigned short* lw = (unsigned short*)lds;
  int tid = threadIdx.x;
  {
    int4* d = (int4*)lw;
#pragma unroll
    for (int i = 0; i < 4; ++i) {
      d[tid + i * 512] = ((const int4*)wh)[tid + i * 512];
      d[2048 + tid + i * 512] = ((const int4*)wl)[tid + i * 512];
    }
  }
  int wv = tid >> 6, lane = tid & 63;
  int lrow = lane & 15, lk = lane >> 4;
  int rbase = blockIdx.x * 128 + wv * 16;

  bf16x8 a_h[4];
  const unsigned short* ap = Ah + (size_t)(rbase + lrow) * 128 + lk * 8;
#pragma unroll
  for (int t = 0; t < 4; ++t) a_h[t] = *(const bf16x8*)(ap + t * 32);
  __syncthreads();

  f32x4 acc[8];
#pragma unroll
  for (int c = 0; c < 8; ++c) acc[c] = (f32x4){0.f, 0.f, 0.f, 0.f};
#pragma unroll
  for (int t = 0; t < 4; ++t) {
#pragma unroll
    for (int c = 0; c < 8; ++c) {
      int fo = ((t * 8 + c) * 64 + lane) * 8;
      bf16x8 whf = *(const bf16x8*)(lw + fo);
      bf16x8 wlf = *(const bf16x8*)(lw + 16384 + fo);
      acc[c] = __builtin_amdgcn_mfma_f32_16x16x32_bf16(a_h[t], whf, acc[c], 0, 0, 0);
      acc[c] = __builtin_amdgcn_mfma_f32_16x16x32_bf16(a_h[t], wlf, acc[c], 0, 0, 0);
    }
  }
  __syncthreads();

#pragma unroll
  for (int c = 0; c < 8; ++c)
#pragma unroll
    for (int r = 0; r < 4; ++r)
      lds[(wv * 16 + lk * 4 + r) * 132 + c * 16 + lrow] = acc[c][r];
  __syncthreads();
  int lr = tid >> 2, cb = (tid & 3) << 5;
  int grow = blockIdx.x * 128 + lr;
  if (grow < NN) {
    size_t o = (size_t)grow * 128 + cb;
    const float* sp = &lds[lr * 132 + cb];
#pragma unroll
    for (int i = 0; i < 8; ++i) {
      float4 v = *(const float4*)(sp + i * 4);
      float4 b4 = *(const float4*)&bias[cb + i * 4];
      v.x += b4.x; v.y += b4.y; v.z += b4.z; v.w += b4.w;
      *(float4*)&C[o + i * 4] = v;
    }
  }
}

// ---------------- GATv2 aggregation: wave/row, 4x16 lanes, bf16 gathers (r9) ----------------

template <int WLO>
__global__ __launch_bounds__(256) void k_gat_agg(const unsigned short* __restrict__ gxl,
                                                 const unsigned short* __restrict__ gxr,
                                                 const float* __restrict__ att,
                                                 const float* __restrict__ bias,
                                                 const int* __restrict__ row_ptr,
                                                 const int* __restrict__ csr_src,
                                                 unsigned short* __restrict__ sh,
                                                 unsigned short* __restrict__ sl) {
  int gid = blockIdx.x * blockDim.x + threadIdx.x;
  int row = gid >> 6;
  int lane = gid & 63;
  if (row >= NN) return;
  int g = lane >> 4, j = lane & 15;
  int dbase = j * 8;

  float a[8], r[8];
  {
    float4 a0 = *(const float4*)&att[dbase];
    float4 a1 = *(const float4*)&att[dbase + 4];
    a[0] = a0.x; a[1] = a0.y; a[2] = a0.z; a[3] = a0.w;
    a[4] = a1.x; a[5] = a1.y; a[6] = a1.z; a[7] = a1.w;
    bf16x8 rv = *(const bf16x8*)&gxr[(size_t)row * 128 + dbase];
#pragma unroll
    for (int k = 0; k < 8; ++k) r[k] = bf2f((unsigned short)rv[k]);
  }

  float m = -INFINITY, d = 0.f;
  float acc[8] = {0.f, 0.f, 0.f, 0.f, 0.f, 0.f, 0.f, 0.f};
  int p0 = row_ptr[row], p1 = row_ptr[row + 1];

  for (int p = p0 + g; p < p1; p += 4) {
    int s = csr_src[p];
    bf16x8 xv = *(const bf16x8*)&gxl[(size_t)s * 128 + dbase];
    float v[8];
#pragma unroll
    for (int k = 0; k < 8; ++k) v[k] = bf2f((unsigned short)xv[k]);

    float e = 0.f;
#pragma unroll
    for (int k = 0; k < 8; ++k) {
      float t0 = v[k] + r[k];
      t0 = fmaxf(t0, 0.2f * t0);
      e = fmaf(t0, a[k], e);
    }
    e += __shfl_xor(e, 1);
    e += __shfl_xor(e, 2);
    e += __shfl_xor(e, 4);
    e += __shfl_xor(e, 8);

    float mn = fmaxf(m, e);
    float scl = __expf(m - mn);
    float w = __expf(e - mn);
    d = d * scl + w;
#pragma unroll
    for (int k = 0; k < 8; ++k) acc[k] = acc[k] * scl + w * v[k];
    m = mn;
  }

  float mo = fmaxf(m, __shfl_xor(m, 16));
  mo = fmaxf(mo, __shfl_xor(mo, 32));
  float scl = __expf(m - mo);
  d *= scl;
  d += __shfl_xor(d, 16);
  d += __shfl_xor(d, 32);
#pragma unroll
  for (int k = 0; k < 8; ++k) {
    acc[k] *= scl;
    acc[k] += __shfl_xor(acc[k], 16);
    acc[k] += __shfl_xor(acc[k], 32);
  }

  if (g == 0) {
    float inv = 1.f / d;
    float4 b0 = *(const float4*)&bias[dbase];
    float4 b1v = *(const float4*)&bias[dbase + 4];
    float bb[8] = {b0.x, b0.y, b0.z, b0.w, b1v.x, b1v.y, b1v.z, b1v.w};
    bf16x8 vh, vl;
#pragma unroll
    for (int k = 0; k < 8; ++k) {
      float h = gelu_exact(acc[k] * inv + bb[k]);
      unsigned short hi = f2bf(h);
      vh[k] = (short)hi;
      if (WLO) vl[k] = (short)f2bf(h - bf2f(hi));
    }
    *(bf16x8*)(sh + (size_t)row * 128 + dbase) = vh;
    if (WLO) *(bf16x8*)(sl + (size_t)row * 128 + dbase) = vl;
  }
}

// ---------------- host ----------------

static inline char* take(char*& p, size_t bytes) {
  char* r = p;
  p += (bytes + 255) & ~(size_t)255;
  return r;
}

extern "C" void kernel_launch(void* const* d_in, const int* in_sizes, int n_in,
                              void* d_out, int out_size, void* d_ws, size_t ws_size,
                              hipStream_t stream) {
  const float* x      = (const float*)d_in[0];
  const int*   ei     = (const int*)d_in[1];
  const float* eps    = (const float*)d_in[2];
  const float* encWl  = (const float*)d_in[3];
  const float* encWr  = (const float*)d_in[4];
  const float* encAtt = (const float*)d_in[5];
  const float* encB   = (const float*)d_in[6];
  const float* decWl  = (const float*)d_in[7];
  const float* decWr  = (const float*)d_in[8];
  const float* decAtt = (const float*)d_in[9];
  const float* decB   = (const float*)d_in[10];
  const float* W_mu   = (const float*)d_in[11];
  const float* b_mu   = (const float*)d_in[12];
  const float* W_ls   = (const float*)d_in[13];
  const float* b_ls   = (const float*)d_in[14];
  const float* W_out  = (const float*)d_in[15];
  const float* b_out  = (const float*)d_in[16];
  const float* W_deg  = (const float*)d_in[17];
  const float* b_deg  = (const float*)d_in[18];

  float* out    = (float*)d_out;
  float* x_rec  = out;
  float* z      = out + (size_t)ND;
  float* mu     = out + (size_t)2 * ND;
  float* logstd = out + (size_t)3 * ND;
  float* degp   = out + (size_t)4 * ND;

  char* p = (char*)d_ws;
  int* bktcnt  = (int*)take(p, 1024 * 4);
  int* bktoff  = (int*)take(p, 1024 * 4);
  int* bktcur  = (int*)take(p, 1024 * 4);
  int* ebuf_g  = (int*)take(p, (size_t)ET * 4);
  int* row_ptr = (int*)take(p, (size_t)(NN + 1) * 4);
  int* csr_src = (int*)take(p, (size_t)ET * 4);
  unsigned short* gxl  = (unsigned short*)take(p, (size_t)MPAD * 128 * 2);
  unsigned short* gxr  = (unsigned short*)take(p, (size_t)MPAD * 128 * 2);
  unsigned short* stgh = (unsigned short*)take(p, (size_t)MPAD * 128 * 2);
  unsigned short* stgl = (unsigned short*)take(p, (size_t)MPAD * 128 * 2);
  unsigned short* wfh  = (unsigned short*)take(p, (size_t)19 * 16384 * 2);
  unsigned short* wfl  = (unsigned short*)take(p, (size_t)19 * 16384 * 2);

  const int gMM   = MPAD / 128;                   // 782
  const int gMMH  = (NN + 95) / 96;               // 1042 (96-row head blocks)
  const int gWave = (NN * 64 + 255) / 256;        // 25000
  const int gXC   = (MPAD * 128 / 8 + 255) / 256; // 6256

  // CSR build
  k_zero_int<<<4, 256, 0, stream>>>(bktcnt, 1024);
  kb_hist<<<GSC, 256, 0, stream>>>(ei, bktcnt);
  kb_scan<<<1, 256, 0, stream>>>(bktcnt, bktoff, bktcur);
  kb_scatter<<<GSC, 256, 0, stream>>>(ei, bktcur, ebuf_g);
  kb_fin<<<NBKT, 256, 0, stream>>>(ebuf_g, bktoff, csr_src, row_ptr);

  // weight frags + x stage
  k_wconv<<<152, 256, 0, stream>>>(encWl, encWr, decWl, decWr, W_mu, W_ls, W_out, wfh, wfl);
  k_xconv<<<gXC, 256, 0, stream>>>(x, stgh);

  const size_t WM = 16384;
  // encoder
  for (int l = 0; l < 4; ++l) {
    k_mmL<<<gMM, 512, 0, stream>>>(stgh,
                                   wfh + (size_t)l * WM, wfh + (size_t)(4 + l) * WM,
                                   gxl, gxr);
    if (l < 3)
      k_gat_agg<0><<<gWave, 256, 0, stream>>>(gxl, gxr, encAtt + (size_t)l * DD,
                                              encB + (size_t)l * DD, row_ptr, csr_src,
                                              stgh, stgl);
    else
      k_gat_agg<1><<<gWave, 256, 0, stream>>>(gxl, gxr, encAtt + (size_t)l * DD,
                                              encB + (size_t)l * DD, row_ptr, csr_src,
                                              stgh, stgl);
  }

  // heads: mu, logstd, z, z-stage(hi), degree head
  k_mmH<<<gMMH, 384, 0, stream>>>(stgh, stgl,
                                  wfh + (size_t)16 * WM, wfl + (size_t)16 * WM,
                                  wfh + (size_t)17 * WM, wfl + (size_t)17 * WM,
                                  b_mu, b_ls, eps, W_deg, b_deg,
                                  mu, logstd, z, stgh, degp);

  // decoder
  for (int l = 0; l < 4; ++l) {
    k_mmL<<<gMM, 512, 0, stream>>>(stgh,
                                   wfh + (size_t)(8 + l) * WM, wfh + (size_t)(12 + l) * WM,
                                   gxl, gxr);
    k_gat_agg<0><<<gWave, 256, 0, stream>>>(gxl, gxr, decAtt + (size_t)l * DD,
                                            decB + (size_t)l * DD, row_ptr, csr_src,
                                            stgh, stgl);
  }

  // x_rec (A-hi, 2-term W)
  k_mmO<<<gMM, 512, 0, stream>>>(stgh,
                                 wfh + (size_t)18 * WM, wfl + (size_t)18 * WM,
                                 b_out, x_rec);
}

// Round 12
// 1334.799 us; speedup vs baseline: 1.0774x; 1.0304x over previous
//
#include <hip/hip_runtime.h>
#include <math.h>

#define NN 100000
#define MPAD 100096
#define DD 128
#define EE 1600000
#define ET (EE + NN)
#define ND (NN * DD)

#define NBKT 782
#define IPB 16384
#define GSC 104
#define SCAP 4096   // slack capacity per bucket (mean 2174, sigma ~47)

typedef short bf16x8 __attribute__((ext_vector_type(8)));
typedef float f32x4 __attribute__((ext_vector_type(4)));

static __device__ __forceinline__ unsigned short f2bf(float f) {
  unsigned int u = __float_as_uint(f);
  u += 0x7FFFu + ((u >> 16) & 1u);
  return (unsigned short)(u >> 16);
}
static __device__ __forceinline__ float bf2f(unsigned short h) {
  return __uint_as_float(((unsigned int)h) << 16);
}
static __device__ __forceinline__ float gelu_exact(float v) {
  return 0.5f * v * (1.f + erff(v * 0.7071067811865476f));
}

// ---------------- CSR build: slack-bucket counting sort (no hist pass) ----------------

__global__ void k_zero_int(int* __restrict__ p, int n) {
  int i = blockIdx.x * blockDim.x + threadIdx.x;
  if (i < n) p[i] = 0;
}

// single pass over edges: block-local count -> reserve runs in per-bucket slack -> write
__global__ __launch_bounds__(256) void kb_scatter(const int* __restrict__ ei,
                                                  int* __restrict__ cnt,
                                                  int* __restrict__ slack) {
  __shared__ int lc[NBKT];
  __shared__ int lb[NBKT];
  int t = threadIdx.x;
  for (int b = t; b < NBKT; b += 256) lc[b] = 0;
  __syncthreads();
  int i0 = blockIdx.x * IPB;
  int i1 = min(i0 + IPB, ET);
  for (int i = i0 + t; i < i1; i += 256) {
    int dst = (i < EE) ? ei[EE + i] : (i - EE);
    atomicAdd(&lc[dst >> 7], 1);
  }
  __syncthreads();
  for (int b = t; b < NBKT; b += 256) {
    int c = lc[b];
    lb[b] = c ? atomicAdd(&cnt[b], c) : 0;
    lc[b] = 0;
  }
  __syncthreads();
  for (int i = i0 + t; i < i1; i += 256) {
    int src, dst;
    if (i < EE) { src = ei[i]; dst = ei[EE + i]; } else { src = i - EE; dst = src; }
    int b = dst >> 7;
    int l = atomicAdd(&lc[b], 1);
    int pos = lb[b] + l;
    if (pos < SCAP) slack[(size_t)b * SCAP + pos] = src | ((dst & 127) << 17);
  }
}

__global__ __launch_bounds__(256) void kb_scan(const int* __restrict__ cnt,
                                               int* __restrict__ off) {
  __shared__ int sh[256];
  int t = threadIdx.x;
  int c[4]; int s = 0;
#pragma unroll
  for (int j = 0; j < 4; ++j) {
    int b = t * 4 + j;
    c[j] = s;
    int v = (b < NBKT) ? cnt[b] : 0;
    s += v;
  }
  sh[t] = s; __syncthreads();
  for (int o = 1; o < 256; o <<= 1) {
    int v = (t >= o) ? sh[t - o] : 0;
    __syncthreads();
    sh[t] += v;
    __syncthreads();
  }
  int excl = sh[t] - s;
#pragma unroll
  for (int j = 0; j < 4; ++j) {
    int b = t * 4 + j;
    if (b < NBKT) off[b] = excl + c[j];
  }
  if (t == 255) off[NBKT] = excl + s;
}

// per-bucket local sort -> coalesced csr_src + row_ptr
__global__ __launch_bounds__(256) void kb_fin(const int* __restrict__ slack,
                                              const int* __restrict__ off,
                                              int* __restrict__ csr_src,
                                              int* __restrict__ row_ptr) {
  __shared__ int ebuf[SCAP];
  __shared__ int osrc[SCAP];
  __shared__ int cnt[128], scn[128], lcur[128];
  int b = blockIdx.x;
  int base = off[b];
  int count = min(off[b + 1] - base, SCAP);
  int t = threadIdx.x;
  const int* in = slack + (size_t)b * SCAP;
  if (t < 128) { cnt[t] = 0; lcur[t] = 0; }
  __syncthreads();
  for (int i = t; i < count; i += 256) {
    int w = in[i];
    ebuf[i] = w;
    atomicAdd(&cnt[(w >> 17) & 127], 1);
  }
  __syncthreads();
  if (t < 128) scn[t] = cnt[t];
  __syncthreads();
  for (int o = 1; o < 128; o <<= 1) {
    int v = 0;
    if (t < 128 && t >= o) v = scn[t - o];
    __syncthreads();
    if (t < 128) scn[t] += v;
    __syncthreads();
  }
  for (int i = t; i < count; i += 256) {
    int w = ebuf[i];
    int d = (w >> 17) & 127;
    int l = atomicAdd(&lcur[d], 1);
    osrc[(scn[d] - cnt[d]) + l] = w & 0x1FFFF;
  }
  __syncthreads();
  for (int i = t; i < count; i += 256) csr_src[base + i] = osrc[i];
  if (t < 128) {
    int gd = b * 128 + t;
    if (gd <= NN) row_ptr[gd] = base + scn[t] - cnt[t];
  }
}

// ---------------- weight fragment precompute ----------------

__global__ __launch_bounds__(256) void k_wconv(const float* __restrict__ encWl,
                                               const float* __restrict__ encWr,
                                               const float* __restrict__ decWl,
                                               const float* __restrict__ decWr,
                                               const float* __restrict__ Wmu,
                                               const float* __restrict__ Wls,
                                               const float* __restrict__ Wout,
                                               unsigned short* __restrict__ wfh,
                                               unsigned short* __restrict__ wfl) {
  int wid = (blockIdx.x * 256 + threadIdx.x) >> 6;
  int lane = threadIdx.x & 63;
  if (wid >= 19 * 32) return;
  int mat = wid >> 5;
  int sub = wid & 31;
  const float* W;
  if (mat < 4) W = encWl + (size_t)mat * 16384;
  else if (mat < 8) W = encWr + (size_t)(mat - 4) * 16384;
  else if (mat < 12) W = decWl + (size_t)(mat - 8) * 16384;
  else if (mat < 16) W = decWr + (size_t)(mat - 12) * 16384;
  else if (mat == 16) W = Wmu;
  else if (mat == 17) W = Wls;
  else W = Wout;
  int t = sub >> 3, c = sub & 7;
  int col = c * 16 + (lane & 15);
  int k0 = t * 32 + (lane >> 4) * 8;
  bf16x8 vh, vl;
#pragma unroll
  for (int j = 0; j < 8; ++j) {
    float w = W[(size_t)(k0 + j) * 128 + col];
    unsigned short h = f2bf(w);
    vh[j] = (short)h;
    vl[j] = (short)f2bf(w - bf2f(h));
  }
  size_t base = ((size_t)wid * 64 + lane) * 8;
  *(bf16x8*)(wfh + base) = vh;
  *(bf16x8*)(wfl + base) = vl;
}

// ---------------- layer dual GEMM: 1-term bf16, bf16 out (r9 structure) ----------------
// RF32=1: layer 0 reads fp32 x directly (xconv fused).

template <int RF32>
__global__ __launch_bounds__(512, 4) void k_mmL(const unsigned short* __restrict__ Ah,
                                                const float* __restrict__ Xf,
                                                const unsigned short* __restrict__ w1,
                                                const unsigned short* __restrict__ w2,
                                                unsigned short* __restrict__ o1,
                                                unsigned short* __restrict__ o2) {
  __shared__ float lds[128 * 132];  // 67.6 KB
  unsigned short* lw = (unsigned short*)lds;
  int tid = threadIdx.x;
  {
    int4* d = (int4*)lw;
    const int4* s1 = (const int4*)w1;
    const int4* s2 = (const int4*)w2;
#pragma unroll
    for (int i = 0; i < 4; ++i) {
      d[tid + i * 512] = s1[tid + i * 512];
      d[2048 + tid + i * 512] = s2[tid + i * 512];
    }
  }
  int wv = tid >> 6, lane = tid & 63;
  int lrow = lane & 15, lk = lane >> 4;
  int rbase = blockIdx.x * 128 + wv * 16;
  int row = rbase + lrow;

  bf16x8 a_h[4];
  if (RF32) {
#pragma unroll
    for (int t = 0; t < 4; ++t) {
      float4 f0 = {0.f, 0.f, 0.f, 0.f}, f1 = {0.f, 0.f, 0.f, 0.f};
      if (row < NN) {
        const float* xp = Xf + (size_t)row * 128 + t * 32 + lk * 8;
        f0 = *(const float4*)xp;
        f1 = *(const float4*)(xp + 4);
      }
      bf16x8 v;
      v[0] = (short)f2bf(f0.x); v[1] = (short)f2bf(f0.y);
      v[2] = (short)f2bf(f0.z); v[3] = (short)f2bf(f0.w);
      v[4] = (short)f2bf(f1.x); v[5] = (short)f2bf(f1.y);
      v[6] = (short)f2bf(f1.z); v[7] = (short)f2bf(f1.w);
      a_h[t] = v;
    }
  } else {
    const unsigned short* ap = Ah + (size_t)row * 128 + lk * 8;
#pragma unroll
    for (int t = 0; t < 4; ++t) a_h[t] = *(const bf16x8*)(ap + t * 32);
  }
  __syncthreads();

  f32x4 acc1[8], acc2[8];
#pragma unroll
  for (int c = 0; c < 8; ++c) {
    acc1[c] = (f32x4){0.f, 0.f, 0.f, 0.f};
    acc2[c] = (f32x4){0.f, 0.f, 0.f, 0.f};
  }
#pragma unroll
  for (int t = 0; t < 4; ++t) {
#pragma unroll
    for (int c = 0; c < 8; ++c) {
      int fo = ((t * 8 + c) * 64 + lane) * 8;
      bf16x8 wf1 = *(const bf16x8*)(lw + fo);
      bf16x8 wf2 = *(const bf16x8*)(lw + 16384 + fo);
      acc1[c] = __builtin_amdgcn_mfma_f32_16x16x32_bf16(a_h[t], wf1, acc1[c], 0, 0, 0);
      acc2[c] = __builtin_amdgcn_mfma_f32_16x16x32_bf16(a_h[t], wf2, acc2[c], 0, 0, 0);
    }
  }
  __syncthreads();  // weights dead; LDS becomes transpose buffer

  int lr = tid >> 2, cb = (tid & 3) << 5;
  size_t o = ((size_t)blockIdx.x * 128 + lr) * 128 + cb;

#pragma unroll
  for (int out = 0; out < 2; ++out) {
#pragma unroll
    for (int c = 0; c < 8; ++c)
#pragma unroll
      for (int r = 0; r < 4; ++r)
        lds[(wv * 16 + lk * 4 + r) * 132 + c * 16 + lrow] = out ? acc2[c][r] : acc1[c][r];
    __syncthreads();
    {
      unsigned short* dst = out ? o2 : o1;
      const float* sp = &lds[lr * 132 + cb];
#pragma unroll
      for (int i = 0; i < 4; ++i) {
        union { unsigned short u[8]; int4 v; } pk;
#pragma unroll
        for (int j = 0; j < 8; ++j) pk.u[j] = f2bf(sp[i * 8 + j]);
        *(int4*)&dst[o + i * 8] = pk.v;
      }
    }
    __syncthreads();
  }
}

// ---------------- head kernel (512 thr / 128-row, r9-proven) ----------------

__global__ __launch_bounds__(512, 3) void k_mmH(const unsigned short* Ah,
                                                const unsigned short* Al,
                                                const unsigned short* __restrict__ w1h,
                                                const unsigned short* __restrict__ w1l,
                                                const unsigned short* __restrict__ w2h,
                                                const unsigned short* __restrict__ w2l,
                                                const float* __restrict__ b1,
                                                const float* __restrict__ b2,
                                                const float* __restrict__ eps,
                                                const float* __restrict__ Wd,
                                                const float* __restrict__ bd,
                                                float* __restrict__ mu,
                                                float* __restrict__ logstd,
                                                float* __restrict__ Z,
                                                unsigned short* Zh,
                                                float* __restrict__ degp) {
  __shared__ float lds[128 * 132];
  unsigned short* lw = (unsigned short*)lds;
  int tid = threadIdx.x;
  int wv = tid >> 6, lane = tid & 63;
  int lrow = lane & 15, lk = lane >> 4;
  int rbase = blockIdx.x * 128 + wv * 16;

  {
    int4* d = (int4*)lw;
#pragma unroll
    for (int i = 0; i < 4; ++i) {
      d[tid + i * 512] = ((const int4*)w1h)[tid + i * 512];
      d[2048 + tid + i * 512] = ((const int4*)w1l)[tid + i * 512];
    }
  }
  bf16x8 a_h[4], a_l[4];
  const unsigned short* ap = Ah + (size_t)(rbase + lrow) * 128 + lk * 8;
  const unsigned short* alp = Al + (size_t)(rbase + lrow) * 128 + lk * 8;
#pragma unroll
  for (int t = 0; t < 4; ++t) {
    a_h[t] = *(const bf16x8*)(ap + t * 32);
    a_l[t] = *(const bf16x8*)(alp + t * 32);
  }
  __syncthreads();

  f32x4 acc1[8];
#pragma unroll
  for (int c = 0; c < 8; ++c) acc1[c] = (f32x4){0.f, 0.f, 0.f, 0.f};
#pragma unroll
  for (int t = 0; t < 4; ++t) {
#pragma unroll
    for (int c = 0; c < 8; ++c) {
      int fo = ((t * 8 + c) * 64 + lane) * 8;
      bf16x8 wh = *(const bf16x8*)(lw + fo);
      bf16x8 wl = *(const bf16x8*)(lw + 16384 + fo);
      acc1[c] = __builtin_amdgcn_mfma_f32_16x16x32_bf16(a_h[t], wh, acc1[c], 0, 0, 0);
      acc1[c] = __builtin_amdgcn_mfma_f32_16x16x32_bf16(a_l[t], wh, acc1[c], 0, 0, 0);
      acc1[c] = __builtin_amdgcn_mfma_f32_16x16x32_bf16(a_h[t], wl, acc1[c], 0, 0, 0);
    }
  }
  __syncthreads();

  {
    int4* d = (int4*)lw;
#pragma unroll
    for (int i = 0; i < 4; ++i) {
      d[tid + i * 512] = ((const int4*)w2h)[tid + i * 512];
      d[2048 + tid + i * 512] = ((const int4*)w2l)[tid + i * 512];
    }
  }
  __syncthreads();

  f32x4 acc2[8];
#pragma unroll
  for (int c = 0; c < 8; ++c) acc2[c] = (f32x4){0.f, 0.f, 0.f, 0.f};
#pragma unroll
  for (int t = 0; t < 4; ++t) {
#pragma unroll
    for (int c = 0; c < 8; ++c) {
      int fo = ((t * 8 + c) * 64 + lane) * 8;
      bf16x8 wh = *(const bf16x8*)(lw + fo);
      bf16x8 wl = *(const bf16x8*)(lw + 16384 + fo);
      acc2[c] = __builtin_amdgcn_mfma_f32_16x16x32_bf16(a_h[t], wh, acc2[c], 0, 0, 0);
      acc2[c] = __builtin_amdgcn_mfma_f32_16x16x32_bf16(a_l[t], wh, acc2[c], 0, 0, 0);
      acc2[c] = __builtin_amdgcn_mfma_f32_16x16x32_bf16(a_h[t], wl, acc2[c], 0, 0, 0);
    }
  }
  __syncthreads();

  int lr = tid >> 2, cb = (tid & 3) << 5;
  int grow = blockIdx.x * 128 + lr;
  size_t o = (size_t)grow * 128 + cb;

#pragma unroll
  for (int c = 0; c < 8; ++c)
#pragma unroll
    for (int r = 0; r < 4; ++r)
      lds[(wv * 16 + lk * 4 + r) * 132 + c * 16 + lrow] = acc1[c][r];
  __syncthreads();
  float4 mureg[8];
  if (grow < NN) {
    const float* sp = &lds[lr * 132 + cb];
#pragma unroll
    for (int i = 0; i < 8; ++i) {
      float4 v = *(const float4*)(sp + i * 4);
      float4 b4 = *(const float4*)&b1[cb + i * 4];
      v.x += b4.x; v.y += b4.y; v.z += b4.z; v.w += b4.w;
      mureg[i] = v;
      *(float4*)&mu[o + i * 4] = v;
    }
  }
  __syncthreads();
#pragma unroll
  for (int c = 0; c < 8; ++c)
#pragma unroll
    for (int r = 0; r < 4; ++r)
      lds[(wv * 16 + lk * 4 + r) * 132 + c * 16 + lrow] = acc2[c][r];
  __syncthreads();
  float s_deg = 0.f;
  if (grow < NN) {
    const float* sp = &lds[lr * 132 + cb];
#pragma unroll
    for (int i = 0; i < 8; ++i) {
      float4 v = *(const float4*)(sp + i * 4);
      float4 b4 = *(const float4*)&b2[cb + i * 4];
      float4 ls;
      ls.x = fminf(v.x + b4.x, 10.f);
      ls.y = fminf(v.y + b4.y, 10.f);
      ls.z = fminf(v.z + b4.z, 10.f);
      ls.w = fminf(v.w + b4.w, 10.f);
      *(float4*)&logstd[o + i * 4] = ls;
      float4 e4 = *(const float4*)&eps[o + i * 4];
      float4 z4;
      z4.x = fmaf(e4.x, expf(ls.x), mureg[i].x);
      z4.y = fmaf(e4.y, expf(ls.y), mureg[i].y);
      z4.z = fmaf(e4.z, expf(ls.z), mureg[i].z);
      z4.w = fmaf(e4.w, expf(ls.w), mureg[i].w);
      *(float4*)&Z[o + i * 4] = z4;
      ushort4 hh;
      hh.x = f2bf(z4.x); hh.y = f2bf(z4.y); hh.z = f2bf(z4.z); hh.w = f2bf(z4.w);
      *(ushort4*)&Zh[o + i * 4] = hh;
      float4 wd = *(const float4*)&Wd[cb + i * 4];
      s_deg += z4.x * wd.x + z4.y * wd.y + z4.z * wd.z + z4.w * wd.w;
    }
  }
  s_deg += __shfl_xor(s_deg, 1);
  s_deg += __shfl_xor(s_deg, 2);
  if (grow < NN && (tid & 3) == 0) degp[grow] = s_deg + bd[0];
}

// ---------------- output GEMM: x_rec = A_h@(Wh+Wl) + b, fp32 out ----------------

__global__ __launch_bounds__(512, 4) void k_mmO(const unsigned short* __restrict__ Ah,
                                                const unsigned short* __restrict__ wh,
                                                const unsigned short* __restrict__ wl,
                                                const float* __restrict__ bias,
                                                float* __restrict__ C) {
  __shared__ float lds[128 * 132];
  unsigned short* lw = (unsigned short*)lds;
  int tid = threadIdx.x;
  {
    int4* d = (int4*)lw;
#pragma unroll
    for (int i = 0; i < 4; ++i) {
      d[tid + i * 512] = ((const int4*)wh)[tid + i * 512];
      d[2048 + tid + i * 512] = ((const int4*)wl)[tid + i * 512];
    }
  }
  int wv = tid >> 6, lane = tid & 63;
  int lrow = lane & 15, lk = lane >> 4;
  int rbase = blockIdx.x * 128 + wv * 16;

  bf16x8 a_h[4];
  const unsigned short* ap = Ah + (size_t)(rbase + lrow) * 128 + lk * 8;
#pragma unroll
  for (int t = 0; t < 4; ++t) a_h[t] = *(const bf16x8*)(ap + t * 32);
  __syncthreads();

  f32x4 acc[8];
#pragma unroll
  for (int c = 0; c < 8; ++c) acc[c] = (f32x4){0.f, 0.f, 0.f, 0.f};
#pragma unroll
  for (int t = 0; t < 4; ++t) {
#pragma unroll
    for (int c = 0; c < 8; ++c) {
      int fo = ((t * 8 + c) * 64 + lane) * 8;
      bf16x8 whf = *(const bf16x8*)(lw + fo);
      bf16x8 wlf = *(const bf16x8*)(lw + 16384 + fo);
      acc[c] = __builtin_amdgcn_mfma_f32_16x16x32_bf16(a_h[t], whf, acc[c], 0, 0, 0);
      acc[c] = __builtin_amdgcn_mfma_f32_16x16x32_bf16(a_h[t], wlf, acc[c], 0, 0, 0);
    }
  }
  __syncthreads();

#pragma unroll
  for (int c = 0; c < 8; ++c)
#pragma unroll
    for (int r = 0; r < 4; ++r)
      lds[(wv * 16 + lk * 4 + r) * 132 + c * 16 + lrow] = acc[c][r];
  __syncthreads();
  int lr = tid >> 2, cb = (tid & 3) << 5;
  int grow = blockIdx.x * 128 + lr;
  if (grow < NN) {
    size_t o = (size_t)grow * 128 + cb;
    const float* sp = &lds[lr * 132 + cb];
#pragma unroll
    for (int i = 0; i < 8; ++i) {
      float4 v = *(const float4*)(sp + i * 4);
      float4 b4 = *(const float4*)&bias[cb + i * 4];
      v.x += b4.x; v.y += b4.y; v.z += b4.z; v.w += b4.w;
      *(float4*)&C[o + i * 4] = v;
    }
  }
}

// ---------------- GATv2 aggregation: wave/row, 4x16 lanes, bf16 gathers ----------------

template <int WLO>
__global__ __launch_bounds__(256) void k_gat_agg(const unsigned short* __restrict__ gxl,
                                                 const unsigned short* __restrict__ gxr,
                                                 const float* __restrict__ att,
                                                 const float* __restrict__ bias,
                                                 const int* __restrict__ row_ptr,
                                                 const int* __restrict__ csr_src,
                                                 unsigned short* __restrict__ sh,
                                                 unsigned short* __restrict__ sl) {
  int gid = blockIdx.x * blockDim.x + threadIdx.x;
  int row = gid >> 6;
  int lane = gid & 63;
  if (row >= NN) return;
  int g = lane >> 4, j = lane & 15;
  int dbase = j * 8;

  float a[8], r[8];
  {
    float4 a0 = *(const float4*)&att[dbase];
    float4 a1 = *(const float4*)&att[dbase + 4];
    a[0] = a0.x; a[1] = a0.y; a[2] = a0.z; a[3] = a0.w;
    a[4] = a1.x; a[5] = a1.y; a[6] = a1.z; a[7] = a1.w;
    bf16x8 rv = *(const bf16x8*)&gxr[(size_t)row * 128 + dbase];
#pragma unroll
    for (int k = 0; k < 8; ++k) r[k] = bf2f((unsigned short)rv[k]);
  }

  float m = -INFINITY, d = 0.f;
  float acc[8] = {0.f, 0.f, 0.f, 0.f, 0.f, 0.f, 0.f, 0.f};
  int p0 = row_ptr[row], p1 = row_ptr[row + 1];

  for (int p = p0 + g; p < p1; p += 4) {
    int s = csr_src[p];
    bf16x8 xv = *(const bf16x8*)&gxl[(size_t)s * 128 + dbase];
    float v[8];
#pragma unroll
    for (int k = 0; k < 8; ++k) v[k] = bf2f((unsigned short)xv[k]);

    float e = 0.f;
#pragma unroll
    for (int k = 0; k < 8; ++k) {
      float t0 = v[k] + r[k];
      t0 = fmaxf(t0, 0.2f * t0);
      e = fmaf(t0, a[k], e);
    }
    e += __shfl_xor(e, 1);
    e += __shfl_xor(e, 2);
    e += __shfl_xor(e, 4);
    e += __shfl_xor(e, 8);

    float mn = fmaxf(m, e);
    float scl = __expf(m - mn);
    float w = __expf(e - mn);
    d = d * scl + w;
#pragma unroll
    for (int k = 0; k < 8; ++k) acc[k] = acc[k] * scl + w * v[k];
    m = mn;
  }

  float mo = fmaxf(m, __shfl_xor(m, 16));
  mo = fmaxf(mo, __shfl_xor(mo, 32));
  float scl = __expf(m - mo);
  d *= scl;
  d += __shfl_xor(d, 16);
  d += __shfl_xor(d, 32);
#pragma unroll
  for (int k = 0; k < 8; ++k) {
    acc[k] *= scl;
    acc[k] += __shfl_xor(acc[k], 16);
    acc[k] += __shfl_xor(acc[k], 32);
  }

  if (g == 0) {
    float inv = 1.f / d;
    float4 b0 = *(const float4*)&bias[dbase];
    float4 b1v = *(const float4*)&bias[dbase + 4];
    float bb[8] = {b0.x, b0.y, b0.z, b0.w, b1v.x, b1v.y, b1v.z, b1v.w};
    bf16x8 vh, vl;
#pragma unroll
    for (int k = 0; k < 8; ++k) {
      float h = gelu_exact(acc[k] * inv + bb[k]);
      unsigned short hi = f2bf(h);
      vh[k] = (short)hi;
      if (WLO) vl[k] = (short)f2bf(h - bf2f(hi));
    }
    *(bf16x8*)(sh + (size_t)row * 128 + dbase) = vh;
    if (WLO) *(bf16x8*)(sl + (size_t)row * 128 + dbase) = vl;
  }
}

// ---------------- host ----------------

static inline char* take(char*& p, size_t bytes) {
  char* r = p;
  p += (bytes + 255) & ~(size_t)255;
  return r;
}

extern "C" void kernel_launch(void* const* d_in, const int* in_sizes, int n_in,
                              void* d_out, int out_size, void* d_ws, size_t ws_size,
                              hipStream_t stream) {
  const float* x      = (const float*)d_in[0];
  const int*   ei     = (const int*)d_in[1];
  const float* eps    = (const float*)d_in[2];
  const float* encWl  = (const float*)d_in[3];
  const float* encWr  = (const float*)d_in[4];
  const float* encAtt = (const float*)d_in[5];
  const float* encB   = (const float*)d_in[6];
  const float* decWl  = (const float*)d_in[7];
  const float* decWr  = (const float*)d_in[8];
  const float* decAtt = (const float*)d_in[9];
  const float* decB   = (const float*)d_in[10];
  const float* W_mu   = (const float*)d_in[11];
  const float* b_mu   = (const float*)d_in[12];
  const float* W_ls   = (const float*)d_in[13];
  const float* b_ls   = (const float*)d_in[14];
  const float* W_out  = (const float*)d_in[15];
  const float* b_out  = (const float*)d_in[16];
  const float* W_deg  = (const float*)d_in[17];
  const float* b_deg  = (const float*)d_in[18];

  float* out    = (float*)d_out;
  float* x_rec  = out;
  float* z      = out + (size_t)ND;
  float* mu     = out + (size_t)2 * ND;
  float* logstd = out + (size_t)3 * ND;
  float* degp   = out + (size_t)4 * ND;

  char* p = (char*)d_ws;
  int* bktcnt  = (int*)take(p, 1024 * 4);
  int* bktoff  = (int*)take(p, 1024 * 4);
  int* slack   = (int*)take(p, (size_t)NBKT * SCAP * 4);
  int* row_ptr = (int*)take(p, (size_t)(NN + 1) * 4);
  int* csr_src = (int*)take(p, (size_t)ET * 4);
  unsigned short* gxl  = (unsigned short*)take(p, (size_t)MPAD * 128 * 2);
  unsigned short* gxr  = (unsigned short*)take(p, (size_t)MPAD * 128 * 2);
  unsigned short* stgh = (unsigned short*)take(p, (size_t)MPAD * 128 * 2);
  unsigned short* stgl = (unsigned short*)take(p, (size_t)MPAD * 128 * 2);
  unsigned short* wfh  = (unsigned short*)take(p, (size_t)19 * 16384 * 2);
  unsigned short* wfl  = (unsigned short*)take(p, (size_t)19 * 16384 * 2);

  const int gMM   = MPAD / 128;             // 782
  const int gWave = (NN * 64 + 255) / 256;  // 25000

  // CSR build (slack scatter, no hist pass)
  k_zero_int<<<4, 256, 0, stream>>>(bktcnt, 1024);
  kb_scatter<<<GSC, 256, 0, stream>>>(ei, bktcnt, slack);
  kb_scan<<<1, 256, 0, stream>>>(bktcnt, bktoff);
  kb_fin<<<NBKT, 256, 0, stream>>>(slack, bktoff, csr_src, row_ptr);

  // weight frags
  k_wconv<<<152, 256, 0, stream>>>(encWl, encWr, decWl, decWr, W_mu, W_ls, W_out, wfh, wfl);

  const size_t WM = 16384;
  // encoder (layer 0 reads fp32 x directly)
  for (int l = 0; l < 4; ++l) {
    if (l == 0)
      k_mmL<1><<<gMM, 512, 0, stream>>>(nullptr, x,
                                        wfh + (size_t)l * WM, wfh + (size_t)(4 + l) * WM,
                                        gxl, gxr);
    else
      k_mmL<0><<<gMM, 512, 0, stream>>>(stgh, nullptr,
                                        wfh + (size_t)l * WM, wfh + (size_t)(4 + l) * WM,
                                        gxl, gxr);
    if (l < 3)
      k_gat_agg<0><<<gWave, 256, 0, stream>>>(gxl, gxr, encAtt + (size_t)l * DD,
                                              encB + (size_t)l * DD, row_ptr, csr_src,
                                              stgh, stgl);
    else
      k_gat_agg<1><<<gWave, 256, 0, stream>>>(gxl, gxr, encAtt + (size_t)l * DD,
                                              encB + (size_t)l * DD, row_ptr, csr_src,
                                              stgh, stgl);
  }

  // heads: mu, logstd, z, z-stage(hi), degree head
  k_mmH<<<gMM, 512, 0, stream>>>(stgh, stgl,
                                 wfh + (size_t)16 * WM, wfl + (size_t)16 * WM,
                                 wfh + (size_t)17 * WM, wfl + (size_t)17 * WM,
                                 b_mu, b_ls, eps, W_deg, b_deg,
                                 mu, logstd, z, stgh, degp);

  // decoder
  for (int l = 0; l < 4; ++l) {
    k_mmL<0><<<gMM, 512, 0, stream>>>(stgh, nullptr,
                                      wfh + (size_t)(8 + l) * WM, wfh + (size_t)(12 + l) * WM,
                                      gxl, gxr);
    k_gat_agg<0><<<gWave, 256, 0, stream>>>(gxl, gxr, decAtt + (size_t)l * DD,
                                            decB + (size_t)l * DD, row_ptr, csr_src,
                                            stgh, stgl);
  }

  // x_rec (A-hi, 2-term W)
  k_mmO<<<gMM, 512, 0, stream>>>(stgh,
                                 wfh + (size_t)18 * WM, wfl + (size_t)18 * WM,
                                 b_out, x_rec);
}

// Round 13
// 1260.738 us; speedup vs baseline: 1.1407x; 1.0587x over previous
//
#include <hip/hip_runtime.h>
#include <math.h>

#define NN 100000
#define MPAD 100096
#define DD 128
#define EE 1600000
#define ET (EE + NN)
#define ND (NN * DD)

#define NBKT 782
#define IPB 16384
#define GSC 104
#define SCAP 4096

typedef short bf16x8 __attribute__((ext_vector_type(8)));
typedef float f32x4 __attribute__((ext_vector_type(4)));

static __device__ __forceinline__ unsigned short f2bf(float f) {
  unsigned int u = __float_as_uint(f);
  u += 0x7FFFu + ((u >> 16) & 1u);
  return (unsigned short)(u >> 16);
}
static __device__ __forceinline__ float bf2f(unsigned short h) {
  return __uint_as_float(((unsigned int)h) << 16);
}
static __device__ __forceinline__ float gelu_exact(float v) {
  return 0.5f * v * (1.f + erff(v * 0.7071067811865476f));
}

// ---------------- CSR build: slack-bucket counting sort ----------------

__global__ void k_zero_int(int* __restrict__ p, int n) {
  int i = blockIdx.x * blockDim.x + threadIdx.x;
  if (i < n) p[i] = 0;
}

__global__ __launch_bounds__(256) void kb_scatter(const int* __restrict__ ei,
                                                  int* __restrict__ cnt,
                                                  int* __restrict__ slack) {
  __shared__ int lc[NBKT];
  __shared__ int lb[NBKT];
  int t = threadIdx.x;
  for (int b = t; b < NBKT; b += 256) lc[b] = 0;
  __syncthreads();
  int i0 = blockIdx.x * IPB;
  int i1 = min(i0 + IPB, ET);
  for (int i = i0 + t; i < i1; i += 256) {
    int dst = (i < EE) ? ei[EE + i] : (i - EE);
    atomicAdd(&lc[dst >> 7], 1);
  }
  __syncthreads();
  for (int b = t; b < NBKT; b += 256) {
    int c = lc[b];
    lb[b] = c ? atomicAdd(&cnt[b], c) : 0;
    lc[b] = 0;
  }
  __syncthreads();
  for (int i = i0 + t; i < i1; i += 256) {
    int src, dst;
    if (i < EE) { src = ei[i]; dst = ei[EE + i]; } else { src = i - EE; dst = src; }
    int b = dst >> 7;
    int l = atomicAdd(&lc[b], 1);
    int pos = lb[b] + l;
    if (pos < SCAP) slack[(size_t)b * SCAP + pos] = src | ((dst & 127) << 17);
  }
}

__global__ __launch_bounds__(256) void kb_scan(const int* __restrict__ cnt,
                                               int* __restrict__ off) {
  __shared__ int sh[256];
  int t = threadIdx.x;
  int c[4]; int s = 0;
#pragma unroll
  for (int j = 0; j < 4; ++j) {
    int b = t * 4 + j;
    c[j] = s;
    int v = (b < NBKT) ? cnt[b] : 0;
    s += v;
  }
  sh[t] = s; __syncthreads();
  for (int o = 1; o < 256; o <<= 1) {
    int v = (t >= o) ? sh[t - o] : 0;
    __syncthreads();
    sh[t] += v;
    __syncthreads();
  }
  int excl = sh[t] - s;
#pragma unroll
  for (int j = 0; j < 4; ++j) {
    int b = t * 4 + j;
    if (b < NBKT) off[b] = excl + c[j];
  }
  if (t == 255) off[NBKT] = excl + s;
}

__global__ __launch_bounds__(256) void kb_fin(const int* __restrict__ slack,
                                              const int* __restrict__ off,
                                              int* __restrict__ csr_src,
                                              int* __restrict__ row_ptr) {
  __shared__ int ebuf[SCAP];
  __shared__ int osrc[SCAP];
  __shared__ int cnt[128], scn[128], lcur[128];
  int b = blockIdx.x;
  int base = off[b];
  int count = min(off[b + 1] - base, SCAP);
  int t = threadIdx.x;
  const int* in = slack + (size_t)b * SCAP;
  if (t < 128) { cnt[t] = 0; lcur[t] = 0; }
  __syncthreads();
  for (int i = t; i < count; i += 256) {
    int w = in[i];
    ebuf[i] = w;
    atomicAdd(&cnt[(w >> 17) & 127], 1);
  }
  __syncthreads();
  if (t < 128) scn[t] = cnt[t];
  __syncthreads();
  for (int o = 1; o < 128; o <<= 1) {
    int v = 0;
    if (t < 128 && t >= o) v = scn[t - o];
    __syncthreads();
    if (t < 128) scn[t] += v;
    __syncthreads();
  }
  for (int i = t; i < count; i += 256) {
    int w = ebuf[i];
    int d = (w >> 17) & 127;
    int l = atomicAdd(&lcur[d], 1);
    osrc[(scn[d] - cnt[d]) + l] = w & 0x1FFFF;
  }
  __syncthreads();
  for (int i = t; i < count; i += 256) csr_src[base + i] = osrc[i];
  if (t < 128) {
    int gd = b * 128 + t;
    if (gd <= NN) row_ptr[gd] = base + scn[t] - cnt[t];
  }
}

// ---------------- weight fragment precompute ----------------

__global__ __launch_bounds__(256) void k_wconv(const float* __restrict__ encWl,
                                               const float* __restrict__ encWr,
                                               const float* __restrict__ decWl,
                                               const float* __restrict__ decWr,
                                               const float* __restrict__ Wmu,
                                               const float* __restrict__ Wls,
                                               const float* __restrict__ Wout,
                                               unsigned short* __restrict__ wfh,
                                               unsigned short* __restrict__ wfl) {
  int wid = (blockIdx.x * 256 + threadIdx.x) >> 6;
  int lane = threadIdx.x & 63;
  if (wid >= 19 * 32) return;
  int mat = wid >> 5;
  int sub = wid & 31;
  const float* W;
  if (mat < 4) W = encWl + (size_t)mat * 16384;
  else if (mat < 8) W = encWr + (size_t)(mat - 4) * 16384;
  else if (mat < 12) W = decWl + (size_t)(mat - 8) * 16384;
  else if (mat < 16) W = decWr + (size_t)(mat - 12) * 16384;
  else if (mat == 16) W = Wmu;
  else if (mat == 17) W = Wls;
  else W = Wout;
  int t = sub >> 3, c = sub & 7;
  int col = c * 16 + (lane & 15);
  int k0 = t * 32 + (lane >> 4) * 8;
  bf16x8 vh, vl;
#pragma unroll
  for (int j = 0; j < 8; ++j) {
    float w = W[(size_t)(k0 + j) * 128 + col];
    unsigned short h = f2bf(w);
    vh[j] = (short)h;
    vl[j] = (short)f2bf(w - bf2f(h));
  }
  size_t base = ((size_t)wid * 64 + lane) * 8;
  *(bf16x8*)(wfh + base) = vh;
  *(bf16x8*)(wfl + base) = vl;
}

// ---------------- layer dual GEMM: 1-term bf16, 33.8 KB LDS, sequential outputs ----------

template <int RF32>
__global__ __launch_bounds__(512, 4) void k_mmL(const unsigned short* __restrict__ Ah,
                                                const float* __restrict__ Xf,
                                                const unsigned short* __restrict__ w1,
                                                const unsigned short* __restrict__ w2,
                                                unsigned short* __restrict__ o1,
                                                unsigned short* __restrict__ o2) {
  __shared__ float lds[64 * 132];  // 33.8 KB; also holds 32 KB weight plane
  unsigned short* lw = (unsigned short*)lds;
  int tid = threadIdx.x;
  int wv = tid >> 6, lane = tid & 63;
  int lrow = lane & 15, lk = lane >> 4;
  int row = blockIdx.x * 128 + wv * 16 + lrow;

  // stage w1 (32 KB)
  {
    int4* d = (int4*)lw;
    const int4* s1 = (const int4*)w1;
#pragma unroll
    for (int i = 0; i < 4; ++i) d[tid + i * 512] = s1[tid + i * 512];
  }
  // A fragments (persist across both outputs)
  bf16x8 a_h[4];
  if (RF32) {
#pragma unroll
    for (int t = 0; t < 4; ++t) {
      float4 f0 = {0.f, 0.f, 0.f, 0.f}, f1 = {0.f, 0.f, 0.f, 0.f};
      if (row < NN) {
        const float* xp = Xf + (size_t)row * 128 + t * 32 + lk * 8;
        f0 = *(const float4*)xp;
        f1 = *(const float4*)(xp + 4);
      }
      bf16x8 v;
      v[0] = (short)f2bf(f0.x); v[1] = (short)f2bf(f0.y);
      v[2] = (short)f2bf(f0.z); v[3] = (short)f2bf(f0.w);
      v[4] = (short)f2bf(f1.x); v[5] = (short)f2bf(f1.y);
      v[6] = (short)f2bf(f1.z); v[7] = (short)f2bf(f1.w);
      a_h[t] = v;
    }
  } else {
    const unsigned short* ap = Ah + (size_t)row * 128 + lk * 8;
#pragma unroll
    for (int t = 0; t < 4; ++t) a_h[t] = *(const bf16x8*)(ap + t * 32);
  }
  __syncthreads();

#pragma unroll
  for (int out = 0; out < 2; ++out) {
    if (out == 1) {
      // stage w2 (lds free after previous epilogue)
      int4* d = (int4*)lw;
      const int4* s2 = (const int4*)w2;
#pragma unroll
      for (int i = 0; i < 4; ++i) d[tid + i * 512] = s2[tid + i * 512];
      __syncthreads();
    }
    f32x4 acc[8];
#pragma unroll
    for (int c = 0; c < 8; ++c) acc[c] = (f32x4){0.f, 0.f, 0.f, 0.f};
#pragma unroll
    for (int t = 0; t < 4; ++t) {
#pragma unroll
      for (int c = 0; c < 8; ++c) {
        int fo = ((t * 8 + c) * 64 + lane) * 8;
        bf16x8 wf = *(const bf16x8*)(lw + fo);
        acc[c] = __builtin_amdgcn_mfma_f32_16x16x32_bf16(a_h[t], wf, acc[c], 0, 0, 0);
      }
    }
    __syncthreads();  // weights dead; lds = 64x132 transpose buffer

    unsigned short* dst = out ? o2 : o1;
#pragma unroll
    for (int h = 0; h < 2; ++h) {
      if ((wv >> 2) == h) {
        int lrb = (wv & 3) * 16;
#pragma unroll
        for (int c = 0; c < 8; ++c)
#pragma unroll
          for (int r = 0; r < 4; ++r)
            lds[(lrb + lk * 4 + r) * 132 + c * 16 + lrow] = acc[c][r];
      }
      __syncthreads();
      {
        int lr = tid >> 3, c0 = (tid & 7) * 16;
        size_t o = ((size_t)blockIdx.x * 128 + h * 64 + lr) * 128 + c0;
        const float* sp = &lds[lr * 132 + c0];
#pragma unroll
        for (int i = 0; i < 2; ++i) {
          union { unsigned short u[8]; int4 v; } pk;
#pragma unroll
          for (int j = 0; j < 8; ++j) pk.u[j] = f2bf(sp[i * 8 + j]);
          *(int4*)&dst[o + i * 8] = pk.v;
        }
      }
      __syncthreads();
    }
  }
}

// ---------------- head kernel (512 thr / 128-row, r9-proven, unchanged) ----------------

__global__ __launch_bounds__(512, 3) void k_mmH(const unsigned short* Ah,
                                                const unsigned short* Al,
                                                const unsigned short* __restrict__ w1h,
                                                const unsigned short* __restrict__ w1l,
                                                const unsigned short* __restrict__ w2h,
                                                const unsigned short* __restrict__ w2l,
                                                const float* __restrict__ b1,
                                                const float* __restrict__ b2,
                                                const float* __restrict__ eps,
                                                const float* __restrict__ Wd,
                                                const float* __restrict__ bd,
                                                float* __restrict__ mu,
                                                float* __restrict__ logstd,
                                                float* __restrict__ Z,
                                                unsigned short* Zh,
                                                float* __restrict__ degp) {
  __shared__ float lds[128 * 132];
  unsigned short* lw = (unsigned short*)lds;
  int tid = threadIdx.x;
  int wv = tid >> 6, lane = tid & 63;
  int lrow = lane & 15, lk = lane >> 4;
  int rbase = blockIdx.x * 128 + wv * 16;

  {
    int4* d = (int4*)lw;
#pragma unroll
    for (int i = 0; i < 4; ++i) {
      d[tid + i * 512] = ((const int4*)w1h)[tid + i * 512];
      d[2048 + tid + i * 512] = ((const int4*)w1l)[tid + i * 512];
    }
  }
  bf16x8 a_h[4], a_l[4];
  const unsigned short* ap = Ah + (size_t)(rbase + lrow) * 128 + lk * 8;
  const unsigned short* alp = Al + (size_t)(rbase + lrow) * 128 + lk * 8;
#pragma unroll
  for (int t = 0; t < 4; ++t) {
    a_h[t] = *(const bf16x8*)(ap + t * 32);
    a_l[t] = *(const bf16x8*)(alp + t * 32);
  }
  __syncthreads();

  f32x4 acc1[8];
#pragma unroll
  for (int c = 0; c < 8; ++c) acc1[c] = (f32x4){0.f, 0.f, 0.f, 0.f};
#pragma unroll
  for (int t = 0; t < 4; ++t) {
#pragma unroll
    for (int c = 0; c < 8; ++c) {
      int fo = ((t * 8 + c) * 64 + lane) * 8;
      bf16x8 wh = *(const bf16x8*)(lw + fo);
      bf16x8 wl = *(const bf16x8*)(lw + 16384 + fo);
      acc1[c] = __builtin_amdgcn_mfma_f32_16x16x32_bf16(a_h[t], wh, acc1[c], 0, 0, 0);
      acc1[c] = __builtin_amdgcn_mfma_f32_16x16x32_bf16(a_l[t], wh, acc1[c], 0, 0, 0);
      acc1[c] = __builtin_amdgcn_mfma_f32_16x16x32_bf16(a_h[t], wl, acc1[c], 0, 0, 0);
    }
  }
  __syncthreads();

  {
    int4* d = (int4*)lw;
#pragma unroll
    for (int i = 0; i < 4; ++i) {
      d[tid + i * 512] = ((const int4*)w2h)[tid + i * 512];
      d[2048 + tid + i * 512] = ((const int4*)w2l)[tid + i * 512];
    }
  }
  __syncthreads();

  f32x4 acc2[8];
#pragma unroll
  for (int c = 0; c < 8; ++c) acc2[c] = (f32x4){0.f, 0.f, 0.f, 0.f};
#pragma unroll
  for (int t = 0; t < 4; ++t) {
#pragma unroll
    for (int c = 0; c < 8; ++c) {
      int fo = ((t * 8 + c) * 64 + lane) * 8;
      bf16x8 wh = *(const bf16x8*)(lw + fo);
      bf16x8 wl = *(const bf16x8*)(lw + 16384 + fo);
      acc2[c] = __builtin_amdgcn_mfma_f32_16x16x32_bf16(a_h[t], wh, acc2[c], 0, 0, 0);
      acc2[c] = __builtin_amdgcn_mfma_f32_16x16x32_bf16(a_l[t], wh, acc2[c], 0, 0, 0);
      acc2[c] = __builtin_amdgcn_mfma_f32_16x16x32_bf16(a_h[t], wl, acc2[c], 0, 0, 0);
    }
  }
  __syncthreads();

  int lr = tid >> 2, cb = (tid & 3) << 5;
  int grow = blockIdx.x * 128 + lr;
  size_t o = (size_t)grow * 128 + cb;

#pragma unroll
  for (int c = 0; c < 8; ++c)
#pragma unroll
    for (int r = 0; r < 4; ++r)
      lds[(wv * 16 + lk * 4 + r) * 132 + c * 16 + lrow] = acc1[c][r];
  __syncthreads();
  float4 mureg[8];
  if (grow < NN) {
    const float* sp = &lds[lr * 132 + cb];
#pragma unroll
    for (int i = 0; i < 8; ++i) {
      float4 v = *(const float4*)(sp + i * 4);
      float4 b4 = *(const float4*)&b1[cb + i * 4];
      v.x += b4.x; v.y += b4.y; v.z += b4.z; v.w += b4.w;
      mureg[i] = v;
      *(float4*)&mu[o + i * 4] = v;
    }
  }
  __syncthreads();
#pragma unroll
  for (int c = 0; c < 8; ++c)
#pragma unroll
    for (int r = 0; r < 4; ++r)
      lds[(wv * 16 + lk * 4 + r) * 132 + c * 16 + lrow] = acc2[c][r];
  __syncthreads();
  float s_deg = 0.f;
  if (grow < NN) {
    const float* sp = &lds[lr * 132 + cb];
#pragma unroll
    for (int i = 0; i < 8; ++i) {
      float4 v = *(const float4*)(sp + i * 4);
      float4 b4 = *(const float4*)&b2[cb + i * 4];
      float4 ls;
      ls.x = fminf(v.x + b4.x, 10.f);
      ls.y = fminf(v.y + b4.y, 10.f);
      ls.z = fminf(v.z + b4.z, 10.f);
      ls.w = fminf(v.w + b4.w, 10.f);
      *(float4*)&logstd[o + i * 4] = ls;
      float4 e4 = *(const float4*)&eps[o + i * 4];
      float4 z4;
      z4.x = fmaf(e4.x, expf(ls.x), mureg[i].x);
      z4.y = fmaf(e4.y, expf(ls.y), mureg[i].y);
      z4.z = fmaf(e4.z, expf(ls.z), mureg[i].z);
      z4.w = fmaf(e4.w, expf(ls.w), mureg[i].w);
      *(float4*)&Z[o + i * 4] = z4;
      ushort4 hh;
      hh.x = f2bf(z4.x); hh.y = f2bf(z4.y); hh.z = f2bf(z4.z); hh.w = f2bf(z4.w);
      *(ushort4*)&Zh[o + i * 4] = hh;
      float4 wd = *(const float4*)&Wd[cb + i * 4];
      s_deg += z4.x * wd.x + z4.y * wd.y + z4.z * wd.z + z4.w * wd.w;
    }
  }
  s_deg += __shfl_xor(s_deg, 1);
  s_deg += __shfl_xor(s_deg, 2);
  if (grow < NN && (tid & 3) == 0) degp[grow] = s_deg + bd[0];
}

// ---------------- output GEMM: A_h@(Wh+Wl)+b, 33.8 KB LDS, sequential W planes ---------

__global__ __launch_bounds__(512, 4) void k_mmO(const unsigned short* __restrict__ Ah,
                                                const unsigned short* __restrict__ wh,
                                                const unsigned short* __restrict__ wl,
                                                const float* __restrict__ bias,
                                                float* __restrict__ C) {
  __shared__ float lds[64 * 132];
  unsigned short* lw = (unsigned short*)lds;
  int tid = threadIdx.x;
  int wv = tid >> 6, lane = tid & 63;
  int lrow = lane & 15, lk = lane >> 4;
  int row = blockIdx.x * 128 + wv * 16 + lrow;

  {
    int4* d = (int4*)lw;
    const int4* s1 = (const int4*)wh;
#pragma unroll
    for (int i = 0; i < 4; ++i) d[tid + i * 512] = s1[tid + i * 512];
  }
  bf16x8 a_h[4];
  const unsigned short* ap = Ah + (size_t)row * 128 + lk * 8;
#pragma unroll
  for (int t = 0; t < 4; ++t) a_h[t] = *(const bf16x8*)(ap + t * 32);
  __syncthreads();

  f32x4 acc[8];
#pragma unroll
  for (int c = 0; c < 8; ++c) acc[c] = (f32x4){0.f, 0.f, 0.f, 0.f};
#pragma unroll
  for (int t = 0; t < 4; ++t) {
#pragma unroll
    for (int c = 0; c < 8; ++c) {
      int fo = ((t * 8 + c) * 64 + lane) * 8;
      bf16x8 wf = *(const bf16x8*)(lw + fo);
      acc[c] = __builtin_amdgcn_mfma_f32_16x16x32_bf16(a_h[t], wf, acc[c], 0, 0, 0);
    }
  }
  __syncthreads();
  {
    int4* d = (int4*)lw;
    const int4* s2 = (const int4*)wl;
#pragma unroll
    for (int i = 0; i < 4; ++i) d[tid + i * 512] = s2[tid + i * 512];
  }
  __syncthreads();
#pragma unroll
  for (int t = 0; t < 4; ++t) {
#pragma unroll
    for (int c = 0; c < 8; ++c) {
      int fo = ((t * 8 + c) * 64 + lane) * 8;
      bf16x8 wf = *(const bf16x8*)(lw + fo);
      acc[c] = __builtin_amdgcn_mfma_f32_16x16x32_bf16(a_h[t], wf, acc[c], 0, 0, 0);
    }
  }
  __syncthreads();

#pragma unroll
  for (int h = 0; h < 2; ++h) {
    if ((wv >> 2) == h) {
      int lrb = (wv & 3) * 16;
#pragma unroll
      for (int c = 0; c < 8; ++c)
#pragma unroll
        for (int r = 0; r < 4; ++r)
          lds[(lrb + lk * 4 + r) * 132 + c * 16 + lrow] = acc[c][r];
    }
    __syncthreads();
    {
      int lr = tid >> 3, c0 = (tid & 7) * 16;
      int grow = blockIdx.x * 128 + h * 64 + lr;
      if (grow < NN) {
        size_t o = (size_t)grow * 128 + c0;
        const float* sp = &lds[lr * 132 + c0];
#pragma unroll
        for (int i = 0; i < 4; ++i) {
          float4 v = *(const float4*)(sp + i * 4);
          float4 b4 = *(const float4*)&bias[c0 + i * 4];
          v.x += b4.x; v.y += b4.y; v.z += b4.z; v.w += b4.w;
          *(float4*)&C[o + i * 4] = v;
        }
      }
    }
    __syncthreads();
  }
}

// ---------------- GATv2 aggregation: wave/row, 4x16 lanes, bf16 gathers ----------------

template <int WLO>
__global__ __launch_bounds__(256) void k_gat_agg(const unsigned short* __restrict__ gxl,
                                                 const unsigned short* __restrict__ gxr,
                                                 const float* __restrict__ att,
                                                 const float* __restrict__ bias,
                                                 const int* __restrict__ row_ptr,
                                                 const int* __restrict__ csr_src,
                                                 unsigned short* __restrict__ sh,
                                                 unsigned short* __restrict__ sl) {
  int gid = blockIdx.x * blockDim.x + threadIdx.x;
  int row = gid >> 6;
  int lane = gid & 63;
  if (row >= NN) return;
  int g = lane >> 4, j = lane & 15;
  int dbase = j * 8;

  float a[8], r[8];
  {
    float4 a0 = *(const float4*)&att[dbase];
    float4 a1 = *(const float4*)&att[dbase + 4];
    a[0] = a0.x; a[1] = a0.y; a[2] = a0.z; a[3] = a0.w;
    a[4] = a1.x; a[5] = a1.y; a[6] = a1.z; a[7] = a1.w;
    bf16x8 rv = *(const bf16x8*)&gxr[(size_t)row * 128 + dbase];
#pragma unroll
    for (int k = 0; k < 8; ++k) r[k] = bf2f((unsigned short)rv[k]);
  }

  float m = -INFINITY, d = 0.f;
  float acc[8] = {0.f, 0.f, 0.f, 0.f, 0.f, 0.f, 0.f, 0.f};
  int p0 = row_ptr[row], p1 = row_ptr[row + 1];

  for (int p = p0 + g; p < p1; p += 4) {
    int s = csr_src[p];
    bf16x8 xv = *(const bf16x8*)&gxl[(size_t)s * 128 + dbase];
    float v[8];
#pragma unroll
    for (int k = 0; k < 8; ++k) v[k] = bf2f((unsigned short)xv[k]);

    float e = 0.f;
#pragma unroll
    for (int k = 0; k < 8; ++k) {
      float t0 = v[k] + r[k];
      t0 = fmaxf(t0, 0.2f * t0);
      e = fmaf(t0, a[k], e);
    }
    e += __shfl_xor(e, 1);
    e += __shfl_xor(e, 2);
    e += __shfl_xor(e, 4);
    e += __shfl_xor(e, 8);

    float mn = fmaxf(m, e);
    float scl = __expf(m - mn);
    float w = __expf(e - mn);
    d = d * scl + w;
#pragma unroll
    for (int k = 0; k < 8; ++k) acc[k] = acc[k] * scl + w * v[k];
    m = mn;
  }

  float mo = fmaxf(m, __shfl_xor(m, 16));
  mo = fmaxf(mo, __shfl_xor(mo, 32));
  float scl = __expf(m - mo);
  d *= scl;
  d += __shfl_xor(d, 16);
  d += __shfl_xor(d, 32);
#pragma unroll
  for (int k = 0; k < 8; ++k) {
    acc[k] *= scl;
    acc[k] += __shfl_xor(acc[k], 16);
    acc[k] += __shfl_xor(acc[k], 32);
  }

  if (g == 0) {
    float inv = 1.f / d;
    float4 b0 = *(const float4*)&bias[dbase];
    float4 b1v = *(const float4*)&bias[dbase + 4];
    float bb[8] = {b0.x, b0.y, b0.z, b0.w, b1v.x, b1v.y, b1v.z, b1v.w};
    bf16x8 vh, vl;
#pragma unroll
    for (int k = 0; k < 8; ++k) {
      float h = gelu_exact(acc[k] * inv + bb[k]);
      unsigned short hi = f2bf(h);
      vh[k] = (short)hi;
      if (WLO) vl[k] = (short)f2bf(h - bf2f(hi));
    }
    *(bf16x8*)(sh + (size_t)row * 128 + dbase) = vh;
    if (WLO) *(bf16x8*)(sl + (size_t)row * 128 + dbase) = vl;
  }
}

// ---------------- host ----------------

static inline char* take(char*& p, size_t bytes) {
  char* r = p;
  p += (bytes + 255) & ~(size_t)255;
  return r;
}

extern "C" void kernel_launch(void* const* d_in, const int* in_sizes, int n_in,
                              void* d_out, int out_size, void* d_ws, size_t ws_size,
                              hipStream_t stream) {
  const float* x      = (const float*)d_in[0];
  const int*   ei     = (const int*)d_in[1];
  const float* eps    = (const float*)d_in[2];
  const float* encWl  = (const float*)d_in[3];
  const float* encWr  = (const float*)d_in[4];
  const float* encAtt = (const float*)d_in[5];
  const float* encB   = (const float*)d_in[6];
  const float* decWl  = (const float*)d_in[7];
  const float* decWr  = (const float*)d_in[8];
  const float* decAtt = (const float*)d_in[9];
  const float* decB   = (const float*)d_in[10];
  const float* W_mu   = (const float*)d_in[11];
  const float* b_mu   = (const float*)d_in[12];
  const float* W_ls   = (const float*)d_in[13];
  const float* b_ls   = (const float*)d_in[14];
  const float* W_out  = (const float*)d_in[15];
  const float* b_out  = (const float*)d_in[16];
  const float* W_deg  = (const float*)d_in[17];
  const float* b_deg  = (const float*)d_in[18];

  float* out    = (float*)d_out;
  float* x_rec  = out;
  float* z      = out + (size_t)ND;
  float* mu     = out + (size_t)2 * ND;
  float* logstd = out + (size_t)3 * ND;
  float* degp   = out + (size_t)4 * ND;

  char* p = (char*)d_ws;
  int* bktcnt  = (int*)take(p, 1024 * 4);
  int* bktoff  = (int*)take(p, 1024 * 4);
  int* slack   = (int*)take(p, (size_t)NBKT * SCAP * 4);
  int* row_ptr = (int*)take(p, (size_t)(NN + 1) * 4);
  int* csr_src = (int*)take(p, (size_t)ET * 4);
  unsigned short* gxl  = (unsigned short*)take(p, (size_t)MPAD * 128 * 2);
  unsigned short* gxr  = (unsigned short*)take(p, (size_t)MPAD * 128 * 2);
  unsigned short* stgh = (unsigned short*)take(p, (size_t)MPAD * 128 * 2);
  unsigned short* stgl = (unsigned short*)take(p, (size_t)MPAD * 128 * 2);
  unsigned short* wfh  = (unsigned short*)take(p, (size_t)19 * 16384 * 2);
  unsigned short* wfl  = (unsigned short*)take(p, (size_t)19 * 16384 * 2);

  const int gMM   = MPAD / 128;             // 782
  const int gWave = (NN * 64 + 255) / 256;  // 25000

  // CSR build (slack scatter)
  k_zero_int<<<4, 256, 0, stream>>>(bktcnt, 1024);
  kb_scatter<<<GSC, 256, 0, stream>>>(ei, bktcnt, slack);
  kb_scan<<<1, 256, 0, stream>>>(bktcnt, bktoff);
  kb_fin<<<NBKT, 256, 0, stream>>>(slack, bktoff, csr_src, row_ptr);

  // weight frags
  k_wconv<<<152, 256, 0, stream>>>(encWl, encWr, decWl, decWr, W_mu, W_ls, W_out, wfh, wfl);

  const size_t WM = 16384;
  // encoder (layer 0 reads fp32 x directly)
  for (int l = 0; l < 4; ++l) {
    if (l == 0)
      k_mmL<1><<<gMM, 512, 0, stream>>>(nullptr, x,
                                        wfh + (size_t)l * WM, wfh + (size_t)(4 + l) * WM,
                                        gxl, gxr);
    else
      k_mmL<0><<<gMM, 512, 0, stream>>>(stgh, nullptr,
                                        wfh + (size_t)l * WM, wfh + (size_t)(4 + l) * WM,
                                        gxl, gxr);
    if (l < 3)
      k_gat_agg<0><<<gWave, 256, 0, stream>>>(gxl, gxr, encAtt + (size_t)l * DD,
                                              encB + (size_t)l * DD, row_ptr, csr_src,
                                              stgh, stgl);
    else
      k_gat_agg<1><<<gWave, 256, 0, stream>>>(gxl, gxr, encAtt + (size_t)l * DD,
                                              encB + (size_t)l * DD, row_ptr, csr_src,
                                              stgh, stgl);
  }

  // heads
  k_mmH<<<gMM, 512, 0, stream>>>(stgh, stgl,
                                 wfh + (size_t)16 * WM, wfl + (size_t)16 * WM,
                                 wfh + (size_t)17 * WM, wfl + (size_t)17 * WM,
                                 b_mu, b_ls, eps, W_deg, b_deg,
                                 mu, logstd, z, stgh, degp);

  // decoder
  for (int l = 0; l < 4; ++l) {
    k_mmL<0><<<gMM, 512, 0, stream>>>(stgh, nullptr,
                                      wfh + (size_t)(8 + l) * WM, wfh + (size_t)(12 + l) * WM,
                                      gxl, gxr);
    k_gat_agg<0><<<gWave, 256, 0, stream>>>(gxl, gxr, decAtt + (size_t)l * DD,
                                            decB + (size_t)l * DD, row_ptr, csr_src,
                                            stgh, stgl);
  }

  // x_rec
  k_mmO<<<gMM, 512, 0, stream>>>(stgh,
                                 wfh + (size_t)18 * WM, wfl + (size_t)18 * WM,
                                 b_out, x_rec);
}

// Round 14
// 1182.064 us; speedup vs baseline: 1.2166x; 1.0666x over previous
//
#include <hip/hip_runtime.h>
#include <math.h>

#define NN 100000
#define MPAD 100096
#define DD 128
#define EE 1600000
#define ET (EE + NN)
#define ND (NN * DD)

#define NBKT 782
#define IPB 4096
#define GSC 416
#define SCAP 4096

typedef short bf16x8 __attribute__((ext_vector_type(8)));
typedef float f32x4 __attribute__((ext_vector_type(4)));

static __device__ __forceinline__ unsigned short f2bf(float f) {
  unsigned int u = __float_as_uint(f);
  u += 0x7FFFu + ((u >> 16) & 1u);
  return (unsigned short)(u >> 16);
}
static __device__ __forceinline__ float bf2f(unsigned short h) {
  return __uint_as_float(((unsigned int)h) << 16);
}
static __device__ __forceinline__ float gelu_exact(float v) {
  return 0.5f * v * (1.f + erff(v * 0.7071067811865476f));
}

// ---------------- CSR build: slack-bucket counting sort ----------------

__global__ void k_zero_int(int* __restrict__ p, int n) {
  int i = blockIdx.x * blockDim.x + threadIdx.x;
  if (i < n) p[i] = 0;
}

__global__ __launch_bounds__(256) void kb_scatter(const int* __restrict__ ei,
                                                  int* __restrict__ cnt,
                                                  int* __restrict__ slack) {
  __shared__ int lc[NBKT];
  __shared__ int lb[NBKT];
  int t = threadIdx.x;
  for (int b = t; b < NBKT; b += 256) lc[b] = 0;
  __syncthreads();
  int i0 = blockIdx.x * IPB;
  int i1 = min(i0 + IPB, ET);
  for (int i = i0 + t; i < i1; i += 256) {
    int dst = (i < EE) ? ei[EE + i] : (i - EE);
    atomicAdd(&lc[dst >> 7], 1);
  }
  __syncthreads();
  for (int b = t; b < NBKT; b += 256) {
    int c = lc[b];
    lb[b] = c ? atomicAdd(&cnt[b], c) : 0;
    lc[b] = 0;
  }
  __syncthreads();
  for (int i = i0 + t; i < i1; i += 256) {
    int src, dst;
    if (i < EE) { src = ei[i]; dst = ei[EE + i]; } else { src = i - EE; dst = src; }
    int b = dst >> 7;
    int l = atomicAdd(&lc[b], 1);
    int pos = lb[b] + l;
    if (pos < SCAP) slack[(size_t)b * SCAP + pos] = src | ((dst & 127) << 17);
  }
}

__global__ __launch_bounds__(256) void kb_scan(const int* __restrict__ cnt,
                                               int* __restrict__ off) {
  __shared__ int sh[256];
  int t = threadIdx.x;
  int c[4]; int s = 0;
#pragma unroll
  for (int j = 0; j < 4; ++j) {
    int b = t * 4 + j;
    c[j] = s;
    int v = (b < NBKT) ? cnt[b] : 0;
    s += v;
  }
  sh[t] = s; __syncthreads();
  for (int o = 1; o < 256; o <<= 1) {
    int v = (t >= o) ? sh[t - o] : 0;
    __syncthreads();
    sh[t] += v;
    __syncthreads();
  }
  int excl = sh[t] - s;
#pragma unroll
  for (int j = 0; j < 4; ++j) {
    int b = t * 4 + j;
    if (b < NBKT) off[b] = excl + c[j];
  }
  if (t == 255) off[NBKT] = excl + s;
}

__global__ __launch_bounds__(256) void kb_fin(const int* __restrict__ slack,
                                              const int* __restrict__ off,
                                              int* __restrict__ csr_src,
                                              int* __restrict__ row_ptr) {
  __shared__ int ebuf[SCAP];
  __shared__ int osrc[SCAP];
  __shared__ int cnt[128], scn[128], lcur[128];
  int b = blockIdx.x;
  int base = off[b];
  int count = min(off[b + 1] - base, SCAP);
  int t = threadIdx.x;
  const int* in = slack + (size_t)b * SCAP;
  if (t < 128) { cnt[t] = 0; lcur[t] = 0; }
  __syncthreads();
  for (int i = t; i < count; i += 256) {
    int w = in[i];
    ebuf[i] = w;
    atomicAdd(&cnt[(w >> 17) & 127], 1);
  }
  __syncthreads();
  if (t < 128) scn[t] = cnt[t];
  __syncthreads();
  for (int o = 1; o < 128; o <<= 1) {
    int v = 0;
    if (t < 128 && t >= o) v = scn[t - o];
    __syncthreads();
    if (t < 128) scn[t] += v;
    __syncthreads();
  }
  for (int i = t; i < count; i += 256) {
    int w = ebuf[i];
    int d = (w >> 17) & 127;
    int l = atomicAdd(&lcur[d], 1);
    osrc[(scn[d] - cnt[d]) + l] = w & 0x1FFFF;
  }
  __syncthreads();
  for (int i = t; i < count; i += 256) csr_src[base + i] = osrc[i];
  if (t < 128) {
    int gd = b * 128 + t;
    if (gd <= NN) row_ptr[gd] = base + scn[t] - cnt[t];
  }
}

// ---------------- weight fragment precompute ----------------

__global__ __launch_bounds__(256) void k_wconv(const float* __restrict__ encWl,
                                               const float* __restrict__ encWr,
                                               const float* __restrict__ decWl,
                                               const float* __restrict__ decWr,
                                               const float* __restrict__ Wmu,
                                               const float* __restrict__ Wls,
                                               const float* __restrict__ Wout,
                                               unsigned short* __restrict__ wfh,
                                               unsigned short* __restrict__ wfl) {
  int wid = (blockIdx.x * 256 + threadIdx.x) >> 6;
  int lane = threadIdx.x & 63;
  if (wid >= 19 * 32) return;
  int mat = wid >> 5;
  int sub = wid & 31;
  const float* W;
  if (mat < 4) W = encWl + (size_t)mat * 16384;
  else if (mat < 8) W = encWr + (size_t)(mat - 4) * 16384;
  else if (mat < 12) W = decWl + (size_t)(mat - 8) * 16384;
  else if (mat < 16) W = decWr + (size_t)(mat - 12) * 16384;
  else if (mat == 16) W = Wmu;
  else if (mat == 17) W = Wls;
  else W = Wout;
  int t = sub >> 3, c = sub & 7;
  int col = c * 16 + (lane & 15);
  int k0 = t * 32 + (lane >> 4) * 8;
  bf16x8 vh, vl;
#pragma unroll
  for (int j = 0; j < 8; ++j) {
    float w = W[(size_t)(k0 + j) * 128 + col];
    unsigned short h = f2bf(w);
    vh[j] = (short)h;
    vl[j] = (short)f2bf(w - bf2f(h));
  }
  size_t base = ((size_t)wid * 64 + lane) * 8;
  *(bf16x8*)(wfh + base) = vh;
  *(bf16x8*)(wfl + base) = vl;
}

// ---------------- layer dual GEMM: 1-term bf16, 33.8 KB LDS, sequential outputs ----------

template <int RF32>
__global__ __launch_bounds__(512, 4) void k_mmL(const unsigned short* __restrict__ Ah,
                                                const float* __restrict__ Xf,
                                                const unsigned short* __restrict__ w1,
                                                const unsigned short* __restrict__ w2,
                                                unsigned short* __restrict__ o1,
                                                unsigned short* __restrict__ o2) {
  __shared__ float lds[64 * 132];
  unsigned short* lw = (unsigned short*)lds;
  int tid = threadIdx.x;
  int wv = tid >> 6, lane = tid & 63;
  int lrow = lane & 15, lk = lane >> 4;
  int row = blockIdx.x * 128 + wv * 16 + lrow;

  {
    int4* d = (int4*)lw;
    const int4* s1 = (const int4*)w1;
#pragma unroll
    for (int i = 0; i < 4; ++i) d[tid + i * 512] = s1[tid + i * 512];
  }
  bf16x8 a_h[4];
  if (RF32) {
#pragma unroll
    for (int t = 0; t < 4; ++t) {
      float4 f0 = {0.f, 0.f, 0.f, 0.f}, f1 = {0.f, 0.f, 0.f, 0.f};
      if (row < NN) {
        const float* xp = Xf + (size_t)row * 128 + t * 32 + lk * 8;
        f0 = *(const float4*)xp;
        f1 = *(const float4*)(xp + 4);
      }
      bf16x8 v;
      v[0] = (short)f2bf(f0.x); v[1] = (short)f2bf(f0.y);
      v[2] = (short)f2bf(f0.z); v[3] = (short)f2bf(f0.w);
      v[4] = (short)f2bf(f1.x); v[5] = (short)f2bf(f1.y);
      v[6] = (short)f2bf(f1.z); v[7] = (short)f2bf(f1.w);
      a_h[t] = v;
    }
  } else {
    const unsigned short* ap = Ah + (size_t)row * 128 + lk * 8;
#pragma unroll
    for (int t = 0; t < 4; ++t) a_h[t] = *(const bf16x8*)(ap + t * 32);
  }
  __syncthreads();

#pragma unroll
  for (int out = 0; out < 2; ++out) {
    if (out == 1) {
      int4* d = (int4*)lw;
      const int4* s2 = (const int4*)w2;
#pragma unroll
      for (int i = 0; i < 4; ++i) d[tid + i * 512] = s2[tid + i * 512];
      __syncthreads();
    }
    f32x4 acc[8];
#pragma unroll
    for (int c = 0; c < 8; ++c) acc[c] = (f32x4){0.f, 0.f, 0.f, 0.f};
#pragma unroll
    for (int t = 0; t < 4; ++t) {
#pragma unroll
      for (int c = 0; c < 8; ++c) {
        int fo = ((t * 8 + c) * 64 + lane) * 8;
        bf16x8 wf = *(const bf16x8*)(lw + fo);
        acc[c] = __builtin_amdgcn_mfma_f32_16x16x32_bf16(a_h[t], wf, acc[c], 0, 0, 0);
      }
    }
    __syncthreads();

    unsigned short* dst = out ? o2 : o1;
#pragma unroll
    for (int h = 0; h < 2; ++h) {
      if ((wv >> 2) == h) {
        int lrb = (wv & 3) * 16;
#pragma unroll
        for (int c = 0; c < 8; ++c)
#pragma unroll
          for (int r = 0; r < 4; ++r)
            lds[(lrb + lk * 4 + r) * 132 + c * 16 + lrow] = acc[c][r];
      }
      __syncthreads();
      {
        int lr = tid >> 3, c0 = (tid & 7) * 16;
        size_t o = ((size_t)blockIdx.x * 128 + h * 64 + lr) * 128 + c0;
        const float* sp = &lds[lr * 132 + c0];
#pragma unroll
        for (int i = 0; i < 2; ++i) {
          union { unsigned short u[8]; int4 v; } pk;
#pragma unroll
          for (int j = 0; j < 8; ++j) pk.u[j] = f2bf(sp[i * 8 + j]);
          *(int4*)&dst[o + i * 8] = pk.v;
        }
      }
      __syncthreads();
    }
  }
}

// ---------------- head kernel: 2-term (a_h only), mu/ls/z/z-stage/deg ----------------

__global__ __launch_bounds__(512, 3) void k_mmH(const unsigned short* Ah,
                                                const unsigned short* __restrict__ w1h,
                                                const unsigned short* __restrict__ w1l,
                                                const unsigned short* __restrict__ w2h,
                                                const unsigned short* __restrict__ w2l,
                                                const float* __restrict__ b1,
                                                const float* __restrict__ b2,
                                                const float* __restrict__ eps,
                                                const float* __restrict__ Wd,
                                                const float* __restrict__ bd,
                                                float* __restrict__ mu,
                                                float* __restrict__ logstd,
                                                float* __restrict__ Z,
                                                unsigned short* Zh,
                                                float* __restrict__ degp) {
  __shared__ float lds[128 * 132];
  unsigned short* lw = (unsigned short*)lds;
  int tid = threadIdx.x;
  int wv = tid >> 6, lane = tid & 63;
  int lrow = lane & 15, lk = lane >> 4;
  int rbase = blockIdx.x * 128 + wv * 16;

  {
    int4* d = (int4*)lw;
#pragma unroll
    for (int i = 0; i < 4; ++i) {
      d[tid + i * 512] = ((const int4*)w1h)[tid + i * 512];
      d[2048 + tid + i * 512] = ((const int4*)w1l)[tid + i * 512];
    }
  }
  bf16x8 a_h[4];
  const unsigned short* ap = Ah + (size_t)(rbase + lrow) * 128 + lk * 8;
#pragma unroll
  for (int t = 0; t < 4; ++t) a_h[t] = *(const bf16x8*)(ap + t * 32);
  __syncthreads();

  f32x4 acc1[8];
#pragma unroll
  for (int c = 0; c < 8; ++c) acc1[c] = (f32x4){0.f, 0.f, 0.f, 0.f};
#pragma unroll
  for (int t = 0; t < 4; ++t) {
#pragma unroll
    for (int c = 0; c < 8; ++c) {
      int fo = ((t * 8 + c) * 64 + lane) * 8;
      bf16x8 wh = *(const bf16x8*)(lw + fo);
      bf16x8 wl = *(const bf16x8*)(lw + 16384 + fo);
      acc1[c] = __builtin_amdgcn_mfma_f32_16x16x32_bf16(a_h[t], wh, acc1[c], 0, 0, 0);
      acc1[c] = __builtin_amdgcn_mfma_f32_16x16x32_bf16(a_h[t], wl, acc1[c], 0, 0, 0);
    }
  }
  __syncthreads();

  {
    int4* d = (int4*)lw;
#pragma unroll
    for (int i = 0; i < 4; ++i) {
      d[tid + i * 512] = ((const int4*)w2h)[tid + i * 512];
      d[2048 + tid + i * 512] = ((const int4*)w2l)[tid + i * 512];
    }
  }
  __syncthreads();

  f32x4 acc2[8];
#pragma unroll
  for (int c = 0; c < 8; ++c) acc2[c] = (f32x4){0.f, 0.f, 0.f, 0.f};
#pragma unroll
  for (int t = 0; t < 4; ++t) {
#pragma unroll
    for (int c = 0; c < 8; ++c) {
      int fo = ((t * 8 + c) * 64 + lane) * 8;
      bf16x8 wh = *(const bf16x8*)(lw + fo);
      bf16x8 wl = *(const bf16x8*)(lw + 16384 + fo);
      acc2[c] = __builtin_amdgcn_mfma_f32_16x16x32_bf16(a_h[t], wh, acc2[c], 0, 0, 0);
      acc2[c] = __builtin_amdgcn_mfma_f32_16x16x32_bf16(a_h[t], wl, acc2[c], 0, 0, 0);
    }
  }
  __syncthreads();

  int lr = tid >> 2, cb = (tid & 3) << 5;
  int grow = blockIdx.x * 128 + lr;
  size_t o = (size_t)grow * 128 + cb;

#pragma unroll
  for (int c = 0; c < 8; ++c)
#pragma unroll
    for (int r = 0; r < 4; ++r)
      lds[(wv * 16 + lk * 4 + r) * 132 + c * 16 + lrow] = acc1[c][r];
  __syncthreads();
  float4 mureg[8];
  if (grow < NN) {
    const float* sp = &lds[lr * 132 + cb];
#pragma unroll
    for (int i = 0; i < 8; ++i) {
      float4 v = *(const float4*)(sp + i * 4);
      float4 b4 = *(const float4*)&b1[cb + i * 4];
      v.x += b4.x; v.y += b4.y; v.z += b4.z; v.w += b4.w;
      mureg[i] = v;
      *(float4*)&mu[o + i * 4] = v;
    }
  }
  __syncthreads();
#pragma unroll
  for (int c = 0; c < 8; ++c)
#pragma unroll
    for (int r = 0; r < 4; ++r)
      lds[(wv * 16 + lk * 4 + r) * 132 + c * 16 + lrow] = acc2[c][r];
  __syncthreads();
  float s_deg = 0.f;
  if (grow < NN) {
    const float* sp = &lds[lr * 132 + cb];
#pragma unroll
    for (int i = 0; i < 8; ++i) {
      float4 v = *(const float4*)(sp + i * 4);
      float4 b4 = *(const float4*)&b2[cb + i * 4];
      float4 ls;
      ls.x = fminf(v.x + b4.x, 10.f);
      ls.y = fminf(v.y + b4.y, 10.f);
      ls.z = fminf(v.z + b4.z, 10.f);
      ls.w = fminf(v.w + b4.w, 10.f);
      *(float4*)&logstd[o + i * 4] = ls;
      float4 e4 = *(const float4*)&eps[o + i * 4];
      float4 z4;
      z4.x = fmaf(e4.x, expf(ls.x), mureg[i].x);
      z4.y = fmaf(e4.y, expf(ls.y), mureg[i].y);
      z4.z = fmaf(e4.z, expf(ls.z), mureg[i].z);
      z4.w = fmaf(e4.w, expf(ls.w), mureg[i].w);
      *(float4*)&Z[o + i * 4] = z4;
      ushort4 hh;
      hh.x = f2bf(z4.x); hh.y = f2bf(z4.y); hh.z = f2bf(z4.z); hh.w = f2bf(z4.w);
      *(ushort4*)&Zh[o + i * 4] = hh;
      float4 wd = *(const float4*)&Wd[cb + i * 4];
      s_deg += z4.x * wd.x + z4.y * wd.y + z4.z * wd.z + z4.w * wd.w;
    }
  }
  s_deg += __shfl_xor(s_deg, 1);
  s_deg += __shfl_xor(s_deg, 2);
  if (grow < NN && (tid & 3) == 0) degp[grow] = s_deg + bd[0];
}

// ---------------- output GEMM: A_h@(Wh+Wl)+b, 33.8 KB LDS ----------------

__global__ __launch_bounds__(512, 4) void k_mmO(const unsigned short* __restrict__ Ah,
                                                const unsigned short* __restrict__ wh,
                                                const unsigned short* __restrict__ wl,
                                                const float* __restrict__ bias,
                                                float* __restrict__ C) {
  __shared__ float lds[64 * 132];
  unsigned short* lw = (unsigned short*)lds;
  int tid = threadIdx.x;
  int wv = tid >> 6, lane = tid & 63;
  int lrow = lane & 15, lk = lane >> 4;
  int row = blockIdx.x * 128 + wv * 16 + lrow;

  {
    int4* d = (int4*)lw;
    const int4* s1 = (const int4*)wh;
#pragma unroll
    for (int i = 0; i < 4; ++i) d[tid + i * 512] = s1[tid + i * 512];
  }
  bf16x8 a_h[4];
  const unsigned short* ap = Ah + (size_t)row * 128 + lk * 8;
#pragma unroll
  for (int t = 0; t < 4; ++t) a_h[t] = *(const bf16x8*)(ap + t * 32);
  __syncthreads();

  f32x4 acc[8];
#pragma unroll
  for (int c = 0; c < 8; ++c) acc[c] = (f32x4){0.f, 0.f, 0.f, 0.f};
#pragma unroll
  for (int t = 0; t < 4; ++t) {
#pragma unroll
    for (int c = 0; c < 8; ++c) {
      int fo = ((t * 8 + c) * 64 + lane) * 8;
      bf16x8 wf = *(const bf16x8*)(lw + fo);
      acc[c] = __builtin_amdgcn_mfma_f32_16x16x32_bf16(a_h[t], wf, acc[c], 0, 0, 0);
    }
  }
  __syncthreads();
  {
    int4* d = (int4*)lw;
    const int4* s2 = (const int4*)wl;
#pragma unroll
    for (int i = 0; i < 4; ++i) d[tid + i * 512] = s2[tid + i * 512];
  }
  __syncthreads();
#pragma unroll
  for (int t = 0; t < 4; ++t) {
#pragma unroll
    for (int c = 0; c < 8; ++c) {
      int fo = ((t * 8 + c) * 64 + lane) * 8;
      bf16x8 wf = *(const bf16x8*)(lw + fo);
      acc[c] = __builtin_amdgcn_mfma_f32_16x16x32_bf16(a_h[t], wf, acc[c], 0, 0, 0);
    }
  }
  __syncthreads();

#pragma unroll
  for (int h = 0; h < 2; ++h) {
    if ((wv >> 2) == h) {
      int lrb = (wv & 3) * 16;
#pragma unroll
      for (int c = 0; c < 8; ++c)
#pragma unroll
        for (int r = 0; r < 4; ++r)
          lds[(lrb + lk * 4 + r) * 132 + c * 16 + lrow] = acc[c][r];
    }
    __syncthreads();
    {
      int lr = tid >> 3, c0 = (tid & 7) * 16;
      int grow = blockIdx.x * 128 + h * 64 + lr;
      if (grow < NN) {
        size_t o = (size_t)grow * 128 + c0;
        const float* sp = &lds[lr * 132 + c0];
#pragma unroll
        for (int i = 0; i < 4; ++i) {
          float4 v = *(const float4*)(sp + i * 4);
          float4 b4 = *(const float4*)&bias[c0 + i * 4];
          v.x += b4.x; v.y += b4.y; v.z += b4.z; v.w += b4.w;
          *(float4*)&C[o + i * 4] = v;
        }
      }
    }
    __syncthreads();
  }
}

// ---------------- GATv2 aggregation: wave/row, 4x16 lanes, bf16 gathers ----------------

__global__ __launch_bounds__(256) void k_gat_agg(const unsigned short* __restrict__ gxl,
                                                 const unsigned short* __restrict__ gxr,
                                                 const float* __restrict__ att,
                                                 const float* __restrict__ bias,
                                                 const int* __restrict__ row_ptr,
                                                 const int* __restrict__ csr_src,
                                                 unsigned short* __restrict__ sh) {
  int gid = blockIdx.x * blockDim.x + threadIdx.x;
  int row = gid >> 6;
  int lane = gid & 63;
  if (row >= NN) return;
  int g = lane >> 4, j = lane & 15;
  int dbase = j * 8;

  float a[8], r[8];
  {
    float4 a0 = *(const float4*)&att[dbase];
    float4 a1 = *(const float4*)&att[dbase + 4];
    a[0] = a0.x; a[1] = a0.y; a[2] = a0.z; a[3] = a0.w;
    a[4] = a1.x; a[5] = a1.y; a[6] = a1.z; a[7] = a1.w;
    bf16x8 rv = *(const bf16x8*)&gxr[(size_t)row * 128 + dbase];
#pragma unroll
    for (int k = 0; k < 8; ++k) r[k] = bf2f((unsigned short)rv[k]);
  }

  float m = -INFINITY, d = 0.f;
  float acc[8] = {0.f, 0.f, 0.f, 0.f, 0.f, 0.f, 0.f, 0.f};
  int p0 = row_ptr[row], p1 = row_ptr[row + 1];

  for (int p = p0 + g; p < p1; p += 4) {
    int s = csr_src[p];
    bf16x8 xv = *(const bf16x8*)&gxl[(size_t)s * 128 + dbase];
    float v[8];
#pragma unroll
    for (int k = 0; k < 8; ++k) v[k] = bf2f((unsigned short)xv[k]);

    float e = 0.f;
#pragma unroll
    for (int k = 0; k < 8; ++k) {
      float t0 = v[k] + r[k];
      t0 = fmaxf(t0, 0.2f * t0);
      e = fmaf(t0, a[k], e);
    }
    e += __shfl_xor(e, 1);
    e += __shfl_xor(e, 2);
    e += __shfl_xor(e, 4);
    e += __shfl_xor(e, 8);

    float mn = fmaxf(m, e);
    float scl = __expf(m - mn);
    float w = __expf(e - mn);
    d = d * scl + w;
#pragma unroll
    for (int k = 0; k < 8; ++k) acc[k] = acc[k] * scl + w * v[k];
    m = mn;
  }

  float mo = fmaxf(m, __shfl_xor(m, 16));
  mo = fmaxf(mo, __shfl_xor(mo, 32));
  float scl = __expf(m - mo);
  d *= scl;
  d += __shfl_xor(d, 16);
  d += __shfl_xor(d, 32);
#pragma unroll
  for (int k = 0; k < 8; ++k) {
    acc[k] *= scl;
    acc[k] += __shfl_xor(acc[k], 16);
    acc[k] += __shfl_xor(acc[k], 32);
  }

  if (g == 0) {
    float inv = 1.f / d;
    float4 b0 = *(const float4*)&bias[dbase];
    float4 b1v = *(const float4*)&bias[dbase + 4];
    float bb[8] = {b0.x, b0.y, b0.z, b0.w, b1v.x, b1v.y, b1v.z, b1v.w};
    bf16x8 vh;
#pragma unroll
    for (int k = 0; k < 8; ++k) {
      float h = gelu_exact(acc[k] * inv + bb[k]);
      vh[k] = (short)f2bf(h);
    }
    *(bf16x8*)(sh + (size_t)row * 128 + dbase) = vh;
  }
}

// ---------------- host ----------------

static inline char* take(char*& p, size_t bytes) {
  char* r = p;
  p += (bytes + 255) & ~(size_t)255;
  return r;
}

extern "C" void kernel_launch(void* const* d_in, const int* in_sizes, int n_in,
                              void* d_out, int out_size, void* d_ws, size_t ws_size,
                              hipStream_t stream) {
  const float* x      = (const float*)d_in[0];
  const int*   ei     = (const int*)d_in[1];
  const float* eps    = (const float*)d_in[2];
  const float* encWl  = (const float*)d_in[3];
  const float* encWr  = (const float*)d_in[4];
  const float* encAtt = (const float*)d_in[5];
  const float* encB   = (const float*)d_in[6];
  const float* decWl  = (const float*)d_in[7];
  const float* decWr  = (const float*)d_in[8];
  const float* decAtt = (const float*)d_in[9];
  const float* decB   = (const float*)d_in[10];
  const float* W_mu   = (const float*)d_in[11];
  const float* b_mu   = (const float*)d_in[12];
  const float* W_ls   = (const float*)d_in[13];
  const float* b_ls   = (const float*)d_in[14];
  const float* W_out  = (const float*)d_in[15];
  const float* b_out  = (const float*)d_in[16];
  const float* W_deg  = (const float*)d_in[17];
  const float* b_deg  = (const float*)d_in[18];

  float* out    = (float*)d_out;
  float* x_rec  = out;
  float* z      = out + (size_t)ND;
  float* mu     = out + (size_t)2 * ND;
  float* logstd = out + (size_t)3 * ND;
  float* degp   = out + (size_t)4 * ND;

  char* p = (char*)d_ws;
  int* bktcnt  = (int*)take(p, 1024 * 4);
  int* bktoff  = (int*)take(p, 1024 * 4);
  int* slack   = (int*)take(p, (size_t)NBKT * SCAP * 4);
  int* row_ptr = (int*)take(p, (size_t)(NN + 1) * 4);
  int* csr_src = (int*)take(p, (size_t)ET * 4);
  unsigned short* gxl  = (unsigned short*)take(p, (size_t)MPAD * 128 * 2);
  unsigned short* gxr  = (unsigned short*)take(p, (size_t)MPAD * 128 * 2);
  unsigned short* stgh = (unsigned short*)take(p, (size_t)MPAD * 128 * 2);
  unsigned short* wfh  = (unsigned short*)take(p, (size_t)19 * 16384 * 2);
  unsigned short* wfl  = (unsigned short*)take(p, (size_t)19 * 16384 * 2);

  const int gMM   = MPAD / 128;             // 782
  const int gWave = (NN * 64 + 255) / 256;  // 25000

  // CSR build (slack scatter, 416 blocks)
  k_zero_int<<<4, 256, 0, stream>>>(bktcnt, 1024);
  kb_scatter<<<GSC, 256, 0, stream>>>(ei, bktcnt, slack);
  kb_scan<<<1, 256, 0, stream>>>(bktcnt, bktoff);
  kb_fin<<<NBKT, 256, 0, stream>>>(slack, bktoff, csr_src, row_ptr);

  // weight frags
  k_wconv<<<152, 256, 0, stream>>>(encWl, encWr, decWl, decWr, W_mu, W_ls, W_out, wfh, wfl);

  const size_t WM = 16384;
  // encoder (layer 0 reads fp32 x directly)
  for (int l = 0; l < 4; ++l) {
    if (l == 0)
      k_mmL<1><<<gMM, 512, 0, stream>>>(nullptr, x,
                                        wfh + (size_t)l * WM, wfh + (size_t)(4 + l) * WM,
                                        gxl, gxr);
    else
      k_mmL<0><<<gMM, 512, 0, stream>>>(stgh, nullptr,
                                        wfh + (size_t)l * WM, wfh + (size_t)(4 + l) * WM,
                                        gxl, gxr);
    k_gat_agg<<<gWave, 256, 0, stream>>>(gxl, gxr, encAtt + (size_t)l * DD,
                                         encB + (size_t)l * DD, row_ptr, csr_src, stgh);
  }

  // heads: mu, logstd, z, z-stage(hi), degree head (2-term)
  k_mmH<<<gMM, 512, 0, stream>>>(stgh,
                                 wfh + (size_t)16 * WM, wfl + (size_t)16 * WM,
                                 wfh + (size_t)17 * WM, wfl + (size_t)17 * WM,
                                 b_mu, b_ls, eps, W_deg, b_deg,
                                 mu, logstd, z, stgh, degp);

  // decoder
  for (int l = 0; l < 4; ++l) {
    k_mmL<0><<<gMM, 512, 0, stream>>>(stgh, nullptr,
                                      wfh + (size_t)(8 + l) * WM, wfh + (size_t)(12 + l) * WM,
                                      gxl, gxr);
    k_gat_agg<<<gWave, 256, 0, stream>>>(gxl, gxr, decAtt + (size_t)l * DD,
                                         decB + (size_t)l * DD, row_ptr, csr_src, stgh);
  }

  // x_rec
  k_mmO<<<gMM, 512, 0, stream>>>(stgh,
                                 wfh + (size_t)18 * WM, wfl + (size_t)18 * WM,
                                 b_out, x_rec);
}

// Round 15
// 1158.252 us; speedup vs baseline: 1.2417x; 1.0206x over previous
//
#include <hip/hip_runtime.h>
#include <math.h>

#define NN 100000
#define MPAD 100096
#define DD 128
#define EE 1600000
#define ET (EE + NN)
#define ND (NN * DD)

#define NBKT 782
#define IPB 4096
#define GSC 416
#define SCAP 4096

typedef short bf16x8 __attribute__((ext_vector_type(8)));
typedef float f32x4 __attribute__((ext_vector_type(4)));

static __device__ __forceinline__ unsigned short f2bf(float f) {
  unsigned int u = __float_as_uint(f);
  u += 0x7FFFu + ((u >> 16) & 1u);
  return (unsigned short)(u >> 16);
}
static __device__ __forceinline__ float bf2f(unsigned short h) {
  return __uint_as_float(((unsigned int)h) << 16);
}
static __device__ __forceinline__ float gelu_exact(float v) {
  return 0.5f * v * (1.f + erff(v * 0.7071067811865476f));
}

// ---------------- CSR build: slack-bucket counting sort ----------------

__global__ void k_zero_int(int* __restrict__ p, int n) {
  int i = blockIdx.x * blockDim.x + threadIdx.x;
  if (i < n) p[i] = 0;
}

__global__ __launch_bounds__(256) void kb_scatter(const int* __restrict__ ei,
                                                  int* __restrict__ cnt,
                                                  int* __restrict__ slack) {
  __shared__ int lc[NBKT];
  __shared__ int lb[NBKT];
  int t = threadIdx.x;
  for (int b = t; b < NBKT; b += 256) lc[b] = 0;
  __syncthreads();
  int i0 = blockIdx.x * IPB;
  int i1 = min(i0 + IPB, ET);
  for (int i = i0 + t; i < i1; i += 256) {
    int dst = (i < EE) ? ei[EE + i] : (i - EE);
    atomicAdd(&lc[dst >> 7], 1);
  }
  __syncthreads();
  for (int b = t; b < NBKT; b += 256) {
    int c = lc[b];
    lb[b] = c ? atomicAdd(&cnt[b], c) : 0;
    lc[b] = 0;
  }
  __syncthreads();
  for (int i = i0 + t; i < i1; i += 256) {
    int src, dst;
    if (i < EE) { src = ei[i]; dst = ei[EE + i]; } else { src = i - EE; dst = src; }
    int b = dst >> 7;
    int l = atomicAdd(&lc[b], 1);
    int pos = lb[b] + l;
    if (pos < SCAP) slack[(size_t)b * SCAP + pos] = src | ((dst & 127) << 17);
  }
}

__global__ __launch_bounds__(256) void kb_scan(const int* __restrict__ cnt,
                                               int* __restrict__ off) {
  __shared__ int sh[256];
  int t = threadIdx.x;
  int c[4]; int s = 0;
#pragma unroll
  for (int j = 0; j < 4; ++j) {
    int b = t * 4 + j;
    c[j] = s;
    int v = (b < NBKT) ? cnt[b] : 0;
    s += v;
  }
  sh[t] = s; __syncthreads();
  for (int o = 1; o < 256; o <<= 1) {
    int v = (t >= o) ? sh[t - o] : 0;
    __syncthreads();
    sh[t] += v;
    __syncthreads();
  }
  int excl = sh[t] - s;
#pragma unroll
  for (int j = 0; j < 4; ++j) {
    int b = t * 4 + j;
    if (b < NBKT) off[b] = excl + c[j];
  }
  if (t == 255) off[NBKT] = excl + s;
}

__global__ __launch_bounds__(256) void kb_fin(const int* __restrict__ slack,
                                              const int* __restrict__ off,
                                              int* __restrict__ csr_src,
                                              int* __restrict__ row_ptr) {
  __shared__ int ebuf[SCAP];
  __shared__ int osrc[SCAP];
  __shared__ int cnt[128], scn[128], lcur[128];
  int b = blockIdx.x;
  int base = off[b];
  int count = min(off[b + 1] - base, SCAP);
  int t = threadIdx.x;
  const int* in = slack + (size_t)b * SCAP;
  if (t < 128) { cnt[t] = 0; lcur[t] = 0; }
  __syncthreads();
  for (int i = t; i < count; i += 256) {
    int w = in[i];
    ebuf[i] = w;
    atomicAdd(&cnt[(w >> 17) & 127], 1);
  }
  __syncthreads();
  if (t < 128) scn[t] = cnt[t];
  __syncthreads();
  for (int o = 1; o < 128; o <<= 1) {
    int v = 0;
    if (t < 128 && t >= o) v = scn[t - o];
    __syncthreads();
    if (t < 128) scn[t] += v;
    __syncthreads();
  }
  for (int i = t; i < count; i += 256) {
    int w = ebuf[i];
    int d = (w >> 17) & 127;
    int l = atomicAdd(&lcur[d], 1);
    osrc[(scn[d] - cnt[d]) + l] = w & 0x1FFFF;
  }
  __syncthreads();
  for (int i = t; i < count; i += 256) csr_src[base + i] = osrc[i];
  if (t < 128) {
    int gd = b * 128 + t;
    if (gd <= NN) row_ptr[gd] = base + scn[t] - cnt[t];
  }
}

// ---------------- weight fragment precompute ----------------

__global__ __launch_bounds__(256) void k_wconv(const float* __restrict__ encWl,
                                               const float* __restrict__ encWr,
                                               const float* __restrict__ decWl,
                                               const float* __restrict__ decWr,
                                               const float* __restrict__ Wmu,
                                               const float* __restrict__ Wls,
                                               const float* __restrict__ Wout,
                                               unsigned short* __restrict__ wfh,
                                               unsigned short* __restrict__ wfl) {
  int wid = (blockIdx.x * 256 + threadIdx.x) >> 6;
  int lane = threadIdx.x & 63;
  if (wid >= 19 * 32) return;
  int mat = wid >> 5;
  int sub = wid & 31;
  const float* W;
  if (mat < 4) W = encWl + (size_t)mat * 16384;
  else if (mat < 8) W = encWr + (size_t)(mat - 4) * 16384;
  else if (mat < 12) W = decWl + (size_t)(mat - 8) * 16384;
  else if (mat < 16) W = decWr + (size_t)(mat - 12) * 16384;
  else if (mat == 16) W = Wmu;
  else if (mat == 17) W = Wls;
  else W = Wout;
  int t = sub >> 3, c = sub & 7;
  int col = c * 16 + (lane & 15);
  int k0 = t * 32 + (lane >> 4) * 8;
  bf16x8 vh, vl;
#pragma unroll
  for (int j = 0; j < 8; ++j) {
    float w = W[(size_t)(k0 + j) * 128 + col];
    unsigned short h = f2bf(w);
    vh[j] = (short)h;
    vl[j] = (short)f2bf(w - bf2f(h));
  }
  size_t base = ((size_t)wid * 64 + lane) * 8;
  *(bf16x8*)(wfh + base) = vh;
  *(bf16x8*)(wfl + base) = vl;
}

// ---------------- layer dual GEMM: 1-term bf16, 33.8 KB LDS, sequential outputs ----------

template <int RF32>
__global__ __launch_bounds__(512, 4) void k_mmL(const unsigned short* __restrict__ Ah,
                                                const float* __restrict__ Xf,
                                                const unsigned short* __restrict__ w1,
                                                const unsigned short* __restrict__ w2,
                                                unsigned short* __restrict__ o1,
                                                unsigned short* __restrict__ o2) {
  __shared__ float lds[64 * 132];
  unsigned short* lw = (unsigned short*)lds;
  int tid = threadIdx.x;
  int wv = tid >> 6, lane = tid & 63;
  int lrow = lane & 15, lk = lane >> 4;
  int row = blockIdx.x * 128 + wv * 16 + lrow;

  {
    int4* d = (int4*)lw;
    const int4* s1 = (const int4*)w1;
#pragma unroll
    for (int i = 0; i < 4; ++i) d[tid + i * 512] = s1[tid + i * 512];
  }
  bf16x8 a_h[4];
  if (RF32) {
#pragma unroll
    for (int t = 0; t < 4; ++t) {
      float4 f0 = {0.f, 0.f, 0.f, 0.f}, f1 = {0.f, 0.f, 0.f, 0.f};
      if (row < NN) {
        const float* xp = Xf + (size_t)row * 128 + t * 32 + lk * 8;
        f0 = *(const float4*)xp;
        f1 = *(const float4*)(xp + 4);
      }
      bf16x8 v;
      v[0] = (short)f2bf(f0.x); v[1] = (short)f2bf(f0.y);
      v[2] = (short)f2bf(f0.z); v[3] = (short)f2bf(f0.w);
      v[4] = (short)f2bf(f1.x); v[5] = (short)f2bf(f1.y);
      v[6] = (short)f2bf(f1.z); v[7] = (short)f2bf(f1.w);
      a_h[t] = v;
    }
  } else {
    const unsigned short* ap = Ah + (size_t)row * 128 + lk * 8;
#pragma unroll
    for (int t = 0; t < 4; ++t) a_h[t] = *(const bf16x8*)(ap + t * 32);
  }
  __syncthreads();

#pragma unroll
  for (int out = 0; out < 2; ++out) {
    if (out == 1) {
      int4* d = (int4*)lw;
      const int4* s2 = (const int4*)w2;
#pragma unroll
      for (int i = 0; i < 4; ++i) d[tid + i * 512] = s2[tid + i * 512];
      __syncthreads();
    }
    f32x4 acc[8];
#pragma unroll
    for (int c = 0; c < 8; ++c) acc[c] = (f32x4){0.f, 0.f, 0.f, 0.f};
#pragma unroll
    for (int t = 0; t < 4; ++t) {
#pragma unroll
      for (int c = 0; c < 8; ++c) {
        int fo = ((t * 8 + c) * 64 + lane) * 8;
        bf16x8 wf = *(const bf16x8*)(lw + fo);
        acc[c] = __builtin_amdgcn_mfma_f32_16x16x32_bf16(a_h[t], wf, acc[c], 0, 0, 0);
      }
    }
    __syncthreads();

    unsigned short* dst = out ? o2 : o1;
#pragma unroll
    for (int h = 0; h < 2; ++h) {
      if ((wv >> 2) == h) {
        int lrb = (wv & 3) * 16;
#pragma unroll
        for (int c = 0; c < 8; ++c)
#pragma unroll
          for (int r = 0; r < 4; ++r)
            lds[(lrb + lk * 4 + r) * 132 + c * 16 + lrow] = acc[c][r];
      }
      __syncthreads();
      {
        int lr = tid >> 3, c0 = (tid & 7) * 16;
        size_t o = ((size_t)blockIdx.x * 128 + h * 64 + lr) * 128 + c0;
        const float* sp = &lds[lr * 132 + c0];
#pragma unroll
        for (int i = 0; i < 2; ++i) {
          union { unsigned short u[8]; int4 v; } pk;
#pragma unroll
          for (int j = 0; j < 8; ++j) pk.u[j] = f2bf(sp[i * 8 + j]);
          *(int4*)&dst[o + i * 8] = pk.v;
        }
      }
      __syncthreads();
    }
  }
}

// ---------------- output GEMM: C = A_h@(Wh+Wl)+b fp32, 33.8 KB LDS ----------------
// used for x_rec AND for mu.

__global__ __launch_bounds__(512, 4) void k_mmO(const unsigned short* __restrict__ Ah,
                                                const unsigned short* __restrict__ wh,
                                                const unsigned short* __restrict__ wl,
                                                const float* __restrict__ bias,
                                                float* __restrict__ C) {
  __shared__ float lds[64 * 132];
  unsigned short* lw = (unsigned short*)lds;
  int tid = threadIdx.x;
  int wv = tid >> 6, lane = tid & 63;
  int lrow = lane & 15, lk = lane >> 4;
  int row = blockIdx.x * 128 + wv * 16 + lrow;

  {
    int4* d = (int4*)lw;
    const int4* s1 = (const int4*)wh;
#pragma unroll
    for (int i = 0; i < 4; ++i) d[tid + i * 512] = s1[tid + i * 512];
  }
  bf16x8 a_h[4];
  const unsigned short* ap = Ah + (size_t)row * 128 + lk * 8;
#pragma unroll
  for (int t = 0; t < 4; ++t) a_h[t] = *(const bf16x8*)(ap + t * 32);
  __syncthreads();

  f32x4 acc[8];
#pragma unroll
  for (int c = 0; c < 8; ++c) acc[c] = (f32x4){0.f, 0.f, 0.f, 0.f};
#pragma unroll
  for (int t = 0; t < 4; ++t) {
#pragma unroll
    for (int c = 0; c < 8; ++c) {
      int fo = ((t * 8 + c) * 64 + lane) * 8;
      bf16x8 wf = *(const bf16x8*)(lw + fo);
      acc[c] = __builtin_amdgcn_mfma_f32_16x16x32_bf16(a_h[t], wf, acc[c], 0, 0, 0);
    }
  }
  __syncthreads();
  {
    int4* d = (int4*)lw;
    const int4* s2 = (const int4*)wl;
#pragma unroll
    for (int i = 0; i < 4; ++i) d[tid + i * 512] = s2[tid + i * 512];
  }
  __syncthreads();
#pragma unroll
  for (int t = 0; t < 4; ++t) {
#pragma unroll
    for (int c = 0; c < 8; ++c) {
      int fo = ((t * 8 + c) * 64 + lane) * 8;
      bf16x8 wf = *(const bf16x8*)(lw + fo);
      acc[c] = __builtin_amdgcn_mfma_f32_16x16x32_bf16(a_h[t], wf, acc[c], 0, 0, 0);
    }
  }
  __syncthreads();

#pragma unroll
  for (int h = 0; h < 2; ++h) {
    if ((wv >> 2) == h) {
      int lrb = (wv & 3) * 16;
#pragma unroll
      for (int c = 0; c < 8; ++c)
#pragma unroll
        for (int r = 0; r < 4; ++r)
          lds[(lrb + lk * 4 + r) * 132 + c * 16 + lrow] = acc[c][r];
    }
    __syncthreads();
    {
      int lr = tid >> 3, c0 = (tid & 7) * 16;
      int grow = blockIdx.x * 128 + h * 64 + lr;
      if (grow < NN) {
        size_t o = (size_t)grow * 128 + c0;
        const float* sp = &lds[lr * 132 + c0];
#pragma unroll
        for (int i = 0; i < 4; ++i) {
          float4 v = *(const float4*)(sp + i * 4);
          float4 b4 = *(const float4*)&bias[c0 + i * 4];
          v.x += b4.x; v.y += b4.y; v.z += b4.z; v.w += b4.w;
          *(float4*)&C[o + i * 4] = v;
        }
      }
    }
    __syncthreads();
  }
}

// ---------------- LSZ kernel: ls = min(A@Wls+b,10); z = mu + eps*exp(ls); zh; deg ------

__global__ __launch_bounds__(512, 3) void k_mmLSZ(const unsigned short* Ah,
                                                  const unsigned short* __restrict__ wh,
                                                  const unsigned short* __restrict__ wl,
                                                  const float* __restrict__ bias,
                                                  const float* __restrict__ mu,
                                                  const float* __restrict__ eps,
                                                  const float* __restrict__ Wd,
                                                  const float* __restrict__ bd,
                                                  float* __restrict__ logstd,
                                                  float* __restrict__ Z,
                                                  unsigned short* Zh,
                                                  float* __restrict__ degp) {
  __shared__ float lds[64 * 132];
  unsigned short* lw = (unsigned short*)lds;
  int tid = threadIdx.x;
  int wv = tid >> 6, lane = tid & 63;
  int lrow = lane & 15, lk = lane >> 4;
  int row = blockIdx.x * 128 + wv * 16 + lrow;

  {
    int4* d = (int4*)lw;
    const int4* s1 = (const int4*)wh;
#pragma unroll
    for (int i = 0; i < 4; ++i) d[tid + i * 512] = s1[tid + i * 512];
  }
  bf16x8 a_h[4];
  const unsigned short* ap = Ah + (size_t)row * 128 + lk * 8;
#pragma unroll
  for (int t = 0; t < 4; ++t) a_h[t] = *(const bf16x8*)(ap + t * 32);
  __syncthreads();

  f32x4 acc[8];
#pragma unroll
  for (int c = 0; c < 8; ++c) acc[c] = (f32x4){0.f, 0.f, 0.f, 0.f};
#pragma unroll
  for (int t = 0; t < 4; ++t) {
#pragma unroll
    for (int c = 0; c < 8; ++c) {
      int fo = ((t * 8 + c) * 64 + lane) * 8;
      bf16x8 wf = *(const bf16x8*)(lw + fo);
      acc[c] = __builtin_amdgcn_mfma_f32_16x16x32_bf16(a_h[t], wf, acc[c], 0, 0, 0);
    }
  }
  __syncthreads();
  {
    int4* d = (int4*)lw;
    const int4* s2 = (const int4*)wl;
#pragma unroll
    for (int i = 0; i < 4; ++i) d[tid + i * 512] = s2[tid + i * 512];
  }
  __syncthreads();
#pragma unroll
  for (int t = 0; t < 4; ++t) {
#pragma unroll
    for (int c = 0; c < 8; ++c) {
      int fo = ((t * 8 + c) * 64 + lane) * 8;
      bf16x8 wf = *(const bf16x8*)(lw + fo);
      acc[c] = __builtin_amdgcn_mfma_f32_16x16x32_bf16(a_h[t], wf, acc[c], 0, 0, 0);
    }
  }
  __syncthreads();

#pragma unroll
  for (int h = 0; h < 2; ++h) {
    if ((wv >> 2) == h) {
      int lrb = (wv & 3) * 16;
#pragma unroll
      for (int c = 0; c < 8; ++c)
#pragma unroll
        for (int r = 0; r < 4; ++r)
          lds[(lrb + lk * 4 + r) * 132 + c * 16 + lrow] = acc[c][r];
    }
    __syncthreads();
    {
      int lr = tid >> 3, c0 = (tid & 7) * 16;
      int grow = blockIdx.x * 128 + h * 64 + lr;
      float s_deg = 0.f;
      if (grow < NN) {
        size_t o = (size_t)grow * 128 + c0;
        const float* sp = &lds[lr * 132 + c0];
#pragma unroll
        for (int i = 0; i < 4; ++i) {
          float4 v = *(const float4*)(sp + i * 4);
          float4 b4 = *(const float4*)&bias[c0 + i * 4];
          float4 ls;
          ls.x = fminf(v.x + b4.x, 10.f);
          ls.y = fminf(v.y + b4.y, 10.f);
          ls.z = fminf(v.z + b4.z, 10.f);
          ls.w = fminf(v.w + b4.w, 10.f);
          *(float4*)&logstd[o + i * 4] = ls;
          float4 m4 = *(const float4*)&mu[o + i * 4];
          float4 e4 = *(const float4*)&eps[o + i * 4];
          float4 z4;
          z4.x = fmaf(e4.x, expf(ls.x), m4.x);
          z4.y = fmaf(e4.y, expf(ls.y), m4.y);
          z4.z = fmaf(e4.z, expf(ls.z), m4.z);
          z4.w = fmaf(e4.w, expf(ls.w), m4.w);
          *(float4*)&Z[o + i * 4] = z4;
          ushort4 hh;
          hh.x = f2bf(z4.x); hh.y = f2bf(z4.y); hh.z = f2bf(z4.z); hh.w = f2bf(z4.w);
          *(ushort4*)&Zh[o + i * 4] = hh;
          float4 wd = *(const float4*)&Wd[c0 + i * 4];
          s_deg += z4.x * wd.x + z4.y * wd.y + z4.z * wd.z + z4.w * wd.w;
        }
      }
      s_deg += __shfl_xor(s_deg, 1);
      s_deg += __shfl_xor(s_deg, 2);
      s_deg += __shfl_xor(s_deg, 4);
      if (grow < NN && (tid & 7) == 0) degp[grow] = s_deg + bd[0];
    }
    __syncthreads();
  }
}

// ---------------- GATv2 aggregation: wave/row, 4x16 lanes, bf16 gathers ----------------

__global__ __launch_bounds__(256) void k_gat_agg(const unsigned short* __restrict__ gxl,
                                                 const unsigned short* __restrict__ gxr,
                                                 const float* __restrict__ att,
                                                 const float* __restrict__ bias,
                                                 const int* __restrict__ row_ptr,
                                                 const int* __restrict__ csr_src,
                                                 unsigned short* __restrict__ sh) {
  int gid = blockIdx.x * blockDim.x + threadIdx.x;
  int row = gid >> 6;
  int lane = gid & 63;
  if (row >= NN) return;
  int g = lane >> 4, j = lane & 15;
  int dbase = j * 8;

  float a[8], r[8];
  {
    float4 a0 = *(const float4*)&att[dbase];
    float4 a1 = *(const float4*)&att[dbase + 4];
    a[0] = a0.x; a[1] = a0.y; a[2] = a0.z; a[3] = a0.w;
    a[4] = a1.x; a[5] = a1.y; a[6] = a1.z; a[7] = a1.w;
    bf16x8 rv = *(const bf16x8*)&gxr[(size_t)row * 128 + dbase];
#pragma unroll
    for (int k = 0; k < 8; ++k) r[k] = bf2f((unsigned short)rv[k]);
  }

  float m = -INFINITY, d = 0.f;
  float acc[8] = {0.f, 0.f, 0.f, 0.f, 0.f, 0.f, 0.f, 0.f};
  int p0 = row_ptr[row], p1 = row_ptr[row + 1];

  for (int p = p0 + g; p < p1; p += 4) {
    int s = csr_src[p];
    bf16x8 xv = *(const bf16x8*)&gxl[(size_t)s * 128 + dbase];
    float v[8];
#pragma unroll
    for (int k = 0; k < 8; ++k) v[k] = bf2f((unsigned short)xv[k]);

    float e = 0.f;
#pragma unroll
    for (int k = 0; k < 8; ++k) {
      float t0 = v[k] + r[k];
      t0 = fmaxf(t0, 0.2f * t0);
      e = fmaf(t0, a[k], e);
    }
    e += __shfl_xor(e, 1);
    e += __shfl_xor(e, 2);
    e += __shfl_xor(e, 4);
    e += __shfl_xor(e, 8);

    float mn = fmaxf(m, e);
    float scl = __expf(m - mn);
    float w = __expf(e - mn);
    d = d * scl + w;
#pragma unroll
    for (int k = 0; k < 8; ++k) acc[k] = acc[k] * scl + w * v[k];
    m = mn;
  }

  float mo = fmaxf(m, __shfl_xor(m, 16));
  mo = fmaxf(mo, __shfl_xor(mo, 32));
  float scl = __expf(m - mo);
  d *= scl;
  d += __shfl_xor(d, 16);
  d += __shfl_xor(d, 32);
#pragma unroll
  for (int k = 0; k < 8; ++k) {
    acc[k] *= scl;
    acc[k] += __shfl_xor(acc[k], 16);
    acc[k] += __shfl_xor(acc[k], 32);
  }

  if (g == 0) {
    float inv = 1.f / d;
    float4 b0 = *(const float4*)&bias[dbase];
    float4 b1v = *(const float4*)&bias[dbase + 4];
    float bb[8] = {b0.x, b0.y, b0.z, b0.w, b1v.x, b1v.y, b1v.z, b1v.w};
    bf16x8 vh;
#pragma unroll
    for (int k = 0; k < 8; ++k) {
      float h = gelu_exact(acc[k] * inv + bb[k]);
      vh[k] = (short)f2bf(h);
    }
    *(bf16x8*)(sh + (size_t)row * 128 + dbase) = vh;
  }
}

// ---------------- host ----------------

static inline char* take(char*& p, size_t bytes) {
  char* r = p;
  p += (bytes + 255) & ~(size_t)255;
  return r;
}

extern "C" void kernel_launch(void* const* d_in, const int* in_sizes, int n_in,
                              void* d_out, int out_size, void* d_ws, size_t ws_size,
                              hipStream_t stream) {
  const float* x      = (const float*)d_in[0];
  const int*   ei     = (const int*)d_in[1];
  const float* eps    = (const float*)d_in[2];
  const float* encWl  = (const float*)d_in[3];
  const float* encWr  = (const float*)d_in[4];
  const float* encAtt = (const float*)d_in[5];
  const float* encB   = (const float*)d_in[6];
  const float* decWl  = (const float*)d_in[7];
  const float* decWr  = (const float*)d_in[8];
  const float* decAtt = (const float*)d_in[9];
  const float* decB   = (const float*)d_in[10];
  const float* W_mu   = (const float*)d_in[11];
  const float* b_mu   = (const float*)d_in[12];
  const float* W_ls   = (const float*)d_in[13];
  const float* b_ls   = (const float*)d_in[14];
  const float* W_out  = (const float*)d_in[15];
  const float* b_out  = (const float*)d_in[16];
  const float* W_deg  = (const float*)d_in[17];
  const float* b_deg  = (const float*)d_in[18];

  float* out    = (float*)d_out;
  float* x_rec  = out;
  float* z      = out + (size_t)ND;
  float* mu     = out + (size_t)2 * ND;
  float* logstd = out + (size_t)3 * ND;
  float* degp   = out + (size_t)4 * ND;

  char* p = (char*)d_ws;
  int* bktcnt  = (int*)take(p, 1024 * 4);
  int* bktoff  = (int*)take(p, 1024 * 4);
  int* slack   = (int*)take(p, (size_t)NBKT * SCAP * 4);
  int* row_ptr = (int*)take(p, (size_t)(NN + 1) * 4);
  int* csr_src = (int*)take(p, (size_t)ET * 4);
  unsigned short* gxl  = (unsigned short*)take(p, (size_t)MPAD * 128 * 2);
  unsigned short* gxr  = (unsigned short*)take(p, (size_t)MPAD * 128 * 2);
  unsigned short* stgh = (unsigned short*)take(p, (size_t)MPAD * 128 * 2);
  unsigned short* wfh  = (unsigned short*)take(p, (size_t)19 * 16384 * 2);
  unsigned short* wfl  = (unsigned short*)take(p, (size_t)19 * 16384 * 2);

  const int gMM   = MPAD / 128;             // 782
  const int gWave = (NN * 64 + 255) / 256;  // 25000

  // CSR build
  k_zero_int<<<4, 256, 0, stream>>>(bktcnt, 1024);
  kb_scatter<<<GSC, 256, 0, stream>>>(ei, bktcnt, slack);
  kb_scan<<<1, 256, 0, stream>>>(bktcnt, bktoff);
  kb_fin<<<NBKT, 256, 0, stream>>>(slack, bktoff, csr_src, row_ptr);

  // weight frags
  k_wconv<<<152, 256, 0, stream>>>(encWl, encWr, decWl, decWr, W_mu, W_ls, W_out, wfh, wfl);

  const size_t WM = 16384;
  // encoder (layer 0 reads fp32 x directly)
  for (int l = 0; l < 4; ++l) {
    if (l == 0)
      k_mmL<1><<<gMM, 512, 0, stream>>>(nullptr, x,
                                        wfh + (size_t)l * WM, wfh + (size_t)(4 + l) * WM,
                                        gxl, gxr);
    else
      k_mmL<0><<<gMM, 512, 0, stream>>>(stgh, nullptr,
                                        wfh + (size_t)l * WM, wfh + (size_t)(4 + l) * WM,
                                        gxl, gxr);
    k_gat_agg<<<gWave, 256, 0, stream>>>(gxl, gxr, encAtt + (size_t)l * DD,
                                         encB + (size_t)l * DD, row_ptr, csr_src, stgh);
  }

  // heads: mu (proven mmO shape), then ls/z/zh/deg
  k_mmO<<<gMM, 512, 0, stream>>>(stgh,
                                 wfh + (size_t)16 * WM, wfl + (size_t)16 * WM,
                                 b_mu, mu);
  k_mmLSZ<<<gMM, 512, 0, stream>>>(stgh,
                                   wfh + (size_t)17 * WM, wfl + (size_t)17 * WM,
                                   b_ls, mu, eps, W_deg, b_deg,
                                   logstd, z, stgh, degp);

  // decoder
  for (int l = 0; l < 4; ++l) {
    k_mmL<0><<<gMM, 512, 0, stream>>>(stgh, nullptr,
                                      wfh + (size_t)(8 + l) * WM, wfh + (size_t)(12 + l) * WM,
                                      gxl, gxr);
    k_gat_agg<<<gWave, 256, 0, stream>>>(gxl, gxr, decAtt + (size_t)l * DD,
                                         decB + (size_t)l * DD, row_ptr, csr_src, stgh);
  }

  // x_rec
  k_mmO<<<gMM, 512, 0, stream>>>(stgh,
                                 wfh + (size_t)18 * WM, wfl + (size_t)18 * WM,
                                 b_out, x_rec);
}

// Round 16
// 1139.459 us; speedup vs baseline: 1.2621x; 1.0165x over previous
//
#include <hip/hip_runtime.h>
#include <math.h>

#define NN 100000
#define MPAD 100096
#define DD 128
#define EE 1600000
#define ET (EE + NN)
#define ND (NN * DD)

#define NBKT 782
#define IPB 4096
#define GSC 416
#define SCAP 4096

typedef short bf16x8 __attribute__((ext_vector_type(8)));
typedef float f32x4 __attribute__((ext_vector_type(4)));

static __device__ __forceinline__ unsigned short f2bf(float f) {
  unsigned int u = __float_as_uint(f);
  u += 0x7FFFu + ((u >> 16) & 1u);
  return (unsigned short)(u >> 16);
}
static __device__ __forceinline__ float bf2f(unsigned short h) {
  return __uint_as_float(((unsigned int)h) << 16);
}
static __device__ __forceinline__ float gelu_exact(float v) {
  return 0.5f * v * (1.f + erff(v * 0.7071067811865476f));
}

// ---------------- CSR build: slack-bucket counting sort ----------------

__global__ void k_zero_int(int* __restrict__ p, int n) {
  int i = blockIdx.x * blockDim.x + threadIdx.x;
  if (i < n) p[i] = 0;
}

__global__ __launch_bounds__(256) void kb_scatter(const int* __restrict__ ei,
                                                  int* __restrict__ cnt,
                                                  int* __restrict__ slack) {
  __shared__ int lc[NBKT];
  __shared__ int lb[NBKT];
  int t = threadIdx.x;
  for (int b = t; b < NBKT; b += 256) lc[b] = 0;
  __syncthreads();
  int i0 = blockIdx.x * IPB;
  int i1 = min(i0 + IPB, ET);
  for (int i = i0 + t; i < i1; i += 256) {
    int dst = (i < EE) ? ei[EE + i] : (i - EE);
    atomicAdd(&lc[dst >> 7], 1);
  }
  __syncthreads();
  for (int b = t; b < NBKT; b += 256) {
    int c = lc[b];
    lb[b] = c ? atomicAdd(&cnt[b], c) : 0;
    lc[b] = 0;
  }
  __syncthreads();
  for (int i = i0 + t; i < i1; i += 256) {
    int src, dst;
    if (i < EE) { src = ei[i]; dst = ei[EE + i]; } else { src = i - EE; dst = src; }
    int b = dst >> 7;
    int l = atomicAdd(&lc[b], 1);
    int pos = lb[b] + l;
    if (pos < SCAP) slack[(size_t)b * SCAP + pos] = src | ((dst & 127) << 17);
  }
}

__global__ __launch_bounds__(256) void kb_scan(const int* __restrict__ cnt,
                                               int* __restrict__ off) {
  __shared__ int sh[256];
  int t = threadIdx.x;
  int c[4]; int s = 0;
#pragma unroll
  for (int j = 0; j < 4; ++j) {
    int b = t * 4 + j;
    c[j] = s;
    int v = (b < NBKT) ? cnt[b] : 0;
    s += v;
  }
  sh[t] = s; __syncthreads();
  for (int o = 1; o < 256; o <<= 1) {
    int v = (t >= o) ? sh[t - o] : 0;
    __syncthreads();
    sh[t] += v;
    __syncthreads();
  }
  int excl = sh[t] - s;
#pragma unroll
  for (int j = 0; j < 4; ++j) {
    int b = t * 4 + j;
    if (b < NBKT) off[b] = excl + c[j];
  }
  if (t == 255) off[NBKT] = excl + s;
}

__global__ __launch_bounds__(256) void kb_fin(const int* __restrict__ slack,
                                              const int* __restrict__ off,
                                              int* __restrict__ csr_src,
                                              int* __restrict__ row_ptr) {
  __shared__ int ebuf[SCAP];
  __shared__ int osrc[SCAP];
  __shared__ int cnt[128], scn[128], lcur[128];
  int b = blockIdx.x;
  int base = off[b];
  int count = min(off[b + 1] - base, SCAP);
  int t = threadIdx.x;
  const int* in = slack + (size_t)b * SCAP;
  if (t < 128) { cnt[t] = 0; lcur[t] = 0; }
  __syncthreads();
  for (int i = t; i < count; i += 256) {
    int w = in[i];
    ebuf[i] = w;
    atomicAdd(&cnt[(w >> 17) & 127], 1);
  }
  __syncthreads();
  if (t < 128) scn[t] = cnt[t];
  __syncthreads();
  for (int o = 1; o < 128; o <<= 1) {
    int v = 0;
    if (t < 128 && t >= o) v = scn[t - o];
    __syncthreads();
    if (t < 128) scn[t] += v;
    __syncthreads();
  }
  for (int i = t; i < count; i += 256) {
    int w = ebuf[i];
    int d = (w >> 17) & 127;
    int l = atomicAdd(&lcur[d], 1);
    osrc[(scn[d] - cnt[d]) + l] = w & 0x1FFFF;
  }
  __syncthreads();
  for (int i = t; i < count; i += 256) csr_src[base + i] = osrc[i];
  if (t < 128) {
    int gd = b * 128 + t;
    if (gd <= NN) row_ptr[gd] = base + scn[t] - cnt[t];
  }
}

// ---------------- weight fragment precompute ----------------

__global__ __launch_bounds__(256) void k_wconv(const float* __restrict__ encWl,
                                               const float* __restrict__ encWr,
                                               const float* __restrict__ decWl,
                                               const float* __restrict__ decWr,
                                               const float* __restrict__ Wmu,
                                               const float* __restrict__ Wls,
                                               const float* __restrict__ Wout,
                                               unsigned short* __restrict__ wfh,
                                               unsigned short* __restrict__ wfl) {
  int wid = (blockIdx.x * 256 + threadIdx.x) >> 6;
  int lane = threadIdx.x & 63;
  if (wid >= 19 * 32) return;
  int mat = wid >> 5;
  int sub = wid & 31;
  const float* W;
  if (mat < 4) W = encWl + (size_t)mat * 16384;
  else if (mat < 8) W = encWr + (size_t)(mat - 4) * 16384;
  else if (mat < 12) W = decWl + (size_t)(mat - 8) * 16384;
  else if (mat < 16) W = decWr + (size_t)(mat - 12) * 16384;
  else if (mat == 16) W = Wmu;
  else if (mat == 17) W = Wls;
  else W = Wout;
  int t = sub >> 3, c = sub & 7;
  int col = c * 16 + (lane & 15);
  int k0 = t * 32 + (lane >> 4) * 8;
  bf16x8 vh, vl;
#pragma unroll
  for (int j = 0; j < 8; ++j) {
    float w = W[(size_t)(k0 + j) * 128 + col];
    unsigned short h = f2bf(w);
    vh[j] = (short)h;
    vl[j] = (short)f2bf(w - bf2f(h));
  }
  size_t base = ((size_t)wid * 64 + lane) * 8;
  *(bf16x8*)(wfh + base) = vh;
  *(bf16x8*)(wfl + base) = vl;
}

// ---------------- layer dual GEMM: 1-term bf16, 33.8 KB LDS, sequential outputs ----------

template <int RF32>
__global__ __launch_bounds__(512, 4) void k_mmL(const unsigned short* __restrict__ Ah,
                                                const float* __restrict__ Xf,
                                                const unsigned short* __restrict__ w1,
                                                const unsigned short* __restrict__ w2,
                                                unsigned short* __restrict__ o1,
                                                unsigned short* __restrict__ o2) {
  __shared__ float lds[64 * 132];
  unsigned short* lw = (unsigned short*)lds;
  int tid = threadIdx.x;
  int wv = tid >> 6, lane = tid & 63;
  int lrow = lane & 15, lk = lane >> 4;
  int row = blockIdx.x * 128 + wv * 16 + lrow;

  {
    int4* d = (int4*)lw;
    const int4* s1 = (const int4*)w1;
#pragma unroll
    for (int i = 0; i < 4; ++i) d[tid + i * 512] = s1[tid + i * 512];
  }
  bf16x8 a_h[4];
  if (RF32) {
#pragma unroll
    for (int t = 0; t < 4; ++t) {
      float4 f0 = {0.f, 0.f, 0.f, 0.f}, f1 = {0.f, 0.f, 0.f, 0.f};
      if (row < NN) {
        const float* xp = Xf + (size_t)row * 128 + t * 32 + lk * 8;
        f0 = *(const float4*)xp;
        f1 = *(const float4*)(xp + 4);
      }
      bf16x8 v;
      v[0] = (short)f2bf(f0.x); v[1] = (short)f2bf(f0.y);
      v[2] = (short)f2bf(f0.z); v[3] = (short)f2bf(f0.w);
      v[4] = (short)f2bf(f1.x); v[5] = (short)f2bf(f1.y);
      v[6] = (short)f2bf(f1.z); v[7] = (short)f2bf(f1.w);
      a_h[t] = v;
    }
  } else {
    const unsigned short* ap = Ah + (size_t)row * 128 + lk * 8;
#pragma unroll
    for (int t = 0; t < 4; ++t) a_h[t] = *(const bf16x8*)(ap + t * 32);
  }
  __syncthreads();

#pragma unroll
  for (int out = 0; out < 2; ++out) {
    if (out == 1) {
      int4* d = (int4*)lw;
      const int4* s2 = (const int4*)w2;
#pragma unroll
      for (int i = 0; i < 4; ++i) d[tid + i * 512] = s2[tid + i * 512];
      __syncthreads();
    }
    f32x4 acc[8];
#pragma unroll
    for (int c = 0; c < 8; ++c) acc[c] = (f32x4){0.f, 0.f, 0.f, 0.f};
#pragma unroll
    for (int t = 0; t < 4; ++t) {
#pragma unroll
      for (int c = 0; c < 8; ++c) {
        int fo = ((t * 8 + c) * 64 + lane) * 8;
        bf16x8 wf = *(const bf16x8*)(lw + fo);
        acc[c] = __builtin_amdgcn_mfma_f32_16x16x32_bf16(a_h[t], wf, acc[c], 0, 0, 0);
      }
    }
    __syncthreads();

    unsigned short* dst = out ? o2 : o1;
#pragma unroll
    for (int h = 0; h < 2; ++h) {
      if ((wv >> 2) == h) {
        int lrb = (wv & 3) * 16;
#pragma unroll
        for (int c = 0; c < 8; ++c)
#pragma unroll
          for (int r = 0; r < 4; ++r)
            lds[(lrb + lk * 4 + r) * 132 + c * 16 + lrow] = acc[c][r];
      }
      __syncthreads();
      {
        int lr = tid >> 3, c0 = (tid & 7) * 16;
        size_t o = ((size_t)blockIdx.x * 128 + h * 64 + lr) * 128 + c0;
        const float* sp = &lds[lr * 132 + c0];
#pragma unroll
        for (int i = 0; i < 2; ++i) {
          union { unsigned short u[8]; int4 v; } pk;
#pragma unroll
          for (int j = 0; j < 8; ++j) pk.u[j] = f2bf(sp[i * 8 + j]);
          *(int4*)&dst[o + i * 8] = pk.v;
        }
      }
      __syncthreads();
    }
  }
}

// ---------------- output GEMM: C = A_h@(Wh+Wl)+b fp32, 33.8 KB LDS (x_rec) ----------------

__global__ __launch_bounds__(512, 4) void k_mmO(const unsigned short* __restrict__ Ah,
                                                const unsigned short* __restrict__ wh,
                                                const unsigned short* __restrict__ wl,
                                                const float* __restrict__ bias,
                                                float* __restrict__ C) {
  __shared__ float lds[64 * 132];
  unsigned short* lw = (unsigned short*)lds;
  int tid = threadIdx.x;
  int wv = tid >> 6, lane = tid & 63;
  int lrow = lane & 15, lk = lane >> 4;
  int row = blockIdx.x * 128 + wv * 16 + lrow;

  {
    int4* d = (int4*)lw;
    const int4* s1 = (const int4*)wh;
#pragma unroll
    for (int i = 0; i < 4; ++i) d[tid + i * 512] = s1[tid + i * 512];
  }
  bf16x8 a_h[4];
  const unsigned short* ap = Ah + (size_t)row * 128 + lk * 8;
#pragma unroll
  for (int t = 0; t < 4; ++t) a_h[t] = *(const bf16x8*)(ap + t * 32);
  __syncthreads();

  f32x4 acc[8];
#pragma unroll
  for (int c = 0; c < 8; ++c) acc[c] = (f32x4){0.f, 0.f, 0.f, 0.f};
#pragma unroll
  for (int t = 0; t < 4; ++t) {
#pragma unroll
    for (int c = 0; c < 8; ++c) {
      int fo = ((t * 8 + c) * 64 + lane) * 8;
      bf16x8 wf = *(const bf16x8*)(lw + fo);
      acc[c] = __builtin_amdgcn_mfma_f32_16x16x32_bf16(a_h[t], wf, acc[c], 0, 0, 0);
    }
  }
  __syncthreads();
  {
    int4* d = (int4*)lw;
    const int4* s2 = (const int4*)wl;
#pragma unroll
    for (int i = 0; i < 4; ++i) d[tid + i * 512] = s2[tid + i * 512];
  }
  __syncthreads();
#pragma unroll
  for (int t = 0; t < 4; ++t) {
#pragma unroll
    for (int c = 0; c < 8; ++c) {
      int fo = ((t * 8 + c) * 64 + lane) * 8;
      bf16x8 wf = *(const bf16x8*)(lw + fo);
      acc[c] = __builtin_amdgcn_mfma_f32_16x16x32_bf16(a_h[t], wf, acc[c], 0, 0, 0);
    }
  }
  __syncthreads();

#pragma unroll
  for (int h = 0; h < 2; ++h) {
    if ((wv >> 2) == h) {
      int lrb = (wv & 3) * 16;
#pragma unroll
      for (int c = 0; c < 8; ++c)
#pragma unroll
        for (int r = 0; r < 4; ++r)
          lds[(lrb + lk * 4 + r) * 132 + c * 16 + lrow] = acc[c][r];
    }
    __syncthreads();
    {
      int lr = tid >> 3, c0 = (tid & 7) * 16;
      int grow = blockIdx.x * 128 + h * 64 + lr;
      if (grow < NN) {
        size_t o = (size_t)grow * 128 + c0;
        const float* sp = &lds[lr * 132 + c0];
#pragma unroll
        for (int i = 0; i < 4; ++i) {
          float4 v = *(const float4*)(sp + i * 4);
          float4 b4 = *(const float4*)&bias[c0 + i * 4];
          v.x += b4.x; v.y += b4.y; v.z += b4.z; v.w += b4.w;
          *(float4*)&C[o + i * 4] = v;
        }
      }
    }
    __syncthreads();
  }
}

// ---------------- fused head: mu then ls/z/zh/deg, 4-plane sequential, 33.8 KB ----------

__global__ __launch_bounds__(512, 4) void k_mmHZ(const unsigned short* Ah,
                                                 const unsigned short* __restrict__ wmuh,
                                                 const unsigned short* __restrict__ wmul,
                                                 const unsigned short* __restrict__ wlsh,
                                                 const unsigned short* __restrict__ wlsl,
                                                 const float* __restrict__ b_mu,
                                                 const float* __restrict__ b_ls,
                                                 const float* __restrict__ eps,
                                                 const float* __restrict__ Wd,
                                                 const float* __restrict__ bd,
                                                 float* __restrict__ mu,
                                                 float* __restrict__ logstd,
                                                 float* __restrict__ Z,
                                                 unsigned short* Zh,
                                                 float* __restrict__ degp) {
  __shared__ float lds[64 * 132];
  unsigned short* lw = (unsigned short*)lds;
  int tid = threadIdx.x;
  int wv = tid >> 6, lane = tid & 63;
  int lrow = lane & 15, lk = lane >> 4;
  int row = blockIdx.x * 128 + wv * 16 + lrow;

  // ---- mu GEMM ----
  {
    int4* d = (int4*)lw;
#pragma unroll
    for (int i = 0; i < 4; ++i) d[tid + i * 512] = ((const int4*)wmuh)[tid + i * 512];
  }
  bf16x8 a_h[4];
  const unsigned short* ap = Ah + (size_t)row * 128 + lk * 8;
#pragma unroll
  for (int t = 0; t < 4; ++t) a_h[t] = *(const bf16x8*)(ap + t * 32);
  __syncthreads();

  f32x4 acc[8];
#pragma unroll
  for (int c = 0; c < 8; ++c) acc[c] = (f32x4){0.f, 0.f, 0.f, 0.f};
#pragma unroll
  for (int t = 0; t < 4; ++t)
#pragma unroll
    for (int c = 0; c < 8; ++c) {
      int fo = ((t * 8 + c) * 64 + lane) * 8;
      acc[c] = __builtin_amdgcn_mfma_f32_16x16x32_bf16(a_h[t], *(const bf16x8*)(lw + fo),
                                                       acc[c], 0, 0, 0);
    }
  __syncthreads();
  {
    int4* d = (int4*)lw;
#pragma unroll
    for (int i = 0; i < 4; ++i) d[tid + i * 512] = ((const int4*)wmul)[tid + i * 512];
  }
  __syncthreads();
#pragma unroll
  for (int t = 0; t < 4; ++t)
#pragma unroll
    for (int c = 0; c < 8; ++c) {
      int fo = ((t * 8 + c) * 64 + lane) * 8;
      acc[c] = __builtin_amdgcn_mfma_f32_16x16x32_bf16(a_h[t], *(const bf16x8*)(lw + fo),
                                                       acc[c], 0, 0, 0);
    }
  __syncthreads();

  // epilogue: mu
#pragma unroll
  for (int h = 0; h < 2; ++h) {
    if ((wv >> 2) == h) {
      int lrb = (wv & 3) * 16;
#pragma unroll
      for (int c = 0; c < 8; ++c)
#pragma unroll
        for (int r = 0; r < 4; ++r)
          lds[(lrb + lk * 4 + r) * 132 + c * 16 + lrow] = acc[c][r];
    }
    __syncthreads();
    {
      int lr = tid >> 3, c0 = (tid & 7) * 16;
      int grow = blockIdx.x * 128 + h * 64 + lr;
      if (grow < NN) {
        size_t o = (size_t)grow * 128 + c0;
        const float* sp = &lds[lr * 132 + c0];
#pragma unroll
        for (int i = 0; i < 4; ++i) {
          float4 v = *(const float4*)(sp + i * 4);
          float4 b4 = *(const float4*)&b_mu[c0 + i * 4];
          v.x += b4.x; v.y += b4.y; v.z += b4.z; v.w += b4.w;
          *(float4*)&mu[o + i * 4] = v;
        }
      }
    }
    __syncthreads();
  }

  // ---- logstd GEMM ----
  {
    int4* d = (int4*)lw;
#pragma unroll
    for (int i = 0; i < 4; ++i) d[tid + i * 512] = ((const int4*)wlsh)[tid + i * 512];
  }
  __syncthreads();
#pragma unroll
  for (int c = 0; c < 8; ++c) acc[c] = (f32x4){0.f, 0.f, 0.f, 0.f};
#pragma unroll
  for (int t = 0; t < 4; ++t)
#pragma unroll
    for (int c = 0; c < 8; ++c) {
      int fo = ((t * 8 + c) * 64 + lane) * 8;
      acc[c] = __builtin_amdgcn_mfma_f32_16x16x32_bf16(a_h[t], *(const bf16x8*)(lw + fo),
                                                       acc[c], 0, 0, 0);
    }
  __syncthreads();
  {
    int4* d = (int4*)lw;
#pragma unroll
    for (int i = 0; i < 4; ++i) d[tid + i * 512] = ((const int4*)wlsl)[tid + i * 512];
  }
  __syncthreads();
#pragma unroll
  for (int t = 0; t < 4; ++t)
#pragma unroll
    for (int c = 0; c < 8; ++c) {
      int fo = ((t * 8 + c) * 64 + lane) * 8;
      acc[c] = __builtin_amdgcn_mfma_f32_16x16x32_bf16(a_h[t], *(const bf16x8*)(lw + fo),
                                                       acc[c], 0, 0, 0);
    }
  __syncthreads();

  // epilogue: ls, z (mu re-read within block, L1 write-through -> safe), zh, deg
#pragma unroll
  for (int h = 0; h < 2; ++h) {
    if ((wv >> 2) == h) {
      int lrb = (wv & 3) * 16;
#pragma unroll
      for (int c = 0; c < 8; ++c)
#pragma unroll
        for (int r = 0; r < 4; ++r)
          lds[(lrb + lk * 4 + r) * 132 + c * 16 + lrow] = acc[c][r];
    }
    __syncthreads();
    {
      int lr = tid >> 3, c0 = (tid & 7) * 16;
      int grow = blockIdx.x * 128 + h * 64 + lr;
      float s_deg = 0.f;
      if (grow < NN) {
        size_t o = (size_t)grow * 128 + c0;
        const float* sp = &lds[lr * 132 + c0];
#pragma unroll
        for (int i = 0; i < 4; ++i) {
          float4 v = *(const float4*)(sp + i * 4);
          float4 b4 = *(const float4*)&b_ls[c0 + i * 4];
          float4 ls;
          ls.x = fminf(v.x + b4.x, 10.f);
          ls.y = fminf(v.y + b4.y, 10.f);
          ls.z = fminf(v.z + b4.z, 10.f);
          ls.w = fminf(v.w + b4.w, 10.f);
          *(float4*)&logstd[o + i * 4] = ls;
          float4 m4 = *(const float4*)&mu[o + i * 4];
          float4 e4 = *(const float4*)&eps[o + i * 4];
          float4 z4;
          z4.x = fmaf(e4.x, expf(ls.x), m4.x);
          z4.y = fmaf(e4.y, expf(ls.y), m4.y);
          z4.z = fmaf(e4.z, expf(ls.z), m4.z);
          z4.w = fmaf(e4.w, expf(ls.w), m4.w);
          *(float4*)&Z[o + i * 4] = z4;
          ushort4 hh;
          hh.x = f2bf(z4.x); hh.y = f2bf(z4.y); hh.z = f2bf(z4.z); hh.w = f2bf(z4.w);
          *(ushort4*)&Zh[o + i * 4] = hh;
          float4 wd = *(const float4*)&Wd[c0 + i * 4];
          s_deg += z4.x * wd.x + z4.y * wd.y + z4.z * wd.z + z4.w * wd.w;
        }
      }
      s_deg += __shfl_xor(s_deg, 1);
      s_deg += __shfl_xor(s_deg, 2);
      s_deg += __shfl_xor(s_deg, 4);
      if (grow < NN && (tid & 7) == 0) degp[grow] = s_deg + bd[0];
    }
    __syncthreads();
  }
}

// ---------------- GATv2 aggregation: wave/row, 4x16 lanes, bf16 gathers ----------------

__global__ __launch_bounds__(256) void k_gat_agg(const unsigned short* __restrict__ gxl,
                                                 const unsigned short* __restrict__ gxr,
                                                 const float* __restrict__ att,
                                                 const float* __restrict__ bias,
                                                 const int* __restrict__ row_ptr,
                                                 const int* __restrict__ csr_src,
                                                 unsigned short* __restrict__ sh) {
  int gid = blockIdx.x * blockDim.x + threadIdx.x;
  int row = gid >> 6;
  int lane = gid & 63;
  if (row >= NN) return;
  int g = lane >> 4, j = lane & 15;
  int dbase = j * 8;

  float a[8], r[8];
  {
    float4 a0 = *(const float4*)&att[dbase];
    float4 a1 = *(const float4*)&att[dbase + 4];
    a[0] = a0.x; a[1] = a0.y; a[2] = a0.z; a[3] = a0.w;
    a[4] = a1.x; a[5] = a1.y; a[6] = a1.z; a[7] = a1.w;
    bf16x8 rv = *(const bf16x8*)&gxr[(size_t)row * 128 + dbase];
#pragma unroll
    for (int k = 0; k < 8; ++k) r[k] = bf2f((unsigned short)rv[k]);
  }

  float m = -INFINITY, d = 0.f;
  float acc[8] = {0.f, 0.f, 0.f, 0.f, 0.f, 0.f, 0.f, 0.f};
  int p0 = row_ptr[row], p1 = row_ptr[row + 1];

  for (int p = p0 + g; p < p1; p += 4) {
    int s = csr_src[p];
    bf16x8 xv = *(const bf16x8*)&gxl[(size_t)s * 128 + dbase];
    float v[8];
#pragma unroll
    for (int k = 0; k < 8; ++k) v[k] = bf2f((unsigned short)xv[k]);

    float e = 0.f;
#pragma unroll
    for (int k = 0; k < 8; ++k) {
      float t0 = v[k] + r[k];
      t0 = fmaxf(t0, 0.2f * t0);
      e = fmaf(t0, a[k], e);
    }
    e += __shfl_xor(e, 1);
    e += __shfl_xor(e, 2);
    e += __shfl_xor(e, 4);
    e += __shfl_xor(e, 8);

    float mn = fmaxf(m, e);
    float scl = __expf(m - mn);
    float w = __expf(e - mn);
    d = d * scl + w;
#pragma unroll
    for (int k = 0; k < 8; ++k) acc[k] = acc[k] * scl + w * v[k];
    m = mn;
  }

  float mo = fmaxf(m, __shfl_xor(m, 16));
  mo = fmaxf(mo, __shfl_xor(mo, 32));
  float scl = __expf(m - mo);
  d *= scl;
  d += __shfl_xor(d, 16);
  d += __shfl_xor(d, 32);
#pragma unroll
  for (int k = 0; k < 8; ++k) {
    acc[k] *= scl;
    acc[k] += __shfl_xor(acc[k], 16);
    acc[k] += __shfl_xor(acc[k], 32);
  }

  if (g == 0) {
    float inv = 1.f / d;
    float4 b0 = *(const float4*)&bias[dbase];
    float4 b1v = *(const float4*)&bias[dbase + 4];
    float bb[8] = {b0.x, b0.y, b0.z, b0.w, b1v.x, b1v.y, b1v.z, b1v.w};
    bf16x8 vh;
#pragma unroll
    for (int k = 0; k < 8; ++k) {
      float h = gelu_exact(acc[k] * inv + bb[k]);
      vh[k] = (short)f2bf(h);
    }
    *(bf16x8*)(sh + (size_t)row * 128 + dbase) = vh;
  }
}

// ---------------- host ----------------

static inline char* take(char*& p, size_t bytes) {
  char* r = p;
  p += (bytes + 255) & ~(size_t)255;
  return r;
}

extern "C" void kernel_launch(void* const* d_in, const int* in_sizes, int n_in,
                              void* d_out, int out_size, void* d_ws, size_t ws_size,
                              hipStream_t stream) {
  const float* x      = (const float*)d_in[0];
  const int*   ei     = (const int*)d_in[1];
  const float* eps    = (const float*)d_in[2];
  const float* encWl  = (const float*)d_in[3];
  const float* encWr  = (const float*)d_in[4];
  const float* encAtt = (const float*)d_in[5];
  const float* encB   = (const float*)d_in[6];
  const float* decWl  = (const float*)d_in[7];
  const float* decWr  = (const float*)d_in[8];
  const float* decAtt = (const float*)d_in[9];
  const float* decB   = (const float*)d_in[10];
  const float* W_mu   = (const float*)d_in[11];
  const float* b_mu   = (const float*)d_in[12];
  const float* W_ls   = (const float*)d_in[13];
  const float* b_ls   = (const float*)d_in[14];
  const float* W_out  = (const float*)d_in[15];
  const float* b_out  = (const float*)d_in[16];
  const float* W_deg  = (const float*)d_in[17];
  const float* b_deg  = (const float*)d_in[18];

  float* out    = (float*)d_out;
  float* x_rec  = out;
  float* z      = out + (size_t)ND;
  float* mu     = out + (size_t)2 * ND;
  float* logstd = out + (size_t)3 * ND;
  float* degp   = out + (size_t)4 * ND;

  char* p = (char*)d_ws;
  int* bktcnt  = (int*)take(p, 1024 * 4);
  int* bktoff  = (int*)take(p, 1024 * 4);
  int* slack   = (int*)take(p, (size_t)NBKT * SCAP * 4);
  int* row_ptr = (int*)take(p, (size_t)(NN + 1) * 4);
  int* csr_src = (int*)take(p, (size_t)ET * 4);
  unsigned short* gxl  = (unsigned short*)take(p, (size_t)MPAD * 128 * 2);
  unsigned short* gxr  = (unsigned short*)take(p, (size_t)MPAD * 128 * 2);
  unsigned short* stgh = (unsigned short*)take(p, (size_t)MPAD * 128 * 2);
  unsigned short* wfh  = (unsigned short*)take(p, (size_t)19 * 16384 * 2);
  unsigned short* wfl  = (unsigned short*)take(p, (size_t)19 * 16384 * 2);

  const int gMM   = MPAD / 128;             // 782
  const int gWave = (NN * 64 + 255) / 256;  // 25000

  // CSR build
  k_zero_int<<<4, 256, 0, stream>>>(bktcnt, 1024);
  kb_scatter<<<GSC, 256, 0, stream>>>(ei, bktcnt, slack);
  kb_scan<<<1, 256, 0, stream>>>(bktcnt, bktoff);
  kb_fin<<<NBKT, 256, 0, stream>>>(slack, bktoff, csr_src, row_ptr);

  // weight frags
  k_wconv<<<152, 256, 0, stream>>>(encWl, encWr, decWl, decWr, W_mu, W_ls, W_out, wfh, wfl);

  const size_t WM = 16384;
  // encoder (layer 0 reads fp32 x directly)
  for (int l = 0; l < 4; ++l) {
    if (l == 0)
      k_mmL<1><<<gMM, 512, 0, stream>>>(nullptr, x,
                                        wfh + (size_t)l * WM, wfh + (size_t)(4 + l) * WM,
                                        gxl, gxr);
    else
      k_mmL<0><<<gMM, 512, 0, stream>>>(stgh, nullptr,
                                        wfh + (size_t)l * WM, wfh + (size_t)(4 + l) * WM,
                                        gxl, gxr);
    k_gat_agg<<<gWave, 256, 0, stream>>>(gxl, gxr, encAtt + (size_t)l * DD,
                                         encB + (size_t)l * DD, row_ptr, csr_src, stgh);
  }

  // fused heads: mu, ls, z, z-stage, degree
  k_mmHZ<<<gMM, 512, 0, stream>>>(stgh,
                                  wfh + (size_t)16 * WM, wfl + (size_t)16 * WM,
                                  wfh + (size_t)17 * WM, wfl + (size_t)17 * WM,
                                  b_mu, b_ls, eps, W_deg, b_deg,
                                  mu, logstd, z, stgh, degp);

  // decoder
  for (int l = 0; l < 4; ++l) {
    k_mmL<0><<<gMM, 512, 0, stream>>>(stgh, nullptr,
                                      wfh + (size_t)(8 + l) * WM, wfh + (size_t)(12 + l) * WM,
                                      gxl, gxr);
    k_gat_agg<<<gWave, 256, 0, stream>>>(gxl, gxr, decAtt + (size_t)l * DD,
                                         decB + (size_t)l * DD, row_ptr, csr_src, stgh);
  }

  // x_rec
  k_mmO<<<gMM, 512, 0, stream>>>(stgh,
                                 wfh + (size_t)18 * WM, wfl + (size_t)18 * WM,
                                 b_out, x_rec);
}